// Round 8
// baseline (865.290 us; speedup 1.0000x reference)
//
#include <hip/hip_runtime.h>
#include <cstdint>
#include <cstddef>

#define NPTS 262144
#define BLK 256
#define TGX 176
#define TGY 200
#define TGZ 1

#define G_TOPC 70400
#define G_MEDC 1126400
#define G_LOWC 4505600

#define SCAN_ITEMS 32
#define SCAN_CHUNK (BLK*SCAN_ITEMS)
// batched scan block counts / bsum offsets (disjoint: [0,9) [16,154) [160,710))
#define NB_T 9
#define NB_M 138
#define NB_L 550
#define BO_T 0
#define BO_M 16
#define BO_L 160
// vox13 block split
#define NBVT (G_TOPC/BLK)      // 275
#define NBVM (NPTS/BLK)        // 1024
#define NBVL (NPTS/BLK)        // 1024

#define Y2BLKS (NPTS/64)       // 4096 per scale
#define ST1BLKS 256            // stats1 blocks per scale (1024 rows each)
// batched per-scale stage grids
#define NHT 4400               // G_TOPC*16/BLK
#define NHM 8192               // NPTS*8/BLK
#define NJT 8800               // G_TOPC*32/BLK
#define NJM 16384              // NPTS*16/BLK
#define NCL 275                // G_TOPC/BLK (ceil)

// ---------------- per-scale parameter pack ----------------
struct SP {
  const float4* srt; const int* jr; const float4* vm;
  const float* W1; const float* W2;
  const float* g1; const float* b1; const float* g2; const float* b2;
  const int* cnt; const int* uniq; const int* woff; const int* U;
  float* segt; float* part1; float* part2;
  float* coef1; float* coef2; float* Y2; float* hout;
  int C1; int segstride; int gx, gy, gz; float vx, vy, vz;
};

// ---------------- voxel coord helpers ----------------
__device__ __forceinline__ void pcoords(float x, float y, float z,
    float vx, float vy, float vz, int gx, int gy, int gz,
    int& cx, int& cy, int& cz) {
  cx = (int)floorf((x - 0.0f)  / vx);
  cy = (int)floorf((y + 40.0f) / vy);
  cz = (int)floorf((z + 3.0f)  / vz);
  cx = min(max(cx, 0), gx - 1);
  cy = min(max(cy, 0), gy - 1);
  cz = min(max(cz, 0), gz - 1);
}

__device__ __forceinline__ int lin3(float b, float x, float y, float z,
    float vx, float vy, float vz, int gx, int gy, int gz) {
  int cx, cy, cz; pcoords(x, y, z, vx, vy, vz, gx, gy, gz, cx, cy, cz);
  return (((int)b * gz + cz) * gy + cy) * gx + cx;
}

// f-vector (10 features) — identical expression everywhere y1 is recomputed.
__device__ __forceinline__ void build_f(float4 p, float4 vm,
    float vx, float vy, float vz, int gx, int gy, int gz, float* f) {
  int cx, cy, cz; pcoords(p.x, p.y, p.z, vx, vy, vz, gx, gy, gz, cx, cy, cz);
  f[0] = p.x; f[1] = p.y; f[2] = p.z; f[3] = p.w;
  f[4] = p.x - vm.x;
  f[5] = p.y - vm.y;
  f[6] = p.z - vm.z;
  f[7] = p.x - (0.0f   + (cx + 0.5f)*vx);
  f[8] = p.y - (-40.0f + (cy + 0.5f)*vy);
  f[9] = p.z - (-3.0f  + (cz + 0.5f)*vz);
}

// ---------------- batched dense count (all 3 scales) ----------------
__global__ __launch_bounds__(BLK) void k_count3(const float* __restrict__ pts,
    int* __restrict__ ct, int* __restrict__ cm, int* __restrict__ cl) {
  int i = blockIdx.x * BLK + threadIdx.x;
  if (i >= NPTS) return;
  float b = pts[i*5+0], x = pts[i*5+1], y = pts[i*5+2], z = pts[i*5+3];
  atomicAdd(&ct[lin3(b,x,y,z, 0.4f,0.4f,4.0f, 176,200,1)], 1);
  atomicAdd(&cm[lin3(b,x,y,z, 0.2f,0.2f,2.0f, 352,400,2)], 1);
  atomicAdd(&cl[lin3(b,x,y,z, 0.1f,0.1f,1.0f, 704,800,4)], 1);
}

// ---------------- batched scans ----------------
__global__ __launch_bounds__(BLK) void k_scan1_all(const int* __restrict__ ct,
    const int* __restrict__ cm, const int* __restrict__ cl,
    int2* __restrict__ bsum) {
  int bid = blockIdx.x;
  const int* cnt; int G, bo, cb;
  if (bid < NB_T)            { cnt = ct; G = G_TOPC; bo = BO_T; cb = bid; }
  else if (bid < NB_T+NB_M)  { cnt = cm; G = G_MEDC; bo = BO_M; cb = bid - NB_T; }
  else                       { cnt = cl; G = G_LOWC; bo = BO_L; cb = bid - NB_T - NB_M; }
  int base = cb * SCAN_CHUNK + threadIdx.x * SCAN_ITEMS;
  int so = 0, sp = 0;
  #pragma unroll
  for (int k = 0; k < SCAN_ITEMS; k++) {
    int j = base + k;
    if (j < G) { int c = cnt[j]; if (c > 0) { so++; sp += c; } }
  }
  __shared__ int sho[BLK], shp[BLK];
  sho[threadIdx.x] = so; shp[threadIdx.x] = sp; __syncthreads();
  for (int off = BLK/2; off > 0; off >>= 1) {
    if (threadIdx.x < off) {
      sho[threadIdx.x] += sho[threadIdx.x + off];
      shp[threadIdx.x] += shp[threadIdx.x + off];
    }
    __syncthreads();
  }
  if (threadIdx.x == 0) { int2 v; v.x = sho[0]; v.y = shp[0]; bsum[bo + cb] = v; }
}

__device__ void scan_pass(int2* bsum, int off, int nb, int* U,
                          int* so, int* sp) {
  int t = threadIdx.x;
  int vo = 0, vp = 0;
  if (t < nb) { int2 v = bsum[off + t]; vo = v.x; vp = v.y; }
  so[t] = vo; sp[t] = vp; __syncthreads();
  for (int o = 1; o < 1024; o <<= 1) {
    int ao = (t >= o) ? so[t - o] : 0;
    int ap = (t >= o) ? sp[t - o] : 0;
    __syncthreads();
    so[t] += ao; sp[t] += ap;
    __syncthreads();
  }
  if (t < nb) { int2 e; e.x = so[t] - vo; e.y = sp[t] - vp; bsum[off + t] = e; }
  if (t == 0) *U = so[1023];
  __syncthreads();
}

__global__ __launch_bounds__(1024) void k_scan2_all(int2* __restrict__ bsum,
    int* __restrict__ Ut, int* __restrict__ Um, int* __restrict__ Ul) {
  __shared__ int so[1024], sp[1024];
  scan_pass(bsum, BO_T, NB_T, Ut, so, sp);
  scan_pass(bsum, BO_M, NB_M, Um, so, sp);
  scan_pass(bsum, BO_L, NB_L, Ul, so, sp);
}

__global__ __launch_bounds__(BLK) void k_scan3_all(const int* __restrict__ ct,
    const int* __restrict__ cm, const int* __restrict__ cl,
    const int2* __restrict__ bsum,
    int* __restrict__ rkt, int* __restrict__ rkm, int* __restrict__ rkl,
    int* __restrict__ uqt, int* __restrict__ uqm, int* __restrict__ uql,
    int* __restrict__ wot, int* __restrict__ wom, int* __restrict__ wol) {
  int bid = blockIdx.x;
  const int* cnt; int G, bo, cb; int *rank, *uniq, *woff;
  if (bid < NB_T)           { cnt=ct; G=G_TOPC; bo=BO_T; cb=bid;            rank=rkt; uniq=uqt; woff=wot; }
  else if (bid < NB_T+NB_M) { cnt=cm; G=G_MEDC; bo=BO_M; cb=bid-NB_T;       rank=rkm; uniq=uqm; woff=wom; }
  else                      { cnt=cl; G=G_LOWC; bo=BO_L; cb=bid-NB_T-NB_M;  rank=rkl; uniq=uql; woff=wol; }
  int base = cb * SCAN_CHUNK + threadIdx.x * SCAN_ITEMS;
  int so = 0, sp = 0;
  #pragma unroll
  for (int k = 0; k < SCAN_ITEMS; k++) {
    int j = base + k;
    if (j < G) { int c = cnt[j]; if (c > 0) { so++; sp += c; } }
  }
  __shared__ int sho[BLK], shp[BLK];
  sho[threadIdx.x] = so; shp[threadIdx.x] = sp; __syncthreads();
  for (int off = 1; off < BLK; off <<= 1) {
    int ao = (threadIdx.x >= off) ? sho[threadIdx.x - off] : 0;
    int ap = (threadIdx.x >= off) ? shp[threadIdx.x - off] : 0;
    __syncthreads();
    sho[threadIdx.x] += ao; shp[threadIdx.x] += ap;
    __syncthreads();
  }
  int2 bb = bsum[bo + cb];
  int ro = bb.x + sho[threadIdx.x] - so;
  int po = bb.y + shp[threadIdx.x] - sp;
  for (int k = 0; k < SCAN_ITEMS; k++) {
    int j = base + k;
    if (j < G) {
      int c = cnt[j];
      if (c > 0) { rank[j] = ro; uniq[ro] = j; woff[ro] = po; ro++; po += c; }
    }
  }
}

// ---------------- batched counting-sort scatter ----------------
__global__ __launch_bounds__(BLK) void k_scatter3(const float* __restrict__ pts,
    const int* __restrict__ rkt, int* __restrict__ wot, float4* __restrict__ st, int* __restrict__ jt,
    const int* __restrict__ rkm, int* __restrict__ wom, float4* __restrict__ sm, int* __restrict__ jm,
    const int* __restrict__ rkl, int* __restrict__ wol, float4* __restrict__ sl, int* __restrict__ jl) {
  int i = blockIdx.x * BLK + threadIdx.x;
  if (i >= NPTS) return;
  float b = pts[i*5+0], x = pts[i*5+1], y = pts[i*5+2], z = pts[i*5+3], it = pts[i*5+4];
  float4 p; p.x = x; p.y = y; p.z = z; p.w = it;
  {
    int r = rkt[lin3(b,x,y,z, 0.4f,0.4f,4.0f, 176,200,1)];
    int j = atomicAdd(&wot[r], 1); st[j] = p; jt[j] = r;
  }
  {
    int r = rkm[lin3(b,x,y,z, 0.2f,0.2f,2.0f, 352,400,2)];
    int j = atomicAdd(&wom[r], 1); sm[j] = p; jm[j] = r;
  }
  {
    int r = rkl[lin3(b,x,y,z, 0.1f,0.1f,1.0f, 704,800,4)];
    int j = atomicAdd(&wol[r], 1); sl[j] = p; jl[j] = r;
  }
}

// ---------------- batched per-voxel xyz means ----------------
__global__ __launch_bounds__(BLK) void k_vox13(
    const float4* __restrict__ st, const int* __restrict__ uqt, const int* __restrict__ ct,
    const int* __restrict__ wot, const int* __restrict__ Ut, float4* __restrict__ vt,
    const float4* __restrict__ sm, const int* __restrict__ uqm, const int* __restrict__ cm,
    const int* __restrict__ wom, const int* __restrict__ Um, float4* __restrict__ vm,
    const float4* __restrict__ sl, const int* __restrict__ uql, const int* __restrict__ cl,
    const int* __restrict__ wol, const int* __restrict__ Ul, float4* __restrict__ vl) {
  int bid = blockIdx.x;
  const float4* srt; const int *uniq, *cnt, *woff, *Up; float4* vmean; int r;
  if (bid < NBVT)           { r = bid*BLK + threadIdx.x;           srt=st; uniq=uqt; cnt=ct; woff=wot; Up=Ut; vmean=vt; }
  else if (bid < NBVT+NBVM) { r = (bid-NBVT)*BLK + threadIdx.x;    srt=sm; uniq=uqm; cnt=cm; woff=wom; Up=Um; vmean=vm; }
  else                      { r = (bid-NBVT-NBVM)*BLK + threadIdx.x; srt=sl; uniq=uql; cnt=cl; woff=wol; Up=Ul; vmean=vl; }
  if (r >= *Up) return;
  int lin = uniq[r];
  int len = cnt[lin];
  int base = woff[r] - len;
  float sx = 0.f, sy = 0.f, sz = 0.f;
  for (int k = 0; k < len; k++) {
    float4 p = srt[base + k];
    sx += p.x; sy += p.y; sz += p.z;
  }
  float il = 1.0f / (float)len;
  float4 o; o.x = sx*il; o.y = sy*il; o.z = sz*il; o.w = il;
  vmean[r] = o;
}

// ------- fused y1-compute + column sum/sumsq partials (all scales) ----------
__global__ __launch_bounds__(BLK) void k_stats1_all(SP a, SP b, SP c) {
  int s = blockIdx.x >> 8;
  int blk = blockIdx.x & 255;
  SP sp = (s == 0) ? a : ((s == 1) ? b : c);
  const int C1 = sp.C1;
  __shared__ float w[640];
  __shared__ float wsum[4][64], wsq[4][64];
  for (int t = threadIdx.x; t < 10*C1; t += BLK) w[t] = sp.W1[t];
  __syncthreads();
  float f[4][10];
  #pragma unroll
  for (int k = 0; k < 4; k++) {
    int i = blk*1024 + k*BLK + threadIdx.x;
    float4 p = sp.srt[i];
    float4 vmn = sp.vm[sp.jr[i]];
    build_f(p, vmn, sp.vx, sp.vy, sp.vz, sp.gx, sp.gy, sp.gz, f[k]);
  }
  int wv = threadIdx.x >> 6;
  int lane = threadIdx.x & 63;
  for (int o = 0; o < C1; o += 4) {
    float sacc[4] = {0,0,0,0}, qacc[4] = {0,0,0,0};
    #pragma unroll
    for (int k = 0; k < 4; k++) {
      float a0=0.f, a1=0.f, a2=0.f, a3=0.f;
      #pragma unroll
      for (int d = 0; d < 10; d++) {
        float fv = f[k][d];
        const float* wr = &w[d*C1 + o];
        a0 = fmaf(fv, wr[0], a0); a1 = fmaf(fv, wr[1], a1);
        a2 = fmaf(fv, wr[2], a2); a3 = fmaf(fv, wr[3], a3);
      }
      sacc[0] += a0; sacc[1] += a1; sacc[2] += a2; sacc[3] += a3;
      qacc[0] += a0*a0; qacc[1] += a1*a1; qacc[2] += a2*a2; qacc[3] += a3*a3;
    }
    #pragma unroll
    for (int m = 1; m < 64; m <<= 1) {
      #pragma unroll
      for (int e = 0; e < 4; e++) {
        sacc[e] += __shfl_xor(sacc[e], m);
        qacc[e] += __shfl_xor(qacc[e], m);
      }
    }
    if (lane == 0) {
      #pragma unroll
      for (int e = 0; e < 4; e++) { wsum[wv][o+e] = sacc[e]; wsq[wv][o+e] = qacc[e]; }
    }
  }
  __syncthreads();
  if (threadIdx.x < C1) {
    int ch = threadIdx.x;
    float sv = wsum[0][ch] + wsum[1][ch] + wsum[2][ch] + wsum[3][ch];
    float qv = wsq[0][ch] + wsq[1][ch] + wsq[2][ch] + wsq[3][ch];
    sp.part1[(size_t)blk*2*C1 + ch]      = sv;
    sp.part1[(size_t)blk*2*C1 + C1 + ch] = qv;
  }
}

// ---- reduce per-block partials -> BN coef (stage 1: C1; stage 2: C2) -------
__device__ __forceinline__ void partcoef_body(const float* part, int NB, int C,
    int ch, const float* g, const float* b, float* coef) {
  float s = 0.f, q = 0.f;
  for (int bk = threadIdx.x; bk < NB; bk += BLK) {
    s += part[(size_t)bk*2*C + ch];
    q += part[(size_t)bk*2*C + C + ch];
  }
  __shared__ float ss[BLK], sq[BLK];
  ss[threadIdx.x] = s; sq[threadIdx.x] = q; __syncthreads();
  for (int off = BLK/2; off > 0; off >>= 1) {
    if (threadIdx.x < off) {
      ss[threadIdx.x] += ss[threadIdx.x + off];
      sq[threadIdx.x] += sq[threadIdx.x + off];
    }
    __syncthreads();
  }
  if (threadIdx.x == 0) {
    float mu  = ss[0] * (1.0f / NPTS);
    float var = sq[0] * (1.0f / NPTS) - mu*mu;
    float sc  = g[ch] * (1.0f / sqrtf(var + 1e-3f));
    coef[ch]     = sc;
    coef[C + ch] = fmaf(-mu, sc, b[ch]);
  }
}

__global__ __launch_bounds__(BLK) void k_partcoef1_all(SP a, SP b, SP c) {
  int bid = blockIdx.x; SP sp; int ch;
  if (bid < 64)      { sp = a; ch = bid; }
  else if (bid < 96) { sp = b; ch = bid - 64; }
  else               { sp = c; ch = bid - 96; }
  if (ch >= sp.C1) return;
  partcoef_body(sp.part1, ST1BLKS, sp.C1, ch, sp.g1, sp.b1, sp.coef1);
}

__global__ __launch_bounds__(BLK) void k_partcoef2_all(SP a, SP b, SP c) {
  int bid = blockIdx.x; SP sp; int ch;
  if (bid < 128)      { sp = a; ch = bid; }
  else if (bid < 192) { sp = b; ch = bid - 128; }
  else                { sp = c; ch = bid - 192; }
  if (ch >= 2*sp.C1) return;
  partcoef_body(sp.part2, Y2BLKS, 2*sp.C1, ch, sp.g2, sp.b2, sp.coef2);
}

// ---- layer-1 voxel means of BN+ReLU(y1), y1 recomputed (all scales) --------
__global__ __launch_bounds__(BLK) void k_hsegT_all(SP a, SP b, SP c) {
  int bid = blockIdx.x; SP sp; int rb;
  if (bid < NHT)           { sp = a; rb = bid; }
  else if (bid < NHT+NHM)  { sp = b; rb = bid - NHT; }
  else                     { sp = c; rb = bid - NHT - NHM; }
  const int C1 = sp.C1;
  const int qsh = (C1 == 64) ? 4 : 3;
  __shared__ float w[640];
  __shared__ float sc[64], sb[64];
  for (int t = threadIdx.x; t < 10*C1; t += BLK) w[t] = sp.W1[t];
  for (int t = threadIdx.x; t < C1; t += BLK) { sc[t] = sp.coef1[t]; sb[t] = sp.coef1[C1 + t]; }
  __syncthreads();
  int tid = rb * BLK + threadIdx.x;
  int r = tid >> qsh;
  int q = tid & ((1 << qsh) - 1);
  if (r >= *sp.U) return;
  int lin = sp.uniq[r];
  int len = sp.cnt[lin];
  int base = sp.woff[r] - len;
  float4 vmn = sp.vm[r];
  int c0 = q * 4;
  float s0 = sc[c0+0], s1 = sc[c0+1], s2 = sc[c0+2], s3 = sc[c0+3];
  float o0 = sb[c0+0], o1 = sb[c0+1], o2 = sb[c0+2], o3 = sb[c0+3];
  float a0=0.f, a1=0.f, a2=0.f, a3=0.f;
  for (int k = 0; k < len; k++) {
    float4 p = sp.srt[base + k];
    float f[10];
    build_f(p, vmn, sp.vx, sp.vy, sp.vz, sp.gx, sp.gy, sp.gz, f);
    float y0=0.f, y1=0.f, y2=0.f, y3=0.f;
    #pragma unroll
    for (int d = 0; d < 10; d++) {
      float fv = f[d];
      const float* wr = &w[d*C1 + c0];
      y0 = fmaf(fv, wr[0], y0); y1 = fmaf(fv, wr[1], y1);
      y2 = fmaf(fv, wr[2], y2); y3 = fmaf(fv, wr[3], y3);
    }
    a0 += fmaxf(fmaf(y0, s0, o0), 0.f);
    a1 += fmaxf(fmaf(y1, s1, o1), 0.f);
    a2 += fmaxf(fmaf(y2, s2, o2), 0.f);
    a3 += fmaxf(fmaf(y3, s3, o3), 0.f);
  }
  float il = 1.0f / (float)len;
  sp.segt[(size_t)(c0+0)*sp.segstride + r] = a0*il;
  sp.segt[(size_t)(c0+1)*sp.segstride + r] = a1*il;
  sp.segt[(size_t)(c0+2)*sp.segstride + r] = a2*il;
  sp.segt[(size_t)(c0+3)*sp.segstride + r] = a3*il;
}

// ------- layer 2 LDS-tiled GEMM (all scales); fused column stats ------------
__global__ __launch_bounds__(BLK) void k_y2t_all(SP a, SP b, SP c) {
  int s = blockIdx.x >> 12;
  int blk = blockIdx.x & 4095;
  SP sp = (s == 0) ? a : ((s == 1) ? b : c);
  const int C1 = sp.C1;
  const int K  = 2*C1;
  const int C2 = 2*C1;
  const int MT = 64;
  const int NT = 64;
  const int NPAN = C1 >> 5;            // 2 (top) or 1 (med/low)
  __shared__ float At[128*64];   // [k][j]; reused as reduction scratch at end
  __shared__ float Bp[128*64];   // [k][c]; prologue aliases live here
  float* w1A  = Bp;                            // 10*C1 floats
  float* fA   = Bp + 10*C1;                    // 64*11 floats
  int*   jrlA = (int*)(Bp + 10*C1 + MT*11);    // 64 ints
  const int tid  = threadIdx.x;
  const int base = blk * MT;

  for (int t = tid; t < 10*C1; t += BLK) w1A[t] = sp.W1[t];
  if (tid < MT) {
    int jr = sp.jr[base + tid];
    jrlA[tid] = jr;
    float4 p  = sp.srt[base + tid];
    float4 vmn = sp.vm[jr];
    float f[10];
    build_f(p, vmn, sp.vx, sp.vy, sp.vz, sp.gx, sp.gy, sp.gz, f);
    #pragma unroll
    for (int d = 0; d < 10; d++) fA[tid*11 + d] = f[d];
  }
  __syncthreads();

  // A-tile first C1 rows: y1 computed from f + W1, BN+ReLU applied.
  for (int it = tid; it < (C1 >> 2)*MT; it += BLK) {
    int kq = it >> 6;
    int j  = it & 63;
    int c0 = kq * 4;
    float y0=0.f, y1=0.f, y2=0.f, y3=0.f;
    #pragma unroll
    for (int d = 0; d < 10; d++) {
      float fv = fA[j*11 + d];
      const float* wr = &w1A[d*C1 + c0];
      y0 = fmaf(fv, wr[0], y0); y1 = fmaf(fv, wr[1], y1);
      y2 = fmaf(fv, wr[2], y2); y3 = fmaf(fv, wr[3], y3);
    }
    At[(c0+0)*MT + j] = fmaxf(fmaf(y0, sp.coef1[c0+0], sp.coef1[C1+c0+0]), 0.f);
    At[(c0+1)*MT + j] = fmaxf(fmaf(y1, sp.coef1[c0+1], sp.coef1[C1+c0+1]), 0.f);
    At[(c0+2)*MT + j] = fmaxf(fmaf(y2, sp.coef1[c0+2], sp.coef1[C1+c0+2]), 0.f);
    At[(c0+3)*MT + j] = fmaxf(fmaf(y3, sp.coef1[c0+3], sp.coef1[C1+c0+3]), 0.f);
  }
  // A-tile seg half (gather via jrl; consecutive-lane stores, conflict-free).
  for (int it = tid; it < C1*MT; it += BLK) {
    int ch = it >> 6;
    int j  = it & 63;
    At[(C1 + ch)*MT + j] = sp.segt[(size_t)ch*sp.segstride + jrlA[j]];
  }

  const int w      = tid >> 6;
  const int lane   = tid & 63;
  const int colg   = lane & 15;
  const int rowsub = lane >> 4;
  const int arow   = w*16 + rowsub*4;

  float cs[2][4], cq[2][4];
  for (int p = 0; p < NPAN; p++) {
    __syncthreads();   // At+aliases done (p=0) / previous panel compute done
    for (int it = tid; it < K*(NT/4); it += BLK) {
      int k   = it >> 4;
      int cq4 = (it & 15) << 2;
      *(float4*)&Bp[k*NT + cq4] = *(const float4*)&sp.W2[(size_t)k*C2 + p*NT + cq4];
    }
    __syncthreads();
    float4 ac0 = {0,0,0,0}, ac1 = {0,0,0,0}, ac2 = {0,0,0,0}, ac3 = {0,0,0,0};
    #pragma unroll 8
    for (int k = 0; k < K; k++) {
      float4 av = *(const float4*)&At[k*MT + arow];
      float4 bv = *(const float4*)&Bp[k*NT + colg*4];
      ac0.x = fmaf(av.x, bv.x, ac0.x); ac0.y = fmaf(av.x, bv.y, ac0.y);
      ac0.z = fmaf(av.x, bv.z, ac0.z); ac0.w = fmaf(av.x, bv.w, ac0.w);
      ac1.x = fmaf(av.y, bv.x, ac1.x); ac1.y = fmaf(av.y, bv.y, ac1.y);
      ac1.z = fmaf(av.y, bv.z, ac1.z); ac1.w = fmaf(av.y, bv.w, ac1.w);
      ac2.x = fmaf(av.z, bv.x, ac2.x); ac2.y = fmaf(av.z, bv.y, ac2.y);
      ac2.z = fmaf(av.z, bv.z, ac2.z); ac2.w = fmaf(av.z, bv.w, ac2.w);
      ac3.x = fmaf(av.w, bv.x, ac3.x); ac3.y = fmaf(av.w, bv.y, ac3.y);
      ac3.z = fmaf(av.w, bv.z, ac3.z); ac3.w = fmaf(av.w, bv.w, ac3.w);
    }
    cs[p][0] = ac0.x + ac1.x + ac2.x + ac3.x;
    cs[p][1] = ac0.y + ac1.y + ac2.y + ac3.y;
    cs[p][2] = ac0.z + ac1.z + ac2.z + ac3.z;
    cs[p][3] = ac0.w + ac1.w + ac2.w + ac3.w;
    cq[p][0] = ac0.x*ac0.x + ac1.x*ac1.x + ac2.x*ac2.x + ac3.x*ac3.x;
    cq[p][1] = ac0.y*ac0.y + ac1.y*ac1.y + ac2.y*ac2.y + ac3.y*ac3.y;
    cq[p][2] = ac0.z*ac0.z + ac1.z*ac1.z + ac2.z*ac2.z + ac3.z*ac3.z;
    cq[p][3] = ac0.w*ac0.w + ac1.w*ac1.w + ac2.w*ac2.w + ac3.w*ac3.w;
    size_t ob = (size_t)(base + arow)*C2 + p*NT + colg*4;
    *(float4*)&sp.Y2[ob + 0*C2] = ac0;
    *(float4*)&sp.Y2[ob + 1*C2] = ac1;
    *(float4*)&sp.Y2[ob + 2*C2] = ac2;
    *(float4*)&sp.Y2[ob + 3*C2] = ac3;
  }

  // ---- fused per-block column sum/sumsq partials (reuse At as scratch) ----
  __syncthreads();
  float* red = At;                 // [32][C2+1]
  const int contrib = w*4 + rowsub;
  for (int p = 0; p < NPAN; p++) {
    #pragma unroll
    for (int e = 0; e < 4; e++) {
      red[contrib*(C2+1) + p*NT + colg*4 + e]        = cs[p][e];
      red[(16 + contrib)*(C2+1) + p*NT + colg*4 + e] = cq[p][e];
    }
  }
  __syncthreads();
  if (tid < C2) {
    float sv = 0.f, qv = 0.f;
    #pragma unroll 4
    for (int i = 0; i < 16; i++) {
      sv += red[i*(C2+1) + tid];
      qv += red[(16 + i)*(C2+1) + tid];
    }
    sp.part2[(size_t)blk*2*C2 + tid]      = sv;
    sp.part2[(size_t)blk*2*C2 + C2 + tid] = qv;
  }
}

// -------- layer-2 BN+ReLU + voxel mean (all scales) -------------------------
__global__ __launch_bounds__(BLK) void k_hseg2_all(SP a, SP b, SP c) {
  int bid = blockIdx.x; SP sp; int rb;
  if (bid < NJT)           { sp = a; rb = bid; }
  else if (bid < NJT+NJM)  { sp = b; rb = bid - NJT; }
  else                     { sp = c; rb = bid - NJT - NJM; }
  const int C = 2*sp.C1;
  const int qsh = (C == 128) ? 5 : 4;
  __shared__ float sc[128], sb[128];
  for (int t = threadIdx.x; t < C; t += BLK) { sc[t] = sp.coef2[t]; sb[t] = sp.coef2[C + t]; }
  __syncthreads();
  int tid = rb * BLK + threadIdx.x;
  int r = tid >> qsh;
  int q = tid & ((1 << qsh) - 1);
  if (r >= *sp.U) return;
  int lin = sp.uniq[r];
  int len = sp.cnt[lin];
  int base = sp.woff[r] - len;
  int c0 = q * 4;
  float s0 = sc[c0+0], s1 = sc[c0+1], s2 = sc[c0+2], s3 = sc[c0+3];
  float o0 = sb[c0+0], o1 = sb[c0+1], o2 = sb[c0+2], o3 = sb[c0+3];
  float a0=0.f, a1=0.f, a2=0.f, a3=0.f;
  for (int k = 0; k < len; k++) {
    float4 v = *(const float4*)&sp.Y2[(size_t)(base + k)*C + c0];
    a0 += fmaxf(fmaf(v.x, s0, o0), 0.f);
    a1 += fmaxf(fmaf(v.y, s1, o1), 0.f);
    a2 += fmaxf(fmaf(v.z, s2, o2), 0.f);
    a3 += fmaxf(fmaf(v.w, s3, o3), 0.f);
  }
  float il = 1.0f / (float)len;
  float4 o = {a0*il, a1*il, a2*il, a3*il};
  *(float4*)&sp.hout[(size_t)r*C + c0] = o;
}

// ------------- merge: per-parent child-rank lists (med+low batched) ---------
__global__ __launch_bounds__(BLK) void k_clist_all(const int* __restrict__ tuniq,
    const int* __restrict__ Utp,
    const int* __restrict__ cnt_m, const int* __restrict__ rank_m,
    int* __restrict__ clist_m, int* __restrict__ mcnt_m,
    const int* __restrict__ cnt_l, const int* __restrict__ rank_l,
    int* __restrict__ clist_l, int* __restrict__ mcnt_l) {
  int bid = blockIdx.x;
  const int *scnt, *srank; int *clist, *mcnt;
  int gx, gy, gz, f, rb;
  if (bid < NCL) { scnt=cnt_m; srank=rank_m; clist=clist_m; mcnt=mcnt_m;
                   gx=352; gy=400; gz=2; f=2; rb=bid; }
  else           { scnt=cnt_l; srank=rank_l; clist=clist_l; mcnt=mcnt_l;
                   gx=704; gy=800; gz=4; f=4; rb=bid-NCL; }
  int r = rb * BLK + threadIdx.x;
  if (r >= *Utp) return;
  int lin = tuniq[r];
  int x = lin % TGX; int t = lin / TGX;
  int y = t % TGY;   int b = t / TGY;   // TGZ == 1 so z == 0
  int m = 0;
  for (int cz = 0; cz < gz; cz++)
    for (int yy = y*f; yy < y*f + f; yy++)
      for (int xx = x*f; xx < x*f + f; xx++) {
        int cl = ((b*gz + cz)*gy + yy)*gx + xx;
        if (scnt[cl] > 0) clist[(size_t)r*64 + (m++)] = srank[cl];
      }
  mcnt[r] = m;
}

__global__ __launch_bounds__(BLK) void k_merge2_all(
    const float* __restrict__ vox_m, const int* __restrict__ clist_m,
    const int* __restrict__ mcnt_m, float* __restrict__ maccm,
    const float* __restrict__ vox_l, const int* __restrict__ clist_l,
    const int* __restrict__ mcnt_l, float* __restrict__ maccl,
    const int* __restrict__ Utp) {
  int bid = blockIdx.x;
  const float* vox; const int *clist, *mcnt; float* dest; int rb;
  if (bid < NHT) { vox=vox_m; clist=clist_m; mcnt=mcnt_m; dest=maccm; rb=bid; }
  else           { vox=vox_l; clist=clist_l; mcnt=mcnt_l; dest=maccl; rb=bid-NHT; }
  int idx = rb * BLK + threadIdx.x;
  int r = idx >> 4;
  int q = idx & 15;
  if (r >= *Utp) return;
  int m = mcnt[r];
  float a0=0.f, a1=0.f, a2=0.f, a3=0.f;
  for (int t = 0; t < m; t++) {
    int cr = clist[(size_t)r*64 + t];
    float4 v = *(const float4*)&vox[(size_t)cr*64 + q*4];
    a0 += v.x; a1 += v.y; a2 += v.z; a3 += v.w;
  }
  float inv = 1.0f / (float)max(m, 1);
  float4 o = {a0*inv, a1*inv, a2*inv, a3*inv};
  *(float4*)&dest[(size_t)r*64 + q*4] = o;
}

// ---- final: vf tail zero + coors + merged compose (one kernel) -------------
__global__ __launch_bounds__(BLK) void k_fin_all(const int* __restrict__ uniq,
    const int* __restrict__ Up, const float* __restrict__ maccm,
    const float* __restrict__ maccl, float* __restrict__ vf,
    float* __restrict__ mg, float* __restrict__ coors) {
  int idx = blockIdx.x * BLK + threadIdx.x;
  int r = idx >> 5;
  int q = idx & 31;
  if (r >= NPTS) return;
  int U = *Up;
  float4 v = {0.f, 0.f, 0.f, 0.f};
  if (r < U)
    v = (q < 16) ? *(const float4*)&maccm[(size_t)r*64 + q*4]
                 : *(const float4*)&maccl[(size_t)r*64 + (q-16)*4];
  *(float4*)&mg[(size_t)r*128 + q*4] = v;
  if (r >= U) {
    float4 z = {0.f, 0.f, 0.f, 0.f};
    *(float4*)&vf[(size_t)r*128 + q*4] = z;
  }
  if (q == 0) {
    float4 co;
    if (r < U) {
      int lin = uniq[r];
      int x = lin % TGX; int t = lin / TGX;
      int y = t % TGY;   t /= TGY;
      int z = t % TGZ;   int b = t / TGZ;
      co.x = (float)b; co.y = (float)z; co.z = (float)y; co.w = (float)x;
    } else {
      co.x = -1.f; co.y = -1.f; co.z = -1.f; co.w = -1.f;
    }
    *(float4*)&coors[(size_t)r*4] = co;
  }
}

extern "C" void kernel_launch(void* const* d_in, const int* in_sizes, int n_in,
                              void* d_out, int out_size, void* d_ws, size_t ws_size,
                              hipStream_t stream) {
  const float* pts = (const float*)d_in[0];

  float* out = (float*)d_out;
  float* vf = out;                              // N x 128 (final vf)
  float* mg = out + (size_t)NPTS * 128;         // N x 128 (Y2_top, then merged)
  float* co = out + (size_t)NPTS * 256;         // N x 4   (coors)

  char* w = (char*)d_ws;
  size_t off = 0;
  auto alloc = [&](size_t bytes) -> void* {
    void* p = w + off;
    off = (off + bytes + 1023) & ~(size_t)1023;
    return p;
  };
  int*    cnt_t   = (int*)alloc(((size_t)G_TOPC + G_MEDC + G_LOWC) * 4);
  int*    cnt_m   = cnt_t + G_TOPC;
  int*    cnt_l   = cnt_t + G_TOPC + G_MEDC;
  int*    rank_t  = (int*)alloc((size_t)G_TOPC * 4);
  int*    rank_m  = (int*)alloc((size_t)G_MEDC * 4);
  int*    rank_l  = (int*)alloc((size_t)G_LOWC * 4);
  int*    uniq_t  = (int*)alloc((size_t)G_TOPC * 4);
  int*    uniq_m  = (int*)alloc((size_t)NPTS * 4);
  int*    uniq_l  = (int*)alloc((size_t)NPTS * 4);
  int*    woff_t  = (int*)alloc((size_t)G_TOPC * 4);
  int*    woff_m  = (int*)alloc((size_t)NPTS * 4);
  int*    woff_l  = (int*)alloc((size_t)NPTS * 4);
  float4* srt_t   = (float4*)alloc((size_t)NPTS * 16);
  float4* srt_m   = (float4*)alloc((size_t)NPTS * 16);
  float4* srt_l   = (float4*)alloc((size_t)NPTS * 16);
  int*    jr_t    = (int*)alloc((size_t)NPTS * 4);
  int*    jr_m    = (int*)alloc((size_t)NPTS * 4);
  int*    jr_l    = (int*)alloc((size_t)NPTS * 4);
  float4* vm_t    = (float4*)alloc((size_t)G_TOPC * 16);
  float4* vm_m    = (float4*)alloc((size_t)NPTS * 16);
  float4* vm_l    = (float4*)alloc((size_t)NPTS * 16);
  float*  segt_t  = (float*)alloc((size_t)G_TOPC * 64 * 4);
  float*  segt_m  = (float*)alloc((size_t)NPTS * 32 * 4);
  float*  segt_l  = (float*)alloc((size_t)NPTS * 32 * 4);
  float*  vox_m   = (float*)alloc((size_t)NPTS * 64 * 4);
  float*  vox_l   = (float*)alloc((size_t)NPTS * 64 * 4);
  float*  Y2_m    = (float*)alloc((size_t)NPTS * 64 * 4);
  float*  Y2_l    = (float*)alloc((size_t)NPTS * 64 * 4);
  int*    clist_m = (int*)alloc((size_t)G_TOPC * 64 * 4);
  int*    clist_l = (int*)alloc((size_t)G_TOPC * 64 * 4);
  int*    mcnt_m  = (int*)alloc((size_t)G_TOPC * 4);
  int*    mcnt_l  = (int*)alloc((size_t)G_TOPC * 4);
  float*  maccm   = (float*)alloc((size_t)G_TOPC * 64 * 4);
  float*  maccl   = (float*)alloc((size_t)G_TOPC * 64 * 4);
  float*  part1_t = (float*)alloc((size_t)ST1BLKS * 128 * 4);
  float*  part1_m = (float*)alloc((size_t)ST1BLKS * 64 * 4);
  float*  part1_l = (float*)alloc((size_t)ST1BLKS * 64 * 4);
  float*  part2_t = (float*)alloc((size_t)Y2BLKS * 256 * 4);
  float*  part2_m = (float*)alloc((size_t)Y2BLKS * 128 * 4);
  float*  part2_l = (float*)alloc((size_t)Y2BLKS * 128 * 4);
  float*  coef    = (float*)alloc(6 * 256 * 4);
  int2*   bsum    = (int2*)alloc(1024 * 8);
  int*    Ut      = (int*)alloc(64);
  int*    Um      = (int*)alloc(64);
  int*    Ul      = (int*)alloc(64);
  (void)in_sizes; (void)n_in; (void)out_size; (void)ws_size;

  auto mkSP = [&](int scaleIdx) -> SP {
    SP s{};
    if (scaleIdx == 0) {
      s.srt = srt_t; s.jr = jr_t; s.vm = vm_t;
      s.W1 = (const float*)d_in[2];  s.g1 = (const float*)d_in[3];
      s.b1 = (const float*)d_in[4];  s.W2 = (const float*)d_in[5];
      s.g2 = (const float*)d_in[6];  s.b2 = (const float*)d_in[7];
      s.cnt = cnt_t; s.uniq = uniq_t; s.woff = woff_t; s.U = Ut;
      s.segt = segt_t; s.part1 = part1_t; s.part2 = part2_t;
      s.coef1 = coef + 0*256; s.coef2 = coef + 1*256;
      s.Y2 = mg; s.hout = vf;
      s.C1 = 64; s.segstride = G_TOPC;
      s.gx = 176; s.gy = 200; s.gz = 1; s.vx = 0.4f; s.vy = 0.4f; s.vz = 4.0f;
    } else if (scaleIdx == 1) {
      s.srt = srt_m; s.jr = jr_m; s.vm = vm_m;
      s.W1 = (const float*)d_in[8];  s.g1 = (const float*)d_in[9];
      s.b1 = (const float*)d_in[10]; s.W2 = (const float*)d_in[11];
      s.g2 = (const float*)d_in[12]; s.b2 = (const float*)d_in[13];
      s.cnt = cnt_m; s.uniq = uniq_m; s.woff = woff_m; s.U = Um;
      s.segt = segt_m; s.part1 = part1_m; s.part2 = part2_m;
      s.coef1 = coef + 2*256; s.coef2 = coef + 3*256;
      s.Y2 = Y2_m; s.hout = vox_m;
      s.C1 = 32; s.segstride = NPTS;
      s.gx = 352; s.gy = 400; s.gz = 2; s.vx = 0.2f; s.vy = 0.2f; s.vz = 2.0f;
    } else {
      s.srt = srt_l; s.jr = jr_l; s.vm = vm_l;
      s.W1 = (const float*)d_in[14]; s.g1 = (const float*)d_in[15];
      s.b1 = (const float*)d_in[16]; s.W2 = (const float*)d_in[17];
      s.g2 = (const float*)d_in[18]; s.b2 = (const float*)d_in[19];
      s.cnt = cnt_l; s.uniq = uniq_l; s.woff = woff_l; s.U = Ul;
      s.segt = segt_l; s.part1 = part1_l; s.part2 = part2_l;
      s.coef1 = coef + 4*256; s.coef2 = coef + 5*256;
      s.Y2 = Y2_l; s.hout = vox_l;
      s.C1 = 32; s.segstride = NPTS;
      s.gx = 704; s.gy = 800; s.gz = 4; s.vx = 0.1f; s.vy = 0.1f; s.vz = 1.0f;
    }
    return s;
  };
  SP spT = mkSP(0), spM = mkSP(1), spL = mkSP(2);

  // ---- batched voxelization front-end ----
  (void)hipMemsetAsync(cnt_t, 0, ((size_t)G_TOPC + G_MEDC + G_LOWC) * 4, stream);
  k_count3<<<NPTS/BLK, BLK, 0, stream>>>(pts, cnt_t, cnt_m, cnt_l);
  k_scan1_all<<<NB_T + NB_M + NB_L, BLK, 0, stream>>>(cnt_t, cnt_m, cnt_l, bsum);
  k_scan2_all<<<1, 1024, 0, stream>>>(bsum, Ut, Um, Ul);
  k_scan3_all<<<NB_T + NB_M + NB_L, BLK, 0, stream>>>(cnt_t, cnt_m, cnt_l, bsum,
      rank_t, rank_m, rank_l, uniq_t, uniq_m, uniq_l, woff_t, woff_m, woff_l);
  k_clist_all<<<2*NCL, BLK, 0, stream>>>(uniq_t, Ut,
      cnt_m, rank_m, clist_m, mcnt_m, cnt_l, rank_l, clist_l, mcnt_l);
  k_scatter3<<<NPTS/BLK, BLK, 0, stream>>>(pts,
      rank_t, woff_t, srt_t, jr_t,
      rank_m, woff_m, srt_m, jr_m,
      rank_l, woff_l, srt_l, jr_l);
  k_vox13<<<NBVT + NBVM + NBVL, BLK, 0, stream>>>(
      srt_t, uniq_t, cnt_t, woff_t, Ut, vm_t,
      srt_m, uniq_m, cnt_m, woff_m, Um, vm_m,
      srt_l, uniq_l, cnt_l, woff_l, Ul, vm_l);

  // ---- batched VFE pipeline (all scales per stage) ----
  k_stats1_all<<<3*ST1BLKS, BLK, 0, stream>>>(spT, spM, spL);
  k_partcoef1_all<<<128, BLK, 0, stream>>>(spT, spM, spL);
  k_hsegT_all<<<NHT + 2*NHM, BLK, 0, stream>>>(spT, spM, spL);
  k_y2t_all<<<3*Y2BLKS, BLK, 0, stream>>>(spT, spM, spL);
  k_partcoef2_all<<<256, BLK, 0, stream>>>(spT, spM, spL);
  k_hseg2_all<<<NJT + 2*NJM, BLK, 0, stream>>>(spT, spM, spL);

  // ---- merges + final outputs ----
  k_merge2_all<<<2*NHT, BLK, 0, stream>>>(vox_m, clist_m, mcnt_m, maccm,
      vox_l, clist_l, mcnt_l, maccl, Ut);
  k_fin_all<<<(NPTS*32)/BLK, BLK, 0, stream>>>(uniq_t, Ut, maccm, maccl,
      vf, mg, co);
}

// Round 9
// 805.818 us; speedup vs baseline: 1.0738x; 1.0738x over previous
//
#include <hip/hip_runtime.h>
#include <cstdint>
#include <cstddef>

#define NPTS 262144
#define BLK 256
#define TGX 176
#define TGY 200
#define TGZ 1

#define G_TOPC 70400
#define G_MEDC 1126400
#define G_LOWC 4505600

#define SCAN_ITEMS 32
#define SCAN_CHUNK (BLK*SCAN_ITEMS)
// batched scan block counts / bsum offsets (disjoint: [0,9) [16,154) [160,710))
#define NB_T 9
#define NB_M 138
#define NB_L 550
#define BO_T 0
#define BO_M 16
#define BO_L 160
// vox13 block split
#define NBVT (G_TOPC/BLK)      // 275
#define NBVM (NPTS/BLK)        // 1024
#define NBVL (NPTS/BLK)        // 1024

#define Y2B (NPTS/128)         // 2048 blocks per scale (128-row tiles)
#define ST1BLKS 256            // stats1 blocks per scale (1024 rows each)
// batched per-scale stage grids
#define NHT 4400               // G_TOPC*16/BLK
#define NHM 8192               // NPTS*8/BLK
#define NJT 8800               // G_TOPC*32/BLK
#define NJM 16384              // NPTS*16/BLK
#define NCL 275                // G_TOPC/BLK (ceil)

// ---------------- per-scale parameter pack ----------------
struct SP {
  const float4* srt; const int* jr; const float4* vm;
  const float* W1; const float* W2;
  const float* g1; const float* b1; const float* g2; const float* b2;
  const int* cnt; const int* uniq; const int* woff; const int* U;
  float* segt; float* part1; float* part2;
  float* coef1; float* coef2; float* Y2; float* hout;
  int C1; int segstride; int gx, gy, gz; float vx, vy, vz;
};

// ---------------- voxel coord helpers ----------------
__device__ __forceinline__ void pcoords(float x, float y, float z,
    float vx, float vy, float vz, int gx, int gy, int gz,
    int& cx, int& cy, int& cz) {
  cx = (int)floorf((x - 0.0f)  / vx);
  cy = (int)floorf((y + 40.0f) / vy);
  cz = (int)floorf((z + 3.0f)  / vz);
  cx = min(max(cx, 0), gx - 1);
  cy = min(max(cy, 0), gy - 1);
  cz = min(max(cz, 0), gz - 1);
}

__device__ __forceinline__ int lin3(float b, float x, float y, float z,
    float vx, float vy, float vz, int gx, int gy, int gz) {
  int cx, cy, cz; pcoords(x, y, z, vx, vy, vz, gx, gy, gz, cx, cy, cz);
  return (((int)b * gz + cz) * gy + cy) * gx + cx;
}

// f-vector (10 features) — identical expression everywhere y1 is recomputed.
__device__ __forceinline__ void build_f(float4 p, float4 vm,
    float vx, float vy, float vz, int gx, int gy, int gz, float* f) {
  int cx, cy, cz; pcoords(p.x, p.y, p.z, vx, vy, vz, gx, gy, gz, cx, cy, cz);
  f[0] = p.x; f[1] = p.y; f[2] = p.z; f[3] = p.w;
  f[4] = p.x - vm.x;
  f[5] = p.y - vm.y;
  f[6] = p.z - vm.z;
  f[7] = p.x - (0.0f   + (cx + 0.5f)*vx);
  f[8] = p.y - (-40.0f + (cy + 0.5f)*vy);
  f[9] = p.z - (-3.0f  + (cz + 0.5f)*vz);
}

// ---------------- batched dense count (all 3 scales) ----------------
__global__ __launch_bounds__(BLK) void k_count3(const float* __restrict__ pts,
    int* __restrict__ ct, int* __restrict__ cm, int* __restrict__ cl) {
  int i = blockIdx.x * BLK + threadIdx.x;
  if (i >= NPTS) return;
  float b = pts[i*5+0], x = pts[i*5+1], y = pts[i*5+2], z = pts[i*5+3];
  atomicAdd(&ct[lin3(b,x,y,z, 0.4f,0.4f,4.0f, 176,200,1)], 1);
  atomicAdd(&cm[lin3(b,x,y,z, 0.2f,0.2f,2.0f, 352,400,2)], 1);
  atomicAdd(&cl[lin3(b,x,y,z, 0.1f,0.1f,1.0f, 704,800,4)], 1);
}

// ---------------- batched scans ----------------
__global__ __launch_bounds__(BLK) void k_scan1_all(const int* __restrict__ ct,
    const int* __restrict__ cm, const int* __restrict__ cl,
    int2* __restrict__ bsum) {
  int bid = blockIdx.x;
  const int* cnt; int G, bo, cb;
  if (bid < NB_T)            { cnt = ct; G = G_TOPC; bo = BO_T; cb = bid; }
  else if (bid < NB_T+NB_M)  { cnt = cm; G = G_MEDC; bo = BO_M; cb = bid - NB_T; }
  else                       { cnt = cl; G = G_LOWC; bo = BO_L; cb = bid - NB_T - NB_M; }
  int base = cb * SCAN_CHUNK + threadIdx.x * SCAN_ITEMS;
  int so = 0, sp = 0;
  #pragma unroll
  for (int k = 0; k < SCAN_ITEMS; k++) {
    int j = base + k;
    if (j < G) { int c = cnt[j]; if (c > 0) { so++; sp += c; } }
  }
  __shared__ int sho[BLK], shp[BLK];
  sho[threadIdx.x] = so; shp[threadIdx.x] = sp; __syncthreads();
  for (int off = BLK/2; off > 0; off >>= 1) {
    if (threadIdx.x < off) {
      sho[threadIdx.x] += sho[threadIdx.x + off];
      shp[threadIdx.x] += shp[threadIdx.x + off];
    }
    __syncthreads();
  }
  if (threadIdx.x == 0) { int2 v; v.x = sho[0]; v.y = shp[0]; bsum[bo + cb] = v; }
}

__device__ void scan_pass(int2* bsum, int off, int nb, int* U,
                          int* so, int* sp) {
  int t = threadIdx.x;
  int vo = 0, vp = 0;
  if (t < nb) { int2 v = bsum[off + t]; vo = v.x; vp = v.y; }
  so[t] = vo; sp[t] = vp; __syncthreads();
  for (int o = 1; o < 1024; o <<= 1) {
    int ao = (t >= o) ? so[t - o] : 0;
    int ap = (t >= o) ? sp[t - o] : 0;
    __syncthreads();
    so[t] += ao; sp[t] += ap;
    __syncthreads();
  }
  if (t < nb) { int2 e; e.x = so[t] - vo; e.y = sp[t] - vp; bsum[off + t] = e; }
  if (t == 0) *U = so[1023];
  __syncthreads();
}

__global__ __launch_bounds__(1024) void k_scan2_all(int2* __restrict__ bsum,
    int* __restrict__ Ut, int* __restrict__ Um, int* __restrict__ Ul) {
  __shared__ int so[1024], sp[1024];
  scan_pass(bsum, BO_T, NB_T, Ut, so, sp);
  scan_pass(bsum, BO_M, NB_M, Um, so, sp);
  scan_pass(bsum, BO_L, NB_L, Ul, so, sp);
}

__global__ __launch_bounds__(BLK) void k_scan3_all(const int* __restrict__ ct,
    const int* __restrict__ cm, const int* __restrict__ cl,
    const int2* __restrict__ bsum,
    int* __restrict__ rkt, int* __restrict__ rkm, int* __restrict__ rkl,
    int* __restrict__ uqt, int* __restrict__ uqm, int* __restrict__ uql,
    int* __restrict__ wot, int* __restrict__ wom, int* __restrict__ wol) {
  int bid = blockIdx.x;
  const int* cnt; int G, bo, cb; int *rank, *uniq, *woff;
  if (bid < NB_T)           { cnt=ct; G=G_TOPC; bo=BO_T; cb=bid;            rank=rkt; uniq=uqt; woff=wot; }
  else if (bid < NB_T+NB_M) { cnt=cm; G=G_MEDC; bo=BO_M; cb=bid-NB_T;       rank=rkm; uniq=uqm; woff=wom; }
  else                      { cnt=cl; G=G_LOWC; bo=BO_L; cb=bid-NB_T-NB_M;  rank=rkl; uniq=uql; woff=wol; }
  int base = cb * SCAN_CHUNK + threadIdx.x * SCAN_ITEMS;
  int so = 0, sp = 0;
  #pragma unroll
  for (int k = 0; k < SCAN_ITEMS; k++) {
    int j = base + k;
    if (j < G) { int c = cnt[j]; if (c > 0) { so++; sp += c; } }
  }
  __shared__ int sho[BLK], shp[BLK];
  sho[threadIdx.x] = so; shp[threadIdx.x] = sp; __syncthreads();
  for (int off = 1; off < BLK; off <<= 1) {
    int ao = (threadIdx.x >= off) ? sho[threadIdx.x - off] : 0;
    int ap = (threadIdx.x >= off) ? shp[threadIdx.x - off] : 0;
    __syncthreads();
    sho[threadIdx.x] += ao; shp[threadIdx.x] += ap;
    __syncthreads();
  }
  int2 bb = bsum[bo + cb];
  int ro = bb.x + sho[threadIdx.x] - so;
  int po = bb.y + shp[threadIdx.x] - sp;
  for (int k = 0; k < SCAN_ITEMS; k++) {
    int j = base + k;
    if (j < G) {
      int c = cnt[j];
      if (c > 0) { rank[j] = ro; uniq[ro] = j; woff[ro] = po; ro++; po += c; }
    }
  }
}

// ---------------- batched counting-sort scatter ----------------
__global__ __launch_bounds__(BLK) void k_scatter3(const float* __restrict__ pts,
    const int* __restrict__ rkt, int* __restrict__ wot, float4* __restrict__ st, int* __restrict__ jt,
    const int* __restrict__ rkm, int* __restrict__ wom, float4* __restrict__ sm, int* __restrict__ jm,
    const int* __restrict__ rkl, int* __restrict__ wol, float4* __restrict__ sl, int* __restrict__ jl) {
  int i = blockIdx.x * BLK + threadIdx.x;
  if (i >= NPTS) return;
  float b = pts[i*5+0], x = pts[i*5+1], y = pts[i*5+2], z = pts[i*5+3], it = pts[i*5+4];
  float4 p; p.x = x; p.y = y; p.z = z; p.w = it;
  {
    int r = rkt[lin3(b,x,y,z, 0.4f,0.4f,4.0f, 176,200,1)];
    int j = atomicAdd(&wot[r], 1); st[j] = p; jt[j] = r;
  }
  {
    int r = rkm[lin3(b,x,y,z, 0.2f,0.2f,2.0f, 352,400,2)];
    int j = atomicAdd(&wom[r], 1); sm[j] = p; jm[j] = r;
  }
  {
    int r = rkl[lin3(b,x,y,z, 0.1f,0.1f,1.0f, 704,800,4)];
    int j = atomicAdd(&wol[r], 1); sl[j] = p; jl[j] = r;
  }
}

// ---------------- batched per-voxel xyz means ----------------
__global__ __launch_bounds__(BLK) void k_vox13(
    const float4* __restrict__ st, const int* __restrict__ uqt, const int* __restrict__ ct,
    const int* __restrict__ wot, const int* __restrict__ Ut, float4* __restrict__ vt,
    const float4* __restrict__ sm, const int* __restrict__ uqm, const int* __restrict__ cm,
    const int* __restrict__ wom, const int* __restrict__ Um, float4* __restrict__ vm,
    const float4* __restrict__ sl, const int* __restrict__ uql, const int* __restrict__ cl,
    const int* __restrict__ wol, const int* __restrict__ Ul, float4* __restrict__ vl) {
  int bid = blockIdx.x;
  const float4* srt; const int *uniq, *cnt, *woff, *Up; float4* vmean; int r;
  if (bid < NBVT)           { r = bid*BLK + threadIdx.x;           srt=st; uniq=uqt; cnt=ct; woff=wot; Up=Ut; vmean=vt; }
  else if (bid < NBVT+NBVM) { r = (bid-NBVT)*BLK + threadIdx.x;    srt=sm; uniq=uqm; cnt=cm; woff=wom; Up=Um; vmean=vm; }
  else                      { r = (bid-NBVT-NBVM)*BLK + threadIdx.x; srt=sl; uniq=uql; cnt=cl; woff=wol; Up=Ul; vmean=vl; }
  if (r >= *Up) return;
  int lin = uniq[r];
  int len = cnt[lin];
  int base = woff[r] - len;
  float sx = 0.f, sy = 0.f, sz = 0.f;
  for (int k = 0; k < len; k++) {
    float4 p = srt[base + k];
    sx += p.x; sy += p.y; sz += p.z;
  }
  float il = 1.0f / (float)len;
  float4 o; o.x = sx*il; o.y = sy*il; o.z = sz*il; o.w = il;
  vmean[r] = o;
}

// ------- fused y1-compute + column sum/sumsq partials (all scales) ----------
__global__ __launch_bounds__(BLK) void k_stats1_all(SP a, SP b, SP c) {
  int s = blockIdx.x >> 8;
  int blk = blockIdx.x & 255;
  SP sp = (s == 0) ? a : ((s == 1) ? b : c);
  const int C1 = sp.C1;
  __shared__ float w[640];
  __shared__ float wsum[4][64], wsq[4][64];
  for (int t = threadIdx.x; t < 10*C1; t += BLK) w[t] = sp.W1[t];
  __syncthreads();
  float f[4][10];
  #pragma unroll
  for (int k = 0; k < 4; k++) {
    int i = blk*1024 + k*BLK + threadIdx.x;
    float4 p = sp.srt[i];
    float4 vmn = sp.vm[sp.jr[i]];
    build_f(p, vmn, sp.vx, sp.vy, sp.vz, sp.gx, sp.gy, sp.gz, f[k]);
  }
  int wv = threadIdx.x >> 6;
  int lane = threadIdx.x & 63;
  for (int o = 0; o < C1; o += 4) {
    float sacc[4] = {0,0,0,0}, qacc[4] = {0,0,0,0};
    #pragma unroll
    for (int k = 0; k < 4; k++) {
      float a0=0.f, a1=0.f, a2=0.f, a3=0.f;
      #pragma unroll
      for (int d = 0; d < 10; d++) {
        float fv = f[k][d];
        const float* wr = &w[d*C1 + o];
        a0 = fmaf(fv, wr[0], a0); a1 = fmaf(fv, wr[1], a1);
        a2 = fmaf(fv, wr[2], a2); a3 = fmaf(fv, wr[3], a3);
      }
      sacc[0] += a0; sacc[1] += a1; sacc[2] += a2; sacc[3] += a3;
      qacc[0] += a0*a0; qacc[1] += a1*a1; qacc[2] += a2*a2; qacc[3] += a3*a3;
    }
    #pragma unroll
    for (int m = 1; m < 64; m <<= 1) {
      #pragma unroll
      for (int e = 0; e < 4; e++) {
        sacc[e] += __shfl_xor(sacc[e], m);
        qacc[e] += __shfl_xor(qacc[e], m);
      }
    }
    if (lane == 0) {
      #pragma unroll
      for (int e = 0; e < 4; e++) { wsum[wv][o+e] = sacc[e]; wsq[wv][o+e] = qacc[e]; }
    }
  }
  __syncthreads();
  if (threadIdx.x < C1) {
    int ch = threadIdx.x;
    float sv = wsum[0][ch] + wsum[1][ch] + wsum[2][ch] + wsum[3][ch];
    float qv = wsq[0][ch] + wsq[1][ch] + wsq[2][ch] + wsq[3][ch];
    sp.part1[(size_t)blk*2*C1 + ch]      = sv;
    sp.part1[(size_t)blk*2*C1 + C1 + ch] = qv;
  }
}

// ---- reduce per-block partials -> BN coef (stage 1: C1; stage 2: C2) -------
__device__ __forceinline__ void partcoef_body(const float* part, int NB, int C,
    int ch, const float* g, const float* b, float* coef) {
  float s = 0.f, q = 0.f;
  for (int bk = threadIdx.x; bk < NB; bk += BLK) {
    s += part[(size_t)bk*2*C + ch];
    q += part[(size_t)bk*2*C + C + ch];
  }
  __shared__ float ss[BLK], sq[BLK];
  ss[threadIdx.x] = s; sq[threadIdx.x] = q; __syncthreads();
  for (int off = BLK/2; off > 0; off >>= 1) {
    if (threadIdx.x < off) {
      ss[threadIdx.x] += ss[threadIdx.x + off];
      sq[threadIdx.x] += sq[threadIdx.x + off];
    }
    __syncthreads();
  }
  if (threadIdx.x == 0) {
    float mu  = ss[0] * (1.0f / NPTS);
    float var = sq[0] * (1.0f / NPTS) - mu*mu;
    float sc  = g[ch] * (1.0f / sqrtf(var + 1e-3f));
    coef[ch]     = sc;
    coef[C + ch] = fmaf(-mu, sc, b[ch]);
  }
}

__global__ __launch_bounds__(BLK) void k_partcoef1_all(SP a, SP b, SP c) {
  int bid = blockIdx.x; SP sp; int ch;
  if (bid < 64)      { sp = a; ch = bid; }
  else if (bid < 96) { sp = b; ch = bid - 64; }
  else               { sp = c; ch = bid - 96; }
  if (ch >= sp.C1) return;
  partcoef_body(sp.part1, ST1BLKS, sp.C1, ch, sp.g1, sp.b1, sp.coef1);
}

__global__ __launch_bounds__(BLK) void k_partcoef2_all(SP a, SP b, SP c) {
  int bid = blockIdx.x; SP sp; int ch;
  if (bid < 128)      { sp = a; ch = bid; }
  else if (bid < 192) { sp = b; ch = bid - 128; }
  else                { sp = c; ch = bid - 192; }
  if (ch >= 2*sp.C1) return;
  partcoef_body(sp.part2, Y2B, 2*sp.C1, ch, sp.g2, sp.b2, sp.coef2);
}

// ---- layer-1 voxel means of BN+ReLU(y1), y1 recomputed (all scales) --------
__global__ __launch_bounds__(BLK) void k_hsegT_all(SP a, SP b, SP c) {
  int bid = blockIdx.x; SP sp; int rb;
  if (bid < NHT)           { sp = a; rb = bid; }
  else if (bid < NHT+NHM)  { sp = b; rb = bid - NHT; }
  else                     { sp = c; rb = bid - NHT - NHM; }
  const int C1 = sp.C1;
  const int qsh = (C1 == 64) ? 4 : 3;
  __shared__ float w[640];
  __shared__ float sc[64], sb[64];
  for (int t = threadIdx.x; t < 10*C1; t += BLK) w[t] = sp.W1[t];
  for (int t = threadIdx.x; t < C1; t += BLK) { sc[t] = sp.coef1[t]; sb[t] = sp.coef1[C1 + t]; }
  __syncthreads();
  int tid = rb * BLK + threadIdx.x;
  int r = tid >> qsh;
  int q = tid & ((1 << qsh) - 1);
  if (r >= *sp.U) return;
  int lin = sp.uniq[r];
  int len = sp.cnt[lin];
  int base = sp.woff[r] - len;
  float4 vmn = sp.vm[r];
  int c0 = q * 4;
  float s0 = sc[c0+0], s1 = sc[c0+1], s2 = sc[c0+2], s3 = sc[c0+3];
  float o0 = sb[c0+0], o1 = sb[c0+1], o2 = sb[c0+2], o3 = sb[c0+3];
  float a0=0.f, a1=0.f, a2=0.f, a3=0.f;
  for (int k = 0; k < len; k++) {
    float4 p = sp.srt[base + k];
    float f[10];
    build_f(p, vmn, sp.vx, sp.vy, sp.vz, sp.gx, sp.gy, sp.gz, f);
    float y0=0.f, y1=0.f, y2=0.f, y3=0.f;
    #pragma unroll
    for (int d = 0; d < 10; d++) {
      float fv = f[d];
      const float* wr = &w[d*C1 + c0];
      y0 = fmaf(fv, wr[0], y0); y1 = fmaf(fv, wr[1], y1);
      y2 = fmaf(fv, wr[2], y2); y3 = fmaf(fv, wr[3], y3);
    }
    a0 += fmaxf(fmaf(y0, s0, o0), 0.f);
    a1 += fmaxf(fmaf(y1, s1, o1), 0.f);
    a2 += fmaxf(fmaf(y2, s2, o2), 0.f);
    a3 += fmaxf(fmaf(y3, s3, o3), 0.f);
  }
  float il = 1.0f / (float)len;
  sp.segt[(size_t)(c0+0)*sp.segstride + r] = a0*il;
  sp.segt[(size_t)(c0+1)*sp.segstride + r] = a1*il;
  sp.segt[(size_t)(c0+2)*sp.segstride + r] = a2*il;
  sp.segt[(size_t)(c0+3)*sp.segstride + r] = a3*il;
}

// ------- layer 2: 128x64-tile GEMM, K-chunked, compile-time bodies ----------
#define FMA4(ACC, AV, BV) { (ACC).x = fmaf((AV), (BV).x, (ACC).x); \
  (ACC).y = fmaf((AV), (BV).y, (ACC).y); \
  (ACC).z = fmaf((AV), (BV).z, (ACC).z); \
  (ACC).w = fmaf((AV), (BV).w, (ACC).w); }

template<int C1, int NKC, int NPAN>
__device__ __forceinline__ void y2t_body(const SP& sp, int blk,
    float* At, float* Bp, int* jrl) {
  constexpr int C2 = 2*C1;
  constexpr int MT = 128;
  constexpr int NT = 64;
  constexpr int KC = 64;
  const int tid  = threadIdx.x;
  const int base = blk * MT;
  float* w1A = Bp;                 // 10*C1 floats (alias, dead after At chunk 0)
  float* fA  = Bp + 10*C1;         // 128*11 floats

  for (int t = tid; t < 10*C1; t += BLK) w1A[t] = sp.W1[t];
  if (tid < MT) {
    int jr = sp.jr[base + tid];
    jrl[tid] = jr;
    float4 p  = sp.srt[base + tid];
    float4 vmn = sp.vm[jr];
    float f[10];
    build_f(p, vmn, sp.vx, sp.vy, sp.vz, sp.gx, sp.gy, sp.gz, f);
    #pragma unroll
    for (int d = 0; d < 10; d++) fA[tid*11 + d] = f[d];
  }

  const int w      = tid >> 6;
  const int lane   = tid & 63;
  const int colg   = lane & 15;
  const int rowsub = lane >> 4;
  const int rowg   = w*4 + rowsub;      // 0..15
  const int arow   = rowg*8;

  float4 acc[NPAN][8];
  #pragma unroll
  for (int p = 0; p < NPAN; p++)
    #pragma unroll
    for (int rr = 0; rr < 8; rr++) acc[p][rr] = {0.f, 0.f, 0.f, 0.f};

  #pragma unroll
  for (int kc = 0; kc < NKC; kc++) {
    const int c0base = kc*64;
    __syncthreads();   // prologue visible (kc=0) / prior accumulate done
    // y1 quads of this chunk (channels < C1), computed from fA + w1A
    const int nyq = (C1 - c0base) > 0 ? ((C1 - c0base) >> 2 < 16 ? (C1 - c0base) >> 2 : 16) : 0;
    for (int it = tid; it < nyq*MT; it += BLK) {
      int qq = it >> 7;
      int j  = it & 127;
      int c0 = c0base + qq*4;
      float y0=0.f, y1=0.f, y2=0.f, y3=0.f;
      #pragma unroll
      for (int d = 0; d < 10; d++) {
        float fv = fA[j*11 + d];
        const float* wr = &w1A[d*C1 + c0];
        y0 = fmaf(fv, wr[0], y0); y1 = fmaf(fv, wr[1], y1);
        y2 = fmaf(fv, wr[2], y2); y3 = fmaf(fv, wr[3], y3);
      }
      At[(qq*4+0)*MT + j] = fmaxf(fmaf(y0, sp.coef1[c0+0], sp.coef1[C1+c0+0]), 0.f);
      At[(qq*4+1)*MT + j] = fmaxf(fmaf(y1, sp.coef1[c0+1], sp.coef1[C1+c0+1]), 0.f);
      At[(qq*4+2)*MT + j] = fmaxf(fmaf(y2, sp.coef1[c0+2], sp.coef1[C1+c0+2]), 0.f);
      At[(qq*4+3)*MT + j] = fmaxf(fmaf(y3, sp.coef1[c0+3], sp.coef1[C1+c0+3]), 0.f);
    }
    // seg channels of this chunk (K-rows >= C1), gathered via jrl
    const int segstart = (c0base > C1) ? c0base : C1;
    const int nsc = c0base + 64 - segstart;
    for (int it = tid; it < nsc*MT; it += BLK) {
      int ci = it >> 7;
      int j  = it & 127;
      int kk = segstart + ci;
      At[(kk - c0base)*MT + j] = sp.segt[(size_t)(kk - C1)*sp.segstride + jrl[j]];
    }

    #pragma unroll
    for (int p = 0; p < NPAN; p++) {
      __syncthreads();   // At ready / prior panel compute done before Bp overwrite
      for (int it = tid; it < KC*(NT/4); it += BLK) {
        int k   = it >> 4;
        int cq4 = (it & 15) << 2;
        *(float4*)&Bp[k*NT + cq4] =
            *(const float4*)&sp.W2[(size_t)(c0base + k)*C2 + p*NT + cq4];
      }
      __syncthreads();
      #pragma unroll 8
      for (int k = 0; k < KC; k++) {
        float4 a0 = *(const float4*)&At[k*MT + arow];
        float4 a1 = *(const float4*)&At[k*MT + arow + 4];
        float4 bv = *(const float4*)&Bp[k*NT + colg*4];
        FMA4(acc[p][0], a0.x, bv); FMA4(acc[p][1], a0.y, bv);
        FMA4(acc[p][2], a0.z, bv); FMA4(acc[p][3], a0.w, bv);
        FMA4(acc[p][4], a1.x, bv); FMA4(acc[p][5], a1.y, bv);
        FMA4(acc[p][6], a1.z, bv); FMA4(acc[p][7], a1.w, bv);
      }
    }
  }

  // ---- write Y2 tile ----
  #pragma unroll
  for (int p = 0; p < NPAN; p++)
    #pragma unroll
    for (int rr = 0; rr < 8; rr++)
      *(float4*)&sp.Y2[(size_t)(base + arow + rr)*C2 + p*NT + colg*4] = acc[p][rr];

  // ---- fused per-block column sum/sumsq partials (reuse At as scratch) ----
  __syncthreads();
  float* red = At;                 // [32][C2+1]
  #pragma unroll
  for (int p = 0; p < NPAN; p++) {
    #pragma unroll
    for (int e = 0; e < 4; e++) {
      float sv = 0.f, qv = 0.f;
      #pragma unroll
      for (int rr = 0; rr < 8; rr++) {
        float v = (&acc[p][rr].x)[e];
        sv += v; qv += v*v;
      }
      red[rowg*(C2+1) + p*NT + colg*4 + e]        = sv;
      red[(16 + rowg)*(C2+1) + p*NT + colg*4 + e] = qv;
    }
  }
  __syncthreads();
  if (tid < C2) {
    float sv = 0.f, qv = 0.f;
    #pragma unroll 4
    for (int i = 0; i < 16; i++) {
      sv += red[i*(C2+1) + tid];
      qv += red[(16 + i)*(C2+1) + tid];
    }
    sp.part2[(size_t)blk*2*C2 + tid]      = sv;
    sp.part2[(size_t)blk*2*C2 + C2 + tid] = qv;
  }
}

__global__ __launch_bounds__(BLK) void k_y2t_all(SP a, SP b, SP c) {
  __shared__ float At[64*128];   // 32 KB
  __shared__ float Bp[64*64];    // 16 KB (prologue aliases live here)
  __shared__ int   jrl[128];
  int bid = blockIdx.x;
  if (bid < Y2B)        y2t_body<64,2,2>(a, bid, At, Bp, jrl);
  else if (bid < 2*Y2B) y2t_body<32,1,1>(b, bid - Y2B, At, Bp, jrl);
  else                  y2t_body<32,1,1>(c, bid - 2*Y2B, At, Bp, jrl);
}

// -------- layer-2 BN+ReLU + voxel mean (all scales) -------------------------
__global__ __launch_bounds__(BLK) void k_hseg2_all(SP a, SP b, SP c) {
  int bid = blockIdx.x; SP sp; int rb;
  if (bid < NJT)           { sp = a; rb = bid; }
  else if (bid < NJT+NJM)  { sp = b; rb = bid - NJT; }
  else                     { sp = c; rb = bid - NJT - NJM; }
  const int C = 2*sp.C1;
  const int qsh = (C == 128) ? 5 : 4;
  __shared__ float sc[128], sb[128];
  for (int t = threadIdx.x; t < C; t += BLK) { sc[t] = sp.coef2[t]; sb[t] = sp.coef2[C + t]; }
  __syncthreads();
  int tid = rb * BLK + threadIdx.x;
  int r = tid >> qsh;
  int q = tid & ((1 << qsh) - 1);
  if (r >= *sp.U) return;
  int lin = sp.uniq[r];
  int len = sp.cnt[lin];
  int base = sp.woff[r] - len;
  int c0 = q * 4;
  float s0 = sc[c0+0], s1 = sc[c0+1], s2 = sc[c0+2], s3 = sc[c0+3];
  float o0 = sb[c0+0], o1 = sb[c0+1], o2 = sb[c0+2], o3 = sb[c0+3];
  float a0=0.f, a1=0.f, a2=0.f, a3=0.f;
  for (int k = 0; k < len; k++) {
    float4 v = *(const float4*)&sp.Y2[(size_t)(base + k)*C + c0];
    a0 += fmaxf(fmaf(v.x, s0, o0), 0.f);
    a1 += fmaxf(fmaf(v.y, s1, o1), 0.f);
    a2 += fmaxf(fmaf(v.z, s2, o2), 0.f);
    a3 += fmaxf(fmaf(v.w, s3, o3), 0.f);
  }
  float il = 1.0f / (float)len;
  float4 o = {a0*il, a1*il, a2*il, a3*il};
  *(float4*)&sp.hout[(size_t)r*C + c0] = o;
}

// ------------- merge: per-parent child-rank lists (med+low batched) ---------
__global__ __launch_bounds__(BLK) void k_clist_all(const int* __restrict__ tuniq,
    const int* __restrict__ Utp,
    const int* __restrict__ cnt_m, const int* __restrict__ rank_m,
    int* __restrict__ clist_m, int* __restrict__ mcnt_m,
    const int* __restrict__ cnt_l, const int* __restrict__ rank_l,
    int* __restrict__ clist_l, int* __restrict__ mcnt_l) {
  int bid = blockIdx.x;
  const int *scnt, *srank; int *clist, *mcnt;
  int gx, gy, gz, f, rb;
  if (bid < NCL) { scnt=cnt_m; srank=rank_m; clist=clist_m; mcnt=mcnt_m;
                   gx=352; gy=400; gz=2; f=2; rb=bid; }
  else           { scnt=cnt_l; srank=rank_l; clist=clist_l; mcnt=mcnt_l;
                   gx=704; gy=800; gz=4; f=4; rb=bid-NCL; }
  int r = rb * BLK + threadIdx.x;
  if (r >= *Utp) return;
  int lin = tuniq[r];
  int x = lin % TGX; int t = lin / TGX;
  int y = t % TGY;   int b = t / TGY;   // TGZ == 1 so z == 0
  int m = 0;
  for (int cz = 0; cz < gz; cz++)
    for (int yy = y*f; yy < y*f + f; yy++)
      for (int xx = x*f; xx < x*f + f; xx++) {
        int cl = ((b*gz + cz)*gy + yy)*gx + xx;
        if (scnt[cl] > 0) clist[(size_t)r*64 + (m++)] = srank[cl];
      }
  mcnt[r] = m;
}

__global__ __launch_bounds__(BLK) void k_merge2_all(
    const float* __restrict__ vox_m, const int* __restrict__ clist_m,
    const int* __restrict__ mcnt_m, float* __restrict__ maccm,
    const float* __restrict__ vox_l, const int* __restrict__ clist_l,
    const int* __restrict__ mcnt_l, float* __restrict__ maccl,
    const int* __restrict__ Utp) {
  int bid = blockIdx.x;
  const float* vox; const int *clist, *mcnt; float* dest; int rb;
  if (bid < NHT) { vox=vox_m; clist=clist_m; mcnt=mcnt_m; dest=maccm; rb=bid; }
  else           { vox=vox_l; clist=clist_l; mcnt=mcnt_l; dest=maccl; rb=bid-NHT; }
  int idx = rb * BLK + threadIdx.x;
  int r = idx >> 4;
  int q = idx & 15;
  if (r >= *Utp) return;
  int m = mcnt[r];
  float a0=0.f, a1=0.f, a2=0.f, a3=0.f;
  for (int t = 0; t < m; t++) {
    int cr = clist[(size_t)r*64 + t];
    float4 v = *(const float4*)&vox[(size_t)cr*64 + q*4];
    a0 += v.x; a1 += v.y; a2 += v.z; a3 += v.w;
  }
  float inv = 1.0f / (float)max(m, 1);
  float4 o = {a0*inv, a1*inv, a2*inv, a3*inv};
  *(float4*)&dest[(size_t)r*64 + q*4] = o;
}

// ---- final: vf tail zero + coors + merged compose (one kernel) -------------
__global__ __launch_bounds__(BLK) void k_fin_all(const int* __restrict__ uniq,
    const int* __restrict__ Up, const float* __restrict__ maccm,
    const float* __restrict__ maccl, float* __restrict__ vf,
    float* __restrict__ mg, float* __restrict__ coors) {
  int idx = blockIdx.x * BLK + threadIdx.x;
  int r = idx >> 5;
  int q = idx & 31;
  if (r >= NPTS) return;
  int U = *Up;
  float4 v = {0.f, 0.f, 0.f, 0.f};
  if (r < U)
    v = (q < 16) ? *(const float4*)&maccm[(size_t)r*64 + q*4]
                 : *(const float4*)&maccl[(size_t)r*64 + (q-16)*4];
  *(float4*)&mg[(size_t)r*128 + q*4] = v;
  if (r >= U) {
    float4 z = {0.f, 0.f, 0.f, 0.f};
    *(float4*)&vf[(size_t)r*128 + q*4] = z;
  }
  if (q == 0) {
    float4 co;
    if (r < U) {
      int lin = uniq[r];
      int x = lin % TGX; int t = lin / TGX;
      int y = t % TGY;   t /= TGY;
      int z = t % TGZ;   int b = t / TGZ;
      co.x = (float)b; co.y = (float)z; co.z = (float)y; co.w = (float)x;
    } else {
      co.x = -1.f; co.y = -1.f; co.z = -1.f; co.w = -1.f;
    }
    *(float4*)&coors[(size_t)r*4] = co;
  }
}

extern "C" void kernel_launch(void* const* d_in, const int* in_sizes, int n_in,
                              void* d_out, int out_size, void* d_ws, size_t ws_size,
                              hipStream_t stream) {
  const float* pts = (const float*)d_in[0];

  float* out = (float*)d_out;
  float* vf = out;                              // N x 128 (final vf)
  float* mg = out + (size_t)NPTS * 128;         // N x 128 (Y2_top, then merged)
  float* co = out + (size_t)NPTS * 256;         // N x 4   (coors)

  char* w = (char*)d_ws;
  size_t off = 0;
  auto alloc = [&](size_t bytes) -> void* {
    void* p = w + off;
    off = (off + bytes + 1023) & ~(size_t)1023;
    return p;
  };
  int*    cnt_t   = (int*)alloc(((size_t)G_TOPC + G_MEDC + G_LOWC) * 4);
  int*    cnt_m   = cnt_t + G_TOPC;
  int*    cnt_l   = cnt_t + G_TOPC + G_MEDC;
  int*    rank_t  = (int*)alloc((size_t)G_TOPC * 4);
  int*    rank_m  = (int*)alloc((size_t)G_MEDC * 4);
  int*    rank_l  = (int*)alloc((size_t)G_LOWC * 4);
  int*    uniq_t  = (int*)alloc((size_t)G_TOPC * 4);
  int*    uniq_m  = (int*)alloc((size_t)NPTS * 4);
  int*    uniq_l  = (int*)alloc((size_t)NPTS * 4);
  int*    woff_t  = (int*)alloc((size_t)G_TOPC * 4);
  int*    woff_m  = (int*)alloc((size_t)NPTS * 4);
  int*    woff_l  = (int*)alloc((size_t)NPTS * 4);
  float4* srt_t   = (float4*)alloc((size_t)NPTS * 16);
  float4* srt_m   = (float4*)alloc((size_t)NPTS * 16);
  float4* srt_l   = (float4*)alloc((size_t)NPTS * 16);
  int*    jr_t    = (int*)alloc((size_t)NPTS * 4);
  int*    jr_m    = (int*)alloc((size_t)NPTS * 4);
  int*    jr_l    = (int*)alloc((size_t)NPTS * 4);
  float4* vm_t    = (float4*)alloc((size_t)G_TOPC * 16);
  float4* vm_m    = (float4*)alloc((size_t)NPTS * 16);
  float4* vm_l    = (float4*)alloc((size_t)NPTS * 16);
  float*  segt_t  = (float*)alloc((size_t)G_TOPC * 64 * 4);
  float*  segt_m  = (float*)alloc((size_t)NPTS * 32 * 4);
  float*  segt_l  = (float*)alloc((size_t)NPTS * 32 * 4);
  float*  vox_m   = (float*)alloc((size_t)NPTS * 64 * 4);
  float*  vox_l   = (float*)alloc((size_t)NPTS * 64 * 4);
  float*  Y2_m    = (float*)alloc((size_t)NPTS * 64 * 4);
  float*  Y2_l    = (float*)alloc((size_t)NPTS * 64 * 4);
  int*    clist_m = (int*)alloc((size_t)G_TOPC * 64 * 4);
  int*    clist_l = (int*)alloc((size_t)G_TOPC * 64 * 4);
  int*    mcnt_m  = (int*)alloc((size_t)G_TOPC * 4);
  int*    mcnt_l  = (int*)alloc((size_t)G_TOPC * 4);
  float*  maccm   = (float*)alloc((size_t)G_TOPC * 64 * 4);
  float*  maccl   = (float*)alloc((size_t)G_TOPC * 64 * 4);
  float*  part1_t = (float*)alloc((size_t)ST1BLKS * 128 * 4);
  float*  part1_m = (float*)alloc((size_t)ST1BLKS * 64 * 4);
  float*  part1_l = (float*)alloc((size_t)ST1BLKS * 64 * 4);
  float*  part2_t = (float*)alloc((size_t)Y2B * 256 * 4);
  float*  part2_m = (float*)alloc((size_t)Y2B * 128 * 4);
  float*  part2_l = (float*)alloc((size_t)Y2B * 128 * 4);
  float*  coef    = (float*)alloc(6 * 256 * 4);
  int2*   bsum    = (int2*)alloc(1024 * 8);
  int*    Ut      = (int*)alloc(64);
  int*    Um      = (int*)alloc(64);
  int*    Ul      = (int*)alloc(64);
  (void)in_sizes; (void)n_in; (void)out_size; (void)ws_size;

  auto mkSP = [&](int scaleIdx) -> SP {
    SP s{};
    if (scaleIdx == 0) {
      s.srt = srt_t; s.jr = jr_t; s.vm = vm_t;
      s.W1 = (const float*)d_in[2];  s.g1 = (const float*)d_in[3];
      s.b1 = (const float*)d_in[4];  s.W2 = (const float*)d_in[5];
      s.g2 = (const float*)d_in[6];  s.b2 = (const float*)d_in[7];
      s.cnt = cnt_t; s.uniq = uniq_t; s.woff = woff_t; s.U = Ut;
      s.segt = segt_t; s.part1 = part1_t; s.part2 = part2_t;
      s.coef1 = coef + 0*256; s.coef2 = coef + 1*256;
      s.Y2 = mg; s.hout = vf;
      s.C1 = 64; s.segstride = G_TOPC;
      s.gx = 176; s.gy = 200; s.gz = 1; s.vx = 0.4f; s.vy = 0.4f; s.vz = 4.0f;
    } else if (scaleIdx == 1) {
      s.srt = srt_m; s.jr = jr_m; s.vm = vm_m;
      s.W1 = (const float*)d_in[8];  s.g1 = (const float*)d_in[9];
      s.b1 = (const float*)d_in[10]; s.W2 = (const float*)d_in[11];
      s.g2 = (const float*)d_in[12]; s.b2 = (const float*)d_in[13];
      s.cnt = cnt_m; s.uniq = uniq_m; s.woff = woff_m; s.U = Um;
      s.segt = segt_m; s.part1 = part1_m; s.part2 = part2_m;
      s.coef1 = coef + 2*256; s.coef2 = coef + 3*256;
      s.Y2 = Y2_m; s.hout = vox_m;
      s.C1 = 32; s.segstride = NPTS;
      s.gx = 352; s.gy = 400; s.gz = 2; s.vx = 0.2f; s.vy = 0.2f; s.vz = 2.0f;
    } else {
      s.srt = srt_l; s.jr = jr_l; s.vm = vm_l;
      s.W1 = (const float*)d_in[14]; s.g1 = (const float*)d_in[15];
      s.b1 = (const float*)d_in[16]; s.W2 = (const float*)d_in[17];
      s.g2 = (const float*)d_in[18]; s.b2 = (const float*)d_in[19];
      s.cnt = cnt_l; s.uniq = uniq_l; s.woff = woff_l; s.U = Ul;
      s.segt = segt_l; s.part1 = part1_l; s.part2 = part2_l;
      s.coef1 = coef + 4*256; s.coef2 = coef + 5*256;
      s.Y2 = Y2_l; s.hout = vox_l;
      s.C1 = 32; s.segstride = NPTS;
      s.gx = 704; s.gy = 800; s.gz = 4; s.vx = 0.1f; s.vy = 0.1f; s.vz = 1.0f;
    }
    return s;
  };
  SP spT = mkSP(0), spM = mkSP(1), spL = mkSP(2);

  // ---- batched voxelization front-end ----
  (void)hipMemsetAsync(cnt_t, 0, ((size_t)G_TOPC + G_MEDC + G_LOWC) * 4, stream);
  k_count3<<<NPTS/BLK, BLK, 0, stream>>>(pts, cnt_t, cnt_m, cnt_l);
  k_scan1_all<<<NB_T + NB_M + NB_L, BLK, 0, stream>>>(cnt_t, cnt_m, cnt_l, bsum);
  k_scan2_all<<<1, 1024, 0, stream>>>(bsum, Ut, Um, Ul);
  k_scan3_all<<<NB_T + NB_M + NB_L, BLK, 0, stream>>>(cnt_t, cnt_m, cnt_l, bsum,
      rank_t, rank_m, rank_l, uniq_t, uniq_m, uniq_l, woff_t, woff_m, woff_l);
  k_clist_all<<<2*NCL, BLK, 0, stream>>>(uniq_t, Ut,
      cnt_m, rank_m, clist_m, mcnt_m, cnt_l, rank_l, clist_l, mcnt_l);
  k_scatter3<<<NPTS/BLK, BLK, 0, stream>>>(pts,
      rank_t, woff_t, srt_t, jr_t,
      rank_m, woff_m, srt_m, jr_m,
      rank_l, woff_l, srt_l, jr_l);
  k_vox13<<<NBVT + NBVM + NBVL, BLK, 0, stream>>>(
      srt_t, uniq_t, cnt_t, woff_t, Ut, vm_t,
      srt_m, uniq_m, cnt_m, woff_m, Um, vm_m,
      srt_l, uniq_l, cnt_l, woff_l, Ul, vm_l);

  // ---- batched VFE pipeline (all scales per stage) ----
  k_stats1_all<<<3*ST1BLKS, BLK, 0, stream>>>(spT, spM, spL);
  k_partcoef1_all<<<128, BLK, 0, stream>>>(spT, spM, spL);
  k_hsegT_all<<<NHT + 2*NHM, BLK, 0, stream>>>(spT, spM, spL);
  k_y2t_all<<<3*Y2B, BLK, 0, stream>>>(spT, spM, spL);
  k_partcoef2_all<<<256, BLK, 0, stream>>>(spT, spM, spL);
  k_hseg2_all<<<NJT + 2*NJM, BLK, 0, stream>>>(spT, spM, spL);

  // ---- merges + final outputs ----
  k_merge2_all<<<2*NHT, BLK, 0, stream>>>(vox_m, clist_m, mcnt_m, maccm,
      vox_l, clist_l, mcnt_l, maccl, Ut);
  k_fin_all<<<(NPTS*32)/BLK, BLK, 0, stream>>>(uniq_t, Ut, maccm, maccl,
      vf, mg, co);
}

// Round 10
// 728.632 us; speedup vs baseline: 1.1876x; 1.1059x over previous
//
#include <hip/hip_runtime.h>
#include <cstdint>
#include <cstddef>

#define NPTS 262144
#define BLK 256
#define TGX 176
#define TGY 200
#define TGZ 1

#define G_TOPC 70400
#define G_MEDC 1126400
#define G_LOWC 4505600

#define SCAN_ITEMS 32
#define SCAN_CHUNK (BLK*SCAN_ITEMS)
// batched scan block counts / bsum offsets (disjoint: [0,9) [16,154) [160,710))
#define NB_T 9
#define NB_M 138
#define NB_L 550
#define BO_T 0
#define BO_M 16
#define BO_L 160
// vox13 block split
#define NBVT (G_TOPC/BLK)      // 275
#define NBVM (NPTS/BLK)        // 1024
#define NBVL (NPTS/BLK)        // 1024

#define Y2B (NPTS/128)         // 2048 blocks per scale (128-row tiles)
#define ST1BLKS 256            // stats1 blocks per scale (1024 rows each)
// batched per-scale stage grids
#define NHT 4400               // G_TOPC*16/BLK
#define NHM 8192               // NPTS*8/BLK
#define NJT 8800               // G_TOPC*32/BLK
#define NJM 16384              // NPTS*16/BLK
#define NCL 275                // G_TOPC/BLK (ceil)

// ---------------- per-scale parameter pack ----------------
struct SP {
  const float4* srt; const int* jr; const float4* vm;
  const float* W1; const float* W2;
  const float* g1; const float* b1; const float* g2; const float* b2;
  const int* cnt; const int* uniq; const int* woff; const int* U;
  float* segt; float* part1; float* part2;
  float* coef1; float* coef2;
  unsigned short* Y2;          // bf16 storage
  float* hout;
  int C1; int segstride; int gx, gy, gz; float vx, vy, vz;
};

// ---------------- bf16 helpers ----------------
__device__ __forceinline__ unsigned short f2bf(float v) {
  unsigned u = __float_as_uint(v);
  u += 0x7FFFu + ((u >> 16) & 1u);      // round-to-nearest-even
  return (unsigned short)(u >> 16);
}
__device__ __forceinline__ float bf2f(unsigned short h) {
  return __uint_as_float((unsigned)h << 16);
}

// ---------------- voxel coord helpers ----------------
__device__ __forceinline__ void pcoords(float x, float y, float z,
    float vx, float vy, float vz, int gx, int gy, int gz,
    int& cx, int& cy, int& cz) {
  cx = (int)floorf((x - 0.0f)  / vx);
  cy = (int)floorf((y + 40.0f) / vy);
  cz = (int)floorf((z + 3.0f)  / vz);
  cx = min(max(cx, 0), gx - 1);
  cy = min(max(cy, 0), gy - 1);
  cz = min(max(cz, 0), gz - 1);
}

__device__ __forceinline__ int lin3(float b, float x, float y, float z,
    float vx, float vy, float vz, int gx, int gy, int gz) {
  int cx, cy, cz; pcoords(x, y, z, vx, vy, vz, gx, gy, gz, cx, cy, cz);
  return (((int)b * gz + cz) * gy + cy) * gx + cx;
}

// f-vector (10 features) — identical expression everywhere y1 is recomputed.
__device__ __forceinline__ void build_f(float4 p, float4 vm,
    float vx, float vy, float vz, int gx, int gy, int gz, float* f) {
  int cx, cy, cz; pcoords(p.x, p.y, p.z, vx, vy, vz, gx, gy, gz, cx, cy, cz);
  f[0] = p.x; f[1] = p.y; f[2] = p.z; f[3] = p.w;
  f[4] = p.x - vm.x;
  f[5] = p.y - vm.y;
  f[6] = p.z - vm.z;
  f[7] = p.x - (0.0f   + (cx + 0.5f)*vx);
  f[8] = p.y - (-40.0f + (cy + 0.5f)*vy);
  f[9] = p.z - (-3.0f  + (cz + 0.5f)*vz);
}

// ---------------- batched dense count (all 3 scales) ----------------
__global__ __launch_bounds__(BLK) void k_count3(const float* __restrict__ pts,
    int* __restrict__ ct, int* __restrict__ cm, int* __restrict__ cl) {
  int i = blockIdx.x * BLK + threadIdx.x;
  if (i >= NPTS) return;
  float b = pts[i*5+0], x = pts[i*5+1], y = pts[i*5+2], z = pts[i*5+3];
  atomicAdd(&ct[lin3(b,x,y,z, 0.4f,0.4f,4.0f, 176,200,1)], 1);
  atomicAdd(&cm[lin3(b,x,y,z, 0.2f,0.2f,2.0f, 352,400,2)], 1);
  atomicAdd(&cl[lin3(b,x,y,z, 0.1f,0.1f,1.0f, 704,800,4)], 1);
}

// ---------------- batched scans ----------------
__global__ __launch_bounds__(BLK) void k_scan1_all(const int* __restrict__ ct,
    const int* __restrict__ cm, const int* __restrict__ cl,
    int2* __restrict__ bsum) {
  int bid = blockIdx.x;
  const int* cnt; int G, bo, cb;
  if (bid < NB_T)            { cnt = ct; G = G_TOPC; bo = BO_T; cb = bid; }
  else if (bid < NB_T+NB_M)  { cnt = cm; G = G_MEDC; bo = BO_M; cb = bid - NB_T; }
  else                       { cnt = cl; G = G_LOWC; bo = BO_L; cb = bid - NB_T - NB_M; }
  int base = cb * SCAN_CHUNK + threadIdx.x * SCAN_ITEMS;
  int so = 0, sp = 0;
  #pragma unroll
  for (int k = 0; k < SCAN_ITEMS; k++) {
    int j = base + k;
    if (j < G) { int c = cnt[j]; if (c > 0) { so++; sp += c; } }
  }
  __shared__ int sho[BLK], shp[BLK];
  sho[threadIdx.x] = so; shp[threadIdx.x] = sp; __syncthreads();
  for (int off = BLK/2; off > 0; off >>= 1) {
    if (threadIdx.x < off) {
      sho[threadIdx.x] += sho[threadIdx.x + off];
      shp[threadIdx.x] += shp[threadIdx.x + off];
    }
    __syncthreads();
  }
  if (threadIdx.x == 0) { int2 v; v.x = sho[0]; v.y = shp[0]; bsum[bo + cb] = v; }
}

__device__ void scan_pass(int2* bsum, int off, int nb, int* U,
                          int* so, int* sp) {
  int t = threadIdx.x;
  int vo = 0, vp = 0;
  if (t < nb) { int2 v = bsum[off + t]; vo = v.x; vp = v.y; }
  so[t] = vo; sp[t] = vp; __syncthreads();
  for (int o = 1; o < 1024; o <<= 1) {
    int ao = (t >= o) ? so[t - o] : 0;
    int ap = (t >= o) ? sp[t - o] : 0;
    __syncthreads();
    so[t] += ao; sp[t] += ap;
    __syncthreads();
  }
  if (t < nb) { int2 e; e.x = so[t] - vo; e.y = sp[t] - vp; bsum[off + t] = e; }
  if (t == 0) *U = so[1023];
  __syncthreads();
}

__global__ __launch_bounds__(1024) void k_scan2_all(int2* __restrict__ bsum,
    int* __restrict__ Ut, int* __restrict__ Um, int* __restrict__ Ul) {
  __shared__ int so[1024], sp[1024];
  scan_pass(bsum, BO_T, NB_T, Ut, so, sp);
  scan_pass(bsum, BO_M, NB_M, Um, so, sp);
  scan_pass(bsum, BO_L, NB_L, Ul, so, sp);
}

__global__ __launch_bounds__(BLK) void k_scan3_all(const int* __restrict__ ct,
    const int* __restrict__ cm, const int* __restrict__ cl,
    const int2* __restrict__ bsum,
    int* __restrict__ rkt, int* __restrict__ rkm, int* __restrict__ rkl,
    int* __restrict__ uqt, int* __restrict__ uqm, int* __restrict__ uql,
    int* __restrict__ wot, int* __restrict__ wom, int* __restrict__ wol) {
  int bid = blockIdx.x;
  const int* cnt; int G, bo, cb; int *rank, *uniq, *woff;
  if (bid < NB_T)           { cnt=ct; G=G_TOPC; bo=BO_T; cb=bid;            rank=rkt; uniq=uqt; woff=wot; }
  else if (bid < NB_T+NB_M) { cnt=cm; G=G_MEDC; bo=BO_M; cb=bid-NB_T;       rank=rkm; uniq=uqm; woff=wom; }
  else                      { cnt=cl; G=G_LOWC; bo=BO_L; cb=bid-NB_T-NB_M;  rank=rkl; uniq=uql; woff=wol; }
  int base = cb * SCAN_CHUNK + threadIdx.x * SCAN_ITEMS;
  int so = 0, sp = 0;
  #pragma unroll
  for (int k = 0; k < SCAN_ITEMS; k++) {
    int j = base + k;
    if (j < G) { int c = cnt[j]; if (c > 0) { so++; sp += c; } }
  }
  __shared__ int sho[BLK], shp[BLK];
  sho[threadIdx.x] = so; shp[threadIdx.x] = sp; __syncthreads();
  for (int off = 1; off < BLK; off <<= 1) {
    int ao = (threadIdx.x >= off) ? sho[threadIdx.x - off] : 0;
    int ap = (threadIdx.x >= off) ? shp[threadIdx.x - off] : 0;
    __syncthreads();
    sho[threadIdx.x] += ao; shp[threadIdx.x] += ap;
    __syncthreads();
  }
  int2 bb = bsum[bo + cb];
  int ro = bb.x + sho[threadIdx.x] - so;
  int po = bb.y + shp[threadIdx.x] - sp;
  for (int k = 0; k < SCAN_ITEMS; k++) {
    int j = base + k;
    if (j < G) {
      int c = cnt[j];
      if (c > 0) { rank[j] = ro; uniq[ro] = j; woff[ro] = po; ro++; po += c; }
    }
  }
}

// ---------------- batched counting-sort scatter ----------------
__global__ __launch_bounds__(BLK) void k_scatter3(const float* __restrict__ pts,
    const int* __restrict__ rkt, int* __restrict__ wot, float4* __restrict__ st, int* __restrict__ jt,
    const int* __restrict__ rkm, int* __restrict__ wom, float4* __restrict__ sm, int* __restrict__ jm,
    const int* __restrict__ rkl, int* __restrict__ wol, float4* __restrict__ sl, int* __restrict__ jl) {
  int i = blockIdx.x * BLK + threadIdx.x;
  if (i >= NPTS) return;
  float b = pts[i*5+0], x = pts[i*5+1], y = pts[i*5+2], z = pts[i*5+3], it = pts[i*5+4];
  float4 p; p.x = x; p.y = y; p.z = z; p.w = it;
  {
    int r = rkt[lin3(b,x,y,z, 0.4f,0.4f,4.0f, 176,200,1)];
    int j = atomicAdd(&wot[r], 1); st[j] = p; jt[j] = r;
  }
  {
    int r = rkm[lin3(b,x,y,z, 0.2f,0.2f,2.0f, 352,400,2)];
    int j = atomicAdd(&wom[r], 1); sm[j] = p; jm[j] = r;
  }
  {
    int r = rkl[lin3(b,x,y,z, 0.1f,0.1f,1.0f, 704,800,4)];
    int j = atomicAdd(&wol[r], 1); sl[j] = p; jl[j] = r;
  }
}

// ---------------- batched per-voxel xyz means ----------------
__global__ __launch_bounds__(BLK) void k_vox13(
    const float4* __restrict__ st, const int* __restrict__ uqt, const int* __restrict__ ct,
    const int* __restrict__ wot, const int* __restrict__ Ut, float4* __restrict__ vt,
    const float4* __restrict__ sm, const int* __restrict__ uqm, const int* __restrict__ cm,
    const int* __restrict__ wom, const int* __restrict__ Um, float4* __restrict__ vm,
    const float4* __restrict__ sl, const int* __restrict__ uql, const int* __restrict__ cl,
    const int* __restrict__ wol, const int* __restrict__ Ul, float4* __restrict__ vl) {
  int bid = blockIdx.x;
  const float4* srt; const int *uniq, *cnt, *woff, *Up; float4* vmean; int r;
  if (bid < NBVT)           { r = bid*BLK + threadIdx.x;           srt=st; uniq=uqt; cnt=ct; woff=wot; Up=Ut; vmean=vt; }
  else if (bid < NBVT+NBVM) { r = (bid-NBVT)*BLK + threadIdx.x;    srt=sm; uniq=uqm; cnt=cm; woff=wom; Up=Um; vmean=vm; }
  else                      { r = (bid-NBVT-NBVM)*BLK + threadIdx.x; srt=sl; uniq=uql; cnt=cl; woff=wol; Up=Ul; vmean=vl; }
  if (r >= *Up) return;
  int lin = uniq[r];
  int len = cnt[lin];
  int base = woff[r] - len;
  float sx = 0.f, sy = 0.f, sz = 0.f;
  for (int k = 0; k < len; k++) {
    float4 p = srt[base + k];
    sx += p.x; sy += p.y; sz += p.z;
  }
  float il = 1.0f / (float)len;
  float4 o; o.x = sx*il; o.y = sy*il; o.z = sz*il; o.w = il;
  vmean[r] = o;
}

// ------- fused y1-compute + column sum/sumsq partials (all scales) ----------
__global__ __launch_bounds__(BLK) void k_stats1_all(SP a, SP b, SP c) {
  int s = blockIdx.x >> 8;
  int blk = blockIdx.x & 255;
  SP sp = (s == 0) ? a : ((s == 1) ? b : c);
  const int C1 = sp.C1;
  __shared__ float w[640];
  __shared__ float wsum[4][64], wsq[4][64];
  for (int t = threadIdx.x; t < 10*C1; t += BLK) w[t] = sp.W1[t];
  __syncthreads();
  float f[4][10];
  #pragma unroll
  for (int k = 0; k < 4; k++) {
    int i = blk*1024 + k*BLK + threadIdx.x;
    float4 p = sp.srt[i];
    float4 vmn = sp.vm[sp.jr[i]];
    build_f(p, vmn, sp.vx, sp.vy, sp.vz, sp.gx, sp.gy, sp.gz, f[k]);
  }
  int wv = threadIdx.x >> 6;
  int lane = threadIdx.x & 63;
  for (int o = 0; o < C1; o += 4) {
    float sacc[4] = {0,0,0,0}, qacc[4] = {0,0,0,0};
    #pragma unroll
    for (int k = 0; k < 4; k++) {
      float a0=0.f, a1=0.f, a2=0.f, a3=0.f;
      #pragma unroll
      for (int d = 0; d < 10; d++) {
        float fv = f[k][d];
        const float* wr = &w[d*C1 + o];
        a0 = fmaf(fv, wr[0], a0); a1 = fmaf(fv, wr[1], a1);
        a2 = fmaf(fv, wr[2], a2); a3 = fmaf(fv, wr[3], a3);
      }
      sacc[0] += a0; sacc[1] += a1; sacc[2] += a2; sacc[3] += a3;
      qacc[0] += a0*a0; qacc[1] += a1*a1; qacc[2] += a2*a2; qacc[3] += a3*a3;
    }
    #pragma unroll
    for (int m = 1; m < 64; m <<= 1) {
      #pragma unroll
      for (int e = 0; e < 4; e++) {
        sacc[e] += __shfl_xor(sacc[e], m);
        qacc[e] += __shfl_xor(qacc[e], m);
      }
    }
    if (lane == 0) {
      #pragma unroll
      for (int e = 0; e < 4; e++) { wsum[wv][o+e] = sacc[e]; wsq[wv][o+e] = qacc[e]; }
    }
  }
  __syncthreads();
  if (threadIdx.x < C1) {
    int ch = threadIdx.x;
    float sv = wsum[0][ch] + wsum[1][ch] + wsum[2][ch] + wsum[3][ch];
    float qv = wsq[0][ch] + wsq[1][ch] + wsq[2][ch] + wsq[3][ch];
    sp.part1[(size_t)blk*2*C1 + ch]      = sv;
    sp.part1[(size_t)blk*2*C1 + C1 + ch] = qv;
  }
}

// ---- reduce per-block partials -> BN coef (stage 1: C1; stage 2: C2) -------
__device__ __forceinline__ void partcoef_body(const float* part, int NB, int C,
    int ch, const float* g, const float* b, float* coef) {
  float s = 0.f, q = 0.f;
  for (int bk = threadIdx.x; bk < NB; bk += BLK) {
    s += part[(size_t)bk*2*C + ch];
    q += part[(size_t)bk*2*C + C + ch];
  }
  __shared__ float ss[BLK], sq[BLK];
  ss[threadIdx.x] = s; sq[threadIdx.x] = q; __syncthreads();
  for (int off = BLK/2; off > 0; off >>= 1) {
    if (threadIdx.x < off) {
      ss[threadIdx.x] += ss[threadIdx.x + off];
      sq[threadIdx.x] += sq[threadIdx.x + off];
    }
    __syncthreads();
  }
  if (threadIdx.x == 0) {
    float mu  = ss[0] * (1.0f / NPTS);
    float var = sq[0] * (1.0f / NPTS) - mu*mu;
    float sc  = g[ch] * (1.0f / sqrtf(var + 1e-3f));
    coef[ch]     = sc;
    coef[C + ch] = fmaf(-mu, sc, b[ch]);
  }
}

__global__ __launch_bounds__(BLK) void k_partcoef1_all(SP a, SP b, SP c) {
  int bid = blockIdx.x; SP sp; int ch;
  if (bid < 64)      { sp = a; ch = bid; }
  else if (bid < 96) { sp = b; ch = bid - 64; }
  else               { sp = c; ch = bid - 96; }
  if (ch >= sp.C1) return;
  partcoef_body(sp.part1, ST1BLKS, sp.C1, ch, sp.g1, sp.b1, sp.coef1);
}

__global__ __launch_bounds__(BLK) void k_partcoef2_all(SP a, SP b, SP c) {
  int bid = blockIdx.x; SP sp; int ch;
  if (bid < 128)      { sp = a; ch = bid; }
  else if (bid < 192) { sp = b; ch = bid - 128; }
  else                { sp = c; ch = bid - 192; }
  if (ch >= 2*sp.C1) return;
  partcoef_body(sp.part2, Y2B, 2*sp.C1, ch, sp.g2, sp.b2, sp.coef2);
}

// ---- layer-1 voxel means of BN+ReLU(y1), y1 recomputed (all scales) --------
__global__ __launch_bounds__(BLK) void k_hsegT_all(SP a, SP b, SP c) {
  int bid = blockIdx.x; SP sp; int rb;
  if (bid < NHT)           { sp = a; rb = bid; }
  else if (bid < NHT+NHM)  { sp = b; rb = bid - NHT; }
  else                     { sp = c; rb = bid - NHT - NHM; }
  const int C1 = sp.C1;
  const int qsh = (C1 == 64) ? 4 : 3;
  __shared__ float w[640];
  __shared__ float sc[64], sb[64];
  for (int t = threadIdx.x; t < 10*C1; t += BLK) w[t] = sp.W1[t];
  for (int t = threadIdx.x; t < C1; t += BLK) { sc[t] = sp.coef1[t]; sb[t] = sp.coef1[C1 + t]; }
  __syncthreads();
  int tid = rb * BLK + threadIdx.x;
  int r = tid >> qsh;
  int q = tid & ((1 << qsh) - 1);
  if (r >= *sp.U) return;
  int lin = sp.uniq[r];
  int len = sp.cnt[lin];
  int base = sp.woff[r] - len;
  float4 vmn = sp.vm[r];
  int c0 = q * 4;
  float s0 = sc[c0+0], s1 = sc[c0+1], s2 = sc[c0+2], s3 = sc[c0+3];
  float o0 = sb[c0+0], o1 = sb[c0+1], o2 = sb[c0+2], o3 = sb[c0+3];
  float a0=0.f, a1=0.f, a2=0.f, a3=0.f;
  for (int k = 0; k < len; k++) {
    float4 p = sp.srt[base + k];
    float f[10];
    build_f(p, vmn, sp.vx, sp.vy, sp.vz, sp.gx, sp.gy, sp.gz, f);
    float y0=0.f, y1=0.f, y2=0.f, y3=0.f;
    #pragma unroll
    for (int d = 0; d < 10; d++) {
      float fv = f[d];
      const float* wr = &w[d*C1 + c0];
      y0 = fmaf(fv, wr[0], y0); y1 = fmaf(fv, wr[1], y1);
      y2 = fmaf(fv, wr[2], y2); y3 = fmaf(fv, wr[3], y3);
    }
    a0 += fmaxf(fmaf(y0, s0, o0), 0.f);
    a1 += fmaxf(fmaf(y1, s1, o1), 0.f);
    a2 += fmaxf(fmaf(y2, s2, o2), 0.f);
    a3 += fmaxf(fmaf(y3, s3, o3), 0.f);
  }
  float il = 1.0f / (float)len;
  sp.segt[(size_t)(c0+0)*sp.segstride + r] = a0*il;
  sp.segt[(size_t)(c0+1)*sp.segstride + r] = a1*il;
  sp.segt[(size_t)(c0+2)*sp.segstride + r] = a2*il;
  sp.segt[(size_t)(c0+3)*sp.segstride + r] = a3*il;
}

// ------- layer 2: 128x64/128 tile GEMM, KC=32 chunks, reg-staged A ----------
#define FMA4(ACC, AV, BV) { (ACC).x = fmaf((AV), (BV).x, (ACC).x); \
  (ACC).y = fmaf((AV), (BV).y, (ACC).y); \
  (ACC).z = fmaf((AV), (BV).z, (ACC).z); \
  (ACC).w = fmaf((AV), (BV).w, (ACC).w); }

template<int C1>
__device__ __forceinline__ void y2t_body(const SP& sp, int blk,
    float* At, float* Bp) {
  constexpr int C2  = 2*C1;
  constexpr int K   = 2*C1;
  constexpr int MT  = 128;
  constexpr int KC  = 32;
  constexpr int NKC = K / KC;        // 4 (top), 2 (med/low)
  constexpr int NP  = C2 / 64;       // 2 (top), 1 (med/low)
  const int tid  = threadIdx.x;
  const int base = blk * MT;

  // ---- per-thread staging context: this thread owns row jst of the tile ----
  const int jst = tid & 127;
  const int qst = tid >> 7;          // parity: quads/k-rows {qst, qst+2, ...}
  int    jr_s = sp.jr[base + jst];
  float4 p_s  = sp.srt[base + jst];
  float4 vm_s = sp.vm[jr_s];
  float fs[10];
  build_f(p_s, vm_s, sp.vx, sp.vy, sp.vz, sp.gx, sp.gy, sp.gz, fs);

  const int w      = tid >> 6;
  const int lane   = tid & 63;
  const int colg   = lane & 15;
  const int rowsub = lane >> 4;
  const int rowg   = w*4 + rowsub;    // 0..15
  const int arow   = rowg*8;

  float4 acc[NP][8];
  #pragma unroll
  for (int p = 0; p < NP; p++)
    #pragma unroll
    for (int rr = 0; rr < 8; rr++) acc[p][rr] = {0.f, 0.f, 0.f, 0.f};

  #pragma unroll
  for (int kc = 0; kc < NKC; kc++) {
    if (kc) __syncthreads();         // protect At/Bp from prior compute
    if (kc*KC < C1) {
      // y1 chunk: stage BN(ReLU(y1)) for channels [kc*32, kc*32+32)
      #pragma unroll
      for (int m = 0; m < 4; m++) {
        int qq = qst + 2*m;          // 0..7
        int c0 = kc*KC + qq*4;
        float y0=0.f, y1=0.f, y2=0.f, y3=0.f;
        #pragma unroll
        for (int d = 0; d < 10; d++) {
          float fv = fs[d];
          const float* wr = &sp.W1[d*C1 + c0];   // wave-uniform -> s_load
          y0 = fmaf(fv, wr[0], y0); y1 = fmaf(fv, wr[1], y1);
          y2 = fmaf(fv, wr[2], y2); y3 = fmaf(fv, wr[3], y3);
        }
        At[(qq*4+0)*MT + jst] = fmaxf(fmaf(y0, sp.coef1[c0+0], sp.coef1[C1+c0+0]), 0.f);
        At[(qq*4+1)*MT + jst] = fmaxf(fmaf(y1, sp.coef1[c0+1], sp.coef1[C1+c0+1]), 0.f);
        At[(qq*4+2)*MT + jst] = fmaxf(fmaf(y2, sp.coef1[c0+2], sp.coef1[C1+c0+2]), 0.f);
        At[(qq*4+3)*MT + jst] = fmaxf(fmaf(y3, sp.coef1[c0+3], sp.coef1[C1+c0+3]), 0.f);
      }
    } else {
      // seg chunk: gather segmean channels (segch = kc*32 + k - C1)
      #pragma unroll
      for (int m = 0; m < 16; m++) {
        int k = qst + 2*m;           // 0..31
        int segch = kc*KC + k - C1;
        At[k*MT + jst] = sp.segt[(size_t)segch*sp.segstride + jr_s];
      }
    }
    // Bp: full-width W2 rows for this chunk
    constexpr int BQ = KC*C2/4;
    for (int it = tid; it < BQ; it += BLK) {
      int k  = it / (C2/4);
      int c4 = it % (C2/4);
      *(float4*)&Bp[k*C2 + c4*4] =
          *(const float4*)&sp.W2[(size_t)(kc*KC + k)*C2 + c4*4];
    }
    __syncthreads();
    #pragma unroll 8
    for (int k = 0; k < KC; k++) {
      float4 a0 = *(const float4*)&At[k*MT + arow];
      float4 a1 = *(const float4*)&At[k*MT + arow + 4];
      #pragma unroll
      for (int p = 0; p < NP; p++) {
        float4 bv = *(const float4*)&Bp[k*C2 + p*64 + colg*4];
        FMA4(acc[p][0], a0.x, bv); FMA4(acc[p][1], a0.y, bv);
        FMA4(acc[p][2], a0.z, bv); FMA4(acc[p][3], a0.w, bv);
        FMA4(acc[p][4], a1.x, bv); FMA4(acc[p][5], a1.y, bv);
        FMA4(acc[p][6], a1.z, bv); FMA4(acc[p][7], a1.w, bv);
      }
    }
  }

  // ---- write Y2 tile as bf16 ----
  #pragma unroll
  for (int p = 0; p < NP; p++)
    #pragma unroll
    for (int rr = 0; rr < 8; rr++) {
      float4 v = acc[p][rr];
      ushort4 h; h.x = f2bf(v.x); h.y = f2bf(v.y); h.z = f2bf(v.z); h.w = f2bf(v.w);
      *(ushort4*)&sp.Y2[(size_t)(base + arow + rr)*C2 + p*64 + colg*4] = h;
    }

  // ---- fused per-block column sum/sumsq partials (reuse At as scratch) ----
  __syncthreads();
  float* red = At;                 // [32][C2] = 4096 floats, fits At exactly
  #pragma unroll
  for (int p = 0; p < NP; p++) {
    #pragma unroll
    for (int e = 0; e < 4; e++) {
      float sv = 0.f, qv = 0.f;
      #pragma unroll
      for (int rr = 0; rr < 8; rr++) {
        float v = (&acc[p][rr].x)[e];
        sv += v; qv += v*v;
      }
      red[rowg*C2 + p*64 + colg*4 + e]        = sv;
      red[(16 + rowg)*C2 + p*64 + colg*4 + e] = qv;
    }
  }
  __syncthreads();
  if (tid < C2) {
    float sv = 0.f, qv = 0.f;
    #pragma unroll 4
    for (int i = 0; i < 16; i++) {
      sv += red[i*C2 + tid];
      qv += red[(16 + i)*C2 + tid];
    }
    sp.part2[(size_t)blk*2*C2 + tid]      = sv;
    sp.part2[(size_t)blk*2*C2 + C2 + tid] = qv;
  }
}

__global__ __launch_bounds__(BLK) void k_y2t_all(SP a, SP b, SP c) {
  __shared__ float At[32*128];   // 16 KB
  __shared__ float Bp[32*128];   // 16 KB (med uses half)
  int bid = blockIdx.x;
  if (bid < Y2B)        y2t_body<64>(a, bid, At, Bp);
  else if (bid < 2*Y2B) y2t_body<32>(b, bid - Y2B, At, Bp);
  else                  y2t_body<32>(c, bid - 2*Y2B, At, Bp);
}

// -------- layer-2 BN+ReLU + voxel mean (bf16 Y2, all scales) ----------------
__global__ __launch_bounds__(BLK) void k_hseg2_all(SP a, SP b, SP c) {
  int bid = blockIdx.x; SP sp; int rb;
  if (bid < NJT)           { sp = a; rb = bid; }
  else if (bid < NJT+NJM)  { sp = b; rb = bid - NJT; }
  else                     { sp = c; rb = bid - NJT - NJM; }
  const int C = 2*sp.C1;
  const int qsh = (C == 128) ? 5 : 4;
  __shared__ float sc[128], sb[128];
  for (int t = threadIdx.x; t < C; t += BLK) { sc[t] = sp.coef2[t]; sb[t] = sp.coef2[C + t]; }
  __syncthreads();
  int tid = rb * BLK + threadIdx.x;
  int r = tid >> qsh;
  int q = tid & ((1 << qsh) - 1);
  if (r >= *sp.U) return;
  int lin = sp.uniq[r];
  int len = sp.cnt[lin];
  int base = sp.woff[r] - len;
  int c0 = q * 4;
  float s0 = sc[c0+0], s1 = sc[c0+1], s2 = sc[c0+2], s3 = sc[c0+3];
  float o0 = sb[c0+0], o1 = sb[c0+1], o2 = sb[c0+2], o3 = sb[c0+3];
  float a0=0.f, a1=0.f, a2=0.f, a3=0.f;
  const unsigned short* Yh = sp.Y2;
  for (int k = 0; k < len; k++) {
    ushort4 hv = *(const ushort4*)&Yh[(size_t)(base + k)*C + c0];
    a0 += fmaxf(fmaf(bf2f(hv.x), s0, o0), 0.f);
    a1 += fmaxf(fmaf(bf2f(hv.y), s1, o1), 0.f);
    a2 += fmaxf(fmaf(bf2f(hv.z), s2, o2), 0.f);
    a3 += fmaxf(fmaf(bf2f(hv.w), s3, o3), 0.f);
  }
  float il = 1.0f / (float)len;
  float4 o = {a0*il, a1*il, a2*il, a3*il};
  *(float4*)&sp.hout[(size_t)r*C + c0] = o;
}

// ------------- merge: per-parent child-rank lists (med+low batched) ---------
__global__ __launch_bounds__(BLK) void k_clist_all(const int* __restrict__ tuniq,
    const int* __restrict__ Utp,
    const int* __restrict__ cnt_m, const int* __restrict__ rank_m,
    int* __restrict__ clist_m, int* __restrict__ mcnt_m,
    const int* __restrict__ cnt_l, const int* __restrict__ rank_l,
    int* __restrict__ clist_l, int* __restrict__ mcnt_l) {
  int bid = blockIdx.x;
  const int *scnt, *srank; int *clist, *mcnt;
  int gx, gy, gz, f, rb;
  if (bid < NCL) { scnt=cnt_m; srank=rank_m; clist=clist_m; mcnt=mcnt_m;
                   gx=352; gy=400; gz=2; f=2; rb=bid; }
  else           { scnt=cnt_l; srank=rank_l; clist=clist_l; mcnt=mcnt_l;
                   gx=704; gy=800; gz=4; f=4; rb=bid-NCL; }
  int r = rb * BLK + threadIdx.x;
  if (r >= *Utp) return;
  int lin = tuniq[r];
  int x = lin % TGX; int t = lin / TGX;
  int y = t % TGY;   int b = t / TGY;   // TGZ == 1 so z == 0
  int m = 0;
  for (int cz = 0; cz < gz; cz++)
    for (int yy = y*f; yy < y*f + f; yy++)
      for (int xx = x*f; xx < x*f + f; xx++) {
        int cl = ((b*gz + cz)*gy + yy)*gx + xx;
        if (scnt[cl] > 0) clist[(size_t)r*64 + (m++)] = srank[cl];
      }
  mcnt[r] = m;
}

__global__ __launch_bounds__(BLK) void k_merge2_all(
    const float* __restrict__ vox_m, const int* __restrict__ clist_m,
    const int* __restrict__ mcnt_m, float* __restrict__ maccm,
    const float* __restrict__ vox_l, const int* __restrict__ clist_l,
    const int* __restrict__ mcnt_l, float* __restrict__ maccl,
    const int* __restrict__ Utp) {
  int bid = blockIdx.x;
  const float* vox; const int *clist, *mcnt; float* dest; int rb;
  if (bid < NHT) { vox=vox_m; clist=clist_m; mcnt=mcnt_m; dest=maccm; rb=bid; }
  else           { vox=vox_l; clist=clist_l; mcnt=mcnt_l; dest=maccl; rb=bid-NHT; }
  int idx = rb * BLK + threadIdx.x;
  int r = idx >> 4;
  int q = idx & 15;
  if (r >= *Utp) return;
  int m = mcnt[r];
  float a0=0.f, a1=0.f, a2=0.f, a3=0.f;
  for (int t = 0; t < m; t++) {
    int cr = clist[(size_t)r*64 + t];
    float4 v = *(const float4*)&vox[(size_t)cr*64 + q*4];
    a0 += v.x; a1 += v.y; a2 += v.z; a3 += v.w;
  }
  float inv = 1.0f / (float)max(m, 1);
  float4 o = {a0*inv, a1*inv, a2*inv, a3*inv};
  *(float4*)&dest[(size_t)r*64 + q*4] = o;
}

// ---- final: vf tail zero + coors + merged compose (one kernel) -------------
__global__ __launch_bounds__(BLK) void k_fin_all(const int* __restrict__ uniq,
    const int* __restrict__ Up, const float* __restrict__ maccm,
    const float* __restrict__ maccl, float* __restrict__ vf,
    float* __restrict__ mg, float* __restrict__ coors) {
  int idx = blockIdx.x * BLK + threadIdx.x;
  int r = idx >> 5;
  int q = idx & 31;
  if (r >= NPTS) return;
  int U = *Up;
  float4 v = {0.f, 0.f, 0.f, 0.f};
  if (r < U)
    v = (q < 16) ? *(const float4*)&maccm[(size_t)r*64 + q*4]
                 : *(const float4*)&maccl[(size_t)r*64 + (q-16)*4];
  *(float4*)&mg[(size_t)r*128 + q*4] = v;
  if (r >= U) {
    float4 z = {0.f, 0.f, 0.f, 0.f};
    *(float4*)&vf[(size_t)r*128 + q*4] = z;
  }
  if (q == 0) {
    float4 co;
    if (r < U) {
      int lin = uniq[r];
      int x = lin % TGX; int t = lin / TGX;
      int y = t % TGY;   t /= TGY;
      int z = t % TGZ;   int b = t / TGZ;
      co.x = (float)b; co.y = (float)z; co.z = (float)y; co.w = (float)x;
    } else {
      co.x = -1.f; co.y = -1.f; co.z = -1.f; co.w = -1.f;
    }
    *(float4*)&coors[(size_t)r*4] = co;
  }
}

extern "C" void kernel_launch(void* const* d_in, const int* in_sizes, int n_in,
                              void* d_out, int out_size, void* d_ws, size_t ws_size,
                              hipStream_t stream) {
  const float* pts = (const float*)d_in[0];

  float* out = (float*)d_out;
  float* vf = out;                              // N x 128 (final vf)
  float* mg = out + (size_t)NPTS * 128;         // N x 128 (merged)
  float* co = out + (size_t)NPTS * 256;         // N x 4   (coors)

  char* w = (char*)d_ws;
  size_t off = 0;
  auto alloc = [&](size_t bytes) -> void* {
    void* p = w + off;
    off = (off + bytes + 1023) & ~(size_t)1023;
    return p;
  };
  int*    cnt_t   = (int*)alloc(((size_t)G_TOPC + G_MEDC + G_LOWC) * 4);
  int*    cnt_m   = cnt_t + G_TOPC;
  int*    cnt_l   = cnt_t + G_TOPC + G_MEDC;
  int*    rank_t  = (int*)alloc((size_t)G_TOPC * 4);
  int*    rank_m  = (int*)alloc((size_t)G_MEDC * 4);
  int*    rank_l  = (int*)alloc((size_t)G_LOWC * 4);
  int*    uniq_t  = (int*)alloc((size_t)G_TOPC * 4);
  int*    uniq_m  = (int*)alloc((size_t)NPTS * 4);
  int*    uniq_l  = (int*)alloc((size_t)NPTS * 4);
  int*    woff_t  = (int*)alloc((size_t)G_TOPC * 4);
  int*    woff_m  = (int*)alloc((size_t)NPTS * 4);
  int*    woff_l  = (int*)alloc((size_t)NPTS * 4);
  float4* srt_t   = (float4*)alloc((size_t)NPTS * 16);
  float4* srt_m   = (float4*)alloc((size_t)NPTS * 16);
  float4* srt_l   = (float4*)alloc((size_t)NPTS * 16);
  int*    jr_t    = (int*)alloc((size_t)NPTS * 4);
  int*    jr_m    = (int*)alloc((size_t)NPTS * 4);
  int*    jr_l    = (int*)alloc((size_t)NPTS * 4);
  float4* vm_t    = (float4*)alloc((size_t)G_TOPC * 16);
  float4* vm_m    = (float4*)alloc((size_t)NPTS * 16);
  float4* vm_l    = (float4*)alloc((size_t)NPTS * 16);
  float*  segt_t  = (float*)alloc((size_t)G_TOPC * 64 * 4);
  float*  segt_m  = (float*)alloc((size_t)NPTS * 32 * 4);
  float*  segt_l  = (float*)alloc((size_t)NPTS * 32 * 4);
  float*  vox_m   = (float*)alloc((size_t)NPTS * 64 * 4);
  float*  vox_l   = (float*)alloc((size_t)NPTS * 64 * 4);
  unsigned short* Y2h_t = (unsigned short*)alloc((size_t)NPTS * 128 * 2);
  unsigned short* Y2h_m = (unsigned short*)alloc((size_t)NPTS * 64 * 2);
  unsigned short* Y2h_l = (unsigned short*)alloc((size_t)NPTS * 64 * 2);
  int*    clist_m = (int*)alloc((size_t)G_TOPC * 64 * 4);
  int*    clist_l = (int*)alloc((size_t)G_TOPC * 64 * 4);
  int*    mcnt_m  = (int*)alloc((size_t)G_TOPC * 4);
  int*    mcnt_l  = (int*)alloc((size_t)G_TOPC * 4);
  float*  maccm   = (float*)alloc((size_t)G_TOPC * 64 * 4);
  float*  maccl   = (float*)alloc((size_t)G_TOPC * 64 * 4);
  float*  part1_t = (float*)alloc((size_t)ST1BLKS * 128 * 4);
  float*  part1_m = (float*)alloc((size_t)ST1BLKS * 64 * 4);
  float*  part1_l = (float*)alloc((size_t)ST1BLKS * 64 * 4);
  float*  part2_t = (float*)alloc((size_t)Y2B * 256 * 4);
  float*  part2_m = (float*)alloc((size_t)Y2B * 128 * 4);
  float*  part2_l = (float*)alloc((size_t)Y2B * 128 * 4);
  float*  coef    = (float*)alloc(6 * 256 * 4);
  int2*   bsum    = (int2*)alloc(1024 * 8);
  int*    Ut      = (int*)alloc(64);
  int*    Um      = (int*)alloc(64);
  int*    Ul      = (int*)alloc(64);
  (void)in_sizes; (void)n_in; (void)out_size; (void)ws_size;

  auto mkSP = [&](int scaleIdx) -> SP {
    SP s{};
    if (scaleIdx == 0) {
      s.srt = srt_t; s.jr = jr_t; s.vm = vm_t;
      s.W1 = (const float*)d_in[2];  s.g1 = (const float*)d_in[3];
      s.b1 = (const float*)d_in[4];  s.W2 = (const float*)d_in[5];
      s.g2 = (const float*)d_in[6];  s.b2 = (const float*)d_in[7];
      s.cnt = cnt_t; s.uniq = uniq_t; s.woff = woff_t; s.U = Ut;
      s.segt = segt_t; s.part1 = part1_t; s.part2 = part2_t;
      s.coef1 = coef + 0*256; s.coef2 = coef + 1*256;
      s.Y2 = Y2h_t; s.hout = vf;
      s.C1 = 64; s.segstride = G_TOPC;
      s.gx = 176; s.gy = 200; s.gz = 1; s.vx = 0.4f; s.vy = 0.4f; s.vz = 4.0f;
    } else if (scaleIdx == 1) {
      s.srt = srt_m; s.jr = jr_m; s.vm = vm_m;
      s.W1 = (const float*)d_in[8];  s.g1 = (const float*)d_in[9];
      s.b1 = (const float*)d_in[10]; s.W2 = (const float*)d_in[11];
      s.g2 = (const float*)d_in[12]; s.b2 = (const float*)d_in[13];
      s.cnt = cnt_m; s.uniq = uniq_m; s.woff = woff_m; s.U = Um;
      s.segt = segt_m; s.part1 = part1_m; s.part2 = part2_m;
      s.coef1 = coef + 2*256; s.coef2 = coef + 3*256;
      s.Y2 = Y2h_m; s.hout = vox_m;
      s.C1 = 32; s.segstride = NPTS;
      s.gx = 352; s.gy = 400; s.gz = 2; s.vx = 0.2f; s.vy = 0.2f; s.vz = 2.0f;
    } else {
      s.srt = srt_l; s.jr = jr_l; s.vm = vm_l;
      s.W1 = (const float*)d_in[14]; s.g1 = (const float*)d_in[15];
      s.b1 = (const float*)d_in[16]; s.W2 = (const float*)d_in[17];
      s.g2 = (const float*)d_in[18]; s.b2 = (const float*)d_in[19];
      s.cnt = cnt_l; s.uniq = uniq_l; s.woff = woff_l; s.U = Ul;
      s.segt = segt_l; s.part1 = part1_l; s.part2 = part2_l;
      s.coef1 = coef + 4*256; s.coef2 = coef + 5*256;
      s.Y2 = Y2h_l; s.hout = vox_l;
      s.C1 = 32; s.segstride = NPTS;
      s.gx = 704; s.gy = 800; s.gz = 4; s.vx = 0.1f; s.vy = 0.1f; s.vz = 1.0f;
    }
    return s;
  };
  SP spT = mkSP(0), spM = mkSP(1), spL = mkSP(2);

  // ---- batched voxelization front-end ----
  (void)hipMemsetAsync(cnt_t, 0, ((size_t)G_TOPC + G_MEDC + G_LOWC) * 4, stream);
  k_count3<<<NPTS/BLK, BLK, 0, stream>>>(pts, cnt_t, cnt_m, cnt_l);
  k_scan1_all<<<NB_T + NB_M + NB_L, BLK, 0, stream>>>(cnt_t, cnt_m, cnt_l, bsum);
  k_scan2_all<<<1, 1024, 0, stream>>>(bsum, Ut, Um, Ul);
  k_scan3_all<<<NB_T + NB_M + NB_L, BLK, 0, stream>>>(cnt_t, cnt_m, cnt_l, bsum,
      rank_t, rank_m, rank_l, uniq_t, uniq_m, uniq_l, woff_t, woff_m, woff_l);
  k_clist_all<<<2*NCL, BLK, 0, stream>>>(uniq_t, Ut,
      cnt_m, rank_m, clist_m, mcnt_m, cnt_l, rank_l, clist_l, mcnt_l);
  k_scatter3<<<NPTS/BLK, BLK, 0, stream>>>(pts,
      rank_t, woff_t, srt_t, jr_t,
      rank_m, woff_m, srt_m, jr_m,
      rank_l, woff_l, srt_l, jr_l);
  k_vox13<<<NBVT + NBVM + NBVL, BLK, 0, stream>>>(
      srt_t, uniq_t, cnt_t, woff_t, Ut, vm_t,
      srt_m, uniq_m, cnt_m, woff_m, Um, vm_m,
      srt_l, uniq_l, cnt_l, woff_l, Ul, vm_l);

  // ---- batched VFE pipeline (all scales per stage) ----
  k_stats1_all<<<3*ST1BLKS, BLK, 0, stream>>>(spT, spM, spL);
  k_partcoef1_all<<<128, BLK, 0, stream>>>(spT, spM, spL);
  k_hsegT_all<<<NHT + 2*NHM, BLK, 0, stream>>>(spT, spM, spL);
  k_y2t_all<<<3*Y2B, BLK, 0, stream>>>(spT, spM, spL);
  k_partcoef2_all<<<256, BLK, 0, stream>>>(spT, spM, spL);
  k_hseg2_all<<<NJT + 2*NJM, BLK, 0, stream>>>(spT, spM, spL);

  // ---- merges + final outputs ----
  k_merge2_all<<<2*NHT, BLK, 0, stream>>>(vox_m, clist_m, mcnt_m, maccm,
      vox_l, clist_l, mcnt_l, maccl, Ut);
  k_fin_all<<<(NPTS*32)/BLK, BLK, 0, stream>>>(uniq_t, Ut, maccm, maccl,
      vf, mg, co);
}

// Round 11
// 692.078 us; speedup vs baseline: 1.2503x; 1.0528x over previous
//
#include <hip/hip_runtime.h>
#include <cstdint>
#include <cstddef>

#define NPTS 262144
#define BLK 256
#define TGX 176
#define TGY 200
#define TGZ 1

#define G_TOPC 70400
#define G_MEDC 1126400
#define G_LOWC 4505600

#define SCAN_ITEMS 32
#define SCAN_CHUNK (BLK*SCAN_ITEMS)
// batched scan block counts / bsum offsets (disjoint: [0,9) [16,154) [160,710))
#define NB_T 9
#define NB_M 138
#define NB_L 550
#define BO_T 0
#define BO_M 16
#define BO_L 160
// vox13 block split
#define NBVT (G_TOPC/BLK)      // 275
#define NBVM (NPTS/BLK)        // 1024
#define NBVL (NPTS/BLK)        // 1024

#define Y2B2 (NPTS/64)         // 4096 blocks per scale (64-row MFMA tiles)
#define ST1BLKS 256            // stats1 blocks per scale (1024 rows each)
// batched per-scale stage grids
#define NHT 4400               // G_TOPC*16/BLK
#define NHM 8192               // NPTS*8/BLK
#define NJT 8800               // G_TOPC*32/BLK
#define NJM 16384              // NPTS*16/BLK
#define NCL 275                // G_TOPC/BLK (ceil)

typedef __attribute__((ext_vector_type(8))) short bf16x8;
typedef __attribute__((ext_vector_type(4))) float f32x4;

// ---------------- per-scale parameter pack ----------------
struct SP {
  const float4* srt; const int* jr; const float4* vm;
  const float* W1; const float* W2;
  const float* g1; const float* b1; const float* g2; const float* b2;
  const int* cnt; const int* uniq; const int* woff; const int* U;
  float* segt; float* part1; float* part2;
  float* coef1; float* coef2;
  unsigned short* Y2;          // bf16 storage
  float* hout;
  int C1; int segstride; int gx, gy, gz; float vx, vy, vz;
};

// ---------------- bf16 helpers ----------------
__device__ __forceinline__ unsigned short f2bf(float v) {
  unsigned u = __float_as_uint(v);
  u += 0x7FFFu + ((u >> 16) & 1u);      // round-to-nearest-even
  return (unsigned short)(u >> 16);
}
__device__ __forceinline__ float bf2f(unsigned short h) {
  return __uint_as_float((unsigned)h << 16);
}

// ---------------- voxel coord helpers ----------------
__device__ __forceinline__ void pcoords(float x, float y, float z,
    float vx, float vy, float vz, int gx, int gy, int gz,
    int& cx, int& cy, int& cz) {
  cx = (int)floorf((x - 0.0f)  / vx);
  cy = (int)floorf((y + 40.0f) / vy);
  cz = (int)floorf((z + 3.0f)  / vz);
  cx = min(max(cx, 0), gx - 1);
  cy = min(max(cy, 0), gy - 1);
  cz = min(max(cz, 0), gz - 1);
}

__device__ __forceinline__ int lin3(float b, float x, float y, float z,
    float vx, float vy, float vz, int gx, int gy, int gz) {
  int cx, cy, cz; pcoords(x, y, z, vx, vy, vz, gx, gy, gz, cx, cy, cz);
  return (((int)b * gz + cz) * gy + cy) * gx + cx;
}

// f-vector (10 features) — identical expression everywhere y1 is recomputed.
__device__ __forceinline__ void build_f(float4 p, float4 vm,
    float vx, float vy, float vz, int gx, int gy, int gz, float* f) {
  int cx, cy, cz; pcoords(p.x, p.y, p.z, vx, vy, vz, gx, gy, gz, cx, cy, cz);
  f[0] = p.x; f[1] = p.y; f[2] = p.z; f[3] = p.w;
  f[4] = p.x - vm.x;
  f[5] = p.y - vm.y;
  f[6] = p.z - vm.z;
  f[7] = p.x - (0.0f   + (cx + 0.5f)*vx);
  f[8] = p.y - (-40.0f + (cy + 0.5f)*vy);
  f[9] = p.z - (-3.0f  + (cz + 0.5f)*vz);
}

// ---------------- batched dense count (all 3 scales) ----------------
__global__ __launch_bounds__(BLK) void k_count3(const float* __restrict__ pts,
    int* __restrict__ ct, int* __restrict__ cm, int* __restrict__ cl) {
  int i = blockIdx.x * BLK + threadIdx.x;
  if (i >= NPTS) return;
  float b = pts[i*5+0], x = pts[i*5+1], y = pts[i*5+2], z = pts[i*5+3];
  atomicAdd(&ct[lin3(b,x,y,z, 0.4f,0.4f,4.0f, 176,200,1)], 1);
  atomicAdd(&cm[lin3(b,x,y,z, 0.2f,0.2f,2.0f, 352,400,2)], 1);
  atomicAdd(&cl[lin3(b,x,y,z, 0.1f,0.1f,1.0f, 704,800,4)], 1);
}

// ---------------- batched scans ----------------
__global__ __launch_bounds__(BLK) void k_scan1_all(const int* __restrict__ ct,
    const int* __restrict__ cm, const int* __restrict__ cl,
    int2* __restrict__ bsum) {
  int bid = blockIdx.x;
  const int* cnt; int G, bo, cb;
  if (bid < NB_T)            { cnt = ct; G = G_TOPC; bo = BO_T; cb = bid; }
  else if (bid < NB_T+NB_M)  { cnt = cm; G = G_MEDC; bo = BO_M; cb = bid - NB_T; }
  else                       { cnt = cl; G = G_LOWC; bo = BO_L; cb = bid - NB_T - NB_M; }
  int base = cb * SCAN_CHUNK + threadIdx.x * SCAN_ITEMS;
  int so = 0, sp = 0;
  #pragma unroll
  for (int k = 0; k < SCAN_ITEMS; k++) {
    int j = base + k;
    if (j < G) { int c = cnt[j]; if (c > 0) { so++; sp += c; } }
  }
  __shared__ int sho[BLK], shp[BLK];
  sho[threadIdx.x] = so; shp[threadIdx.x] = sp; __syncthreads();
  for (int off = BLK/2; off > 0; off >>= 1) {
    if (threadIdx.x < off) {
      sho[threadIdx.x] += sho[threadIdx.x + off];
      shp[threadIdx.x] += shp[threadIdx.x + off];
    }
    __syncthreads();
  }
  if (threadIdx.x == 0) { int2 v; v.x = sho[0]; v.y = shp[0]; bsum[bo + cb] = v; }
}

__device__ void scan_pass(int2* bsum, int off, int nb, int* U,
                          int* so, int* sp) {
  int t = threadIdx.x;
  int vo = 0, vp = 0;
  if (t < nb) { int2 v = bsum[off + t]; vo = v.x; vp = v.y; }
  so[t] = vo; sp[t] = vp; __syncthreads();
  for (int o = 1; o < 1024; o <<= 1) {
    int ao = (t >= o) ? so[t - o] : 0;
    int ap = (t >= o) ? sp[t - o] : 0;
    __syncthreads();
    so[t] += ao; sp[t] += ap;
    __syncthreads();
  }
  if (t < nb) { int2 e; e.x = so[t] - vo; e.y = sp[t] - vp; bsum[off + t] = e; }
  if (t == 0) *U = so[1023];
  __syncthreads();
}

__global__ __launch_bounds__(1024) void k_scan2_all(int2* __restrict__ bsum,
    int* __restrict__ Ut, int* __restrict__ Um, int* __restrict__ Ul) {
  __shared__ int so[1024], sp[1024];
  scan_pass(bsum, BO_T, NB_T, Ut, so, sp);
  scan_pass(bsum, BO_M, NB_M, Um, so, sp);
  scan_pass(bsum, BO_L, NB_L, Ul, so, sp);
}

__global__ __launch_bounds__(BLK) void k_scan3_all(const int* __restrict__ ct,
    const int* __restrict__ cm, const int* __restrict__ cl,
    const int2* __restrict__ bsum,
    int* __restrict__ rkt, int* __restrict__ rkm, int* __restrict__ rkl,
    int* __restrict__ uqt, int* __restrict__ uqm, int* __restrict__ uql,
    int* __restrict__ wot, int* __restrict__ wom, int* __restrict__ wol) {
  int bid = blockIdx.x;
  const int* cnt; int G, bo, cb; int *rank, *uniq, *woff;
  if (bid < NB_T)           { cnt=ct; G=G_TOPC; bo=BO_T; cb=bid;            rank=rkt; uniq=uqt; woff=wot; }
  else if (bid < NB_T+NB_M) { cnt=cm; G=G_MEDC; bo=BO_M; cb=bid-NB_T;       rank=rkm; uniq=uqm; woff=wom; }
  else                      { cnt=cl; G=G_LOWC; bo=BO_L; cb=bid-NB_T-NB_M;  rank=rkl; uniq=uql; woff=wol; }
  int base = cb * SCAN_CHUNK + threadIdx.x * SCAN_ITEMS;
  int so = 0, sp = 0;
  #pragma unroll
  for (int k = 0; k < SCAN_ITEMS; k++) {
    int j = base + k;
    if (j < G) { int c = cnt[j]; if (c > 0) { so++; sp += c; } }
  }
  __shared__ int sho[BLK], shp[BLK];
  sho[threadIdx.x] = so; shp[threadIdx.x] = sp; __syncthreads();
  for (int off = 1; off < BLK; off <<= 1) {
    int ao = (threadIdx.x >= off) ? sho[threadIdx.x - off] : 0;
    int ap = (threadIdx.x >= off) ? shp[threadIdx.x - off] : 0;
    __syncthreads();
    sho[threadIdx.x] += ao; shp[threadIdx.x] += ap;
    __syncthreads();
  }
  int2 bb = bsum[bo + cb];
  int ro = bb.x + sho[threadIdx.x] - so;
  int po = bb.y + shp[threadIdx.x] - sp;
  for (int k = 0; k < SCAN_ITEMS; k++) {
    int j = base + k;
    if (j < G) {
      int c = cnt[j];
      if (c > 0) { rank[j] = ro; uniq[ro] = j; woff[ro] = po; ro++; po += c; }
    }
  }
}

// ---------------- batched counting-sort scatter ----------------
__global__ __launch_bounds__(BLK) void k_scatter3(const float* __restrict__ pts,
    const int* __restrict__ rkt, int* __restrict__ wot, float4* __restrict__ st, int* __restrict__ jt,
    const int* __restrict__ rkm, int* __restrict__ wom, float4* __restrict__ sm, int* __restrict__ jm,
    const int* __restrict__ rkl, int* __restrict__ wol, float4* __restrict__ sl, int* __restrict__ jl) {
  int i = blockIdx.x * BLK + threadIdx.x;
  if (i >= NPTS) return;
  float b = pts[i*5+0], x = pts[i*5+1], y = pts[i*5+2], z = pts[i*5+3], it = pts[i*5+4];
  float4 p; p.x = x; p.y = y; p.z = z; p.w = it;
  {
    int r = rkt[lin3(b,x,y,z, 0.4f,0.4f,4.0f, 176,200,1)];
    int j = atomicAdd(&wot[r], 1); st[j] = p; jt[j] = r;
  }
  {
    int r = rkm[lin3(b,x,y,z, 0.2f,0.2f,2.0f, 352,400,2)];
    int j = atomicAdd(&wom[r], 1); sm[j] = p; jm[j] = r;
  }
  {
    int r = rkl[lin3(b,x,y,z, 0.1f,0.1f,1.0f, 704,800,4)];
    int j = atomicAdd(&wol[r], 1); sl[j] = p; jl[j] = r;
  }
}

// ---------------- batched per-voxel xyz means ----------------
__global__ __launch_bounds__(BLK) void k_vox13(
    const float4* __restrict__ st, const int* __restrict__ uqt, const int* __restrict__ ct,
    const int* __restrict__ wot, const int* __restrict__ Ut, float4* __restrict__ vt,
    const float4* __restrict__ sm, const int* __restrict__ uqm, const int* __restrict__ cm,
    const int* __restrict__ wom, const int* __restrict__ Um, float4* __restrict__ vm,
    const float4* __restrict__ sl, const int* __restrict__ uql, const int* __restrict__ cl,
    const int* __restrict__ wol, const int* __restrict__ Ul, float4* __restrict__ vl) {
  int bid = blockIdx.x;
  const float4* srt; const int *uniq, *cnt, *woff, *Up; float4* vmean; int r;
  if (bid < NBVT)           { r = bid*BLK + threadIdx.x;           srt=st; uniq=uqt; cnt=ct; woff=wot; Up=Ut; vmean=vt; }
  else if (bid < NBVT+NBVM) { r = (bid-NBVT)*BLK + threadIdx.x;    srt=sm; uniq=uqm; cnt=cm; woff=wom; Up=Um; vmean=vm; }
  else                      { r = (bid-NBVT-NBVM)*BLK + threadIdx.x; srt=sl; uniq=uql; cnt=cl; woff=wol; Up=Ul; vmean=vl; }
  if (r >= *Up) return;
  int lin = uniq[r];
  int len = cnt[lin];
  int base = woff[r] - len;
  float sx = 0.f, sy = 0.f, sz = 0.f;
  for (int k = 0; k < len; k++) {
    float4 p = srt[base + k];
    sx += p.x; sy += p.y; sz += p.z;
  }
  float il = 1.0f / (float)len;
  float4 o; o.x = sx*il; o.y = sy*il; o.z = sz*il; o.w = il;
  vmean[r] = o;
}

// ------- fused y1-compute + column sum/sumsq partials (all scales) ----------
__global__ __launch_bounds__(BLK) void k_stats1_all(SP a, SP b, SP c) {
  int s = blockIdx.x >> 8;
  int blk = blockIdx.x & 255;
  SP sp = (s == 0) ? a : ((s == 1) ? b : c);
  const int C1 = sp.C1;
  __shared__ float w[640];
  __shared__ float wsum[4][64], wsq[4][64];
  for (int t = threadIdx.x; t < 10*C1; t += BLK) w[t] = sp.W1[t];
  __syncthreads();
  float f[4][10];
  #pragma unroll
  for (int k = 0; k < 4; k++) {
    int i = blk*1024 + k*BLK + threadIdx.x;
    float4 p = sp.srt[i];
    float4 vmn = sp.vm[sp.jr[i]];
    build_f(p, vmn, sp.vx, sp.vy, sp.vz, sp.gx, sp.gy, sp.gz, f[k]);
  }
  int wv = threadIdx.x >> 6;
  int lane = threadIdx.x & 63;
  for (int o = 0; o < C1; o += 4) {
    float sacc[4] = {0,0,0,0}, qacc[4] = {0,0,0,0};
    #pragma unroll
    for (int k = 0; k < 4; k++) {
      float a0=0.f, a1=0.f, a2=0.f, a3=0.f;
      #pragma unroll
      for (int d = 0; d < 10; d++) {
        float fv = f[k][d];
        const float* wr = &w[d*C1 + o];
        a0 = fmaf(fv, wr[0], a0); a1 = fmaf(fv, wr[1], a1);
        a2 = fmaf(fv, wr[2], a2); a3 = fmaf(fv, wr[3], a3);
      }
      sacc[0] += a0; sacc[1] += a1; sacc[2] += a2; sacc[3] += a3;
      qacc[0] += a0*a0; qacc[1] += a1*a1; qacc[2] += a2*a2; qacc[3] += a3*a3;
    }
    #pragma unroll
    for (int m = 1; m < 64; m <<= 1) {
      #pragma unroll
      for (int e = 0; e < 4; e++) {
        sacc[e] += __shfl_xor(sacc[e], m);
        qacc[e] += __shfl_xor(qacc[e], m);
      }
    }
    if (lane == 0) {
      #pragma unroll
      for (int e = 0; e < 4; e++) { wsum[wv][o+e] = sacc[e]; wsq[wv][o+e] = qacc[e]; }
    }
  }
  __syncthreads();
  if (threadIdx.x < C1) {
    int ch = threadIdx.x;
    float sv = wsum[0][ch] + wsum[1][ch] + wsum[2][ch] + wsum[3][ch];
    float qv = wsq[0][ch] + wsq[1][ch] + wsq[2][ch] + wsq[3][ch];
    sp.part1[(size_t)blk*2*C1 + ch]      = sv;
    sp.part1[(size_t)blk*2*C1 + C1 + ch] = qv;
  }
}

// ---- reduce per-block partials -> BN coef (stage 1: C1; stage 2: C2) -------
__device__ __forceinline__ void partcoef_body(const float* part, int NB, int C,
    int ch, const float* g, const float* b, float* coef) {
  float s = 0.f, q = 0.f;
  for (int bk = threadIdx.x; bk < NB; bk += BLK) {
    s += part[(size_t)bk*2*C + ch];
    q += part[(size_t)bk*2*C + C + ch];
  }
  __shared__ float ss[BLK], sq[BLK];
  ss[threadIdx.x] = s; sq[threadIdx.x] = q; __syncthreads();
  for (int off = BLK/2; off > 0; off >>= 1) {
    if (threadIdx.x < off) {
      ss[threadIdx.x] += ss[threadIdx.x + off];
      sq[threadIdx.x] += sq[threadIdx.x + off];
    }
    __syncthreads();
  }
  if (threadIdx.x == 0) {
    float mu  = ss[0] * (1.0f / NPTS);
    float var = sq[0] * (1.0f / NPTS) - mu*mu;
    float sc  = g[ch] * (1.0f / sqrtf(var + 1e-3f));
    coef[ch]     = sc;
    coef[C + ch] = fmaf(-mu, sc, b[ch]);
  }
}

__global__ __launch_bounds__(BLK) void k_partcoef1_all(SP a, SP b, SP c) {
  int bid = blockIdx.x; SP sp; int ch;
  if (bid < 64)      { sp = a; ch = bid; }
  else if (bid < 96) { sp = b; ch = bid - 64; }
  else               { sp = c; ch = bid - 96; }
  if (ch >= sp.C1) return;
  partcoef_body(sp.part1, ST1BLKS, sp.C1, ch, sp.g1, sp.b1, sp.coef1);
}

__global__ __launch_bounds__(BLK) void k_partcoef2_all(SP a, SP b, SP c) {
  int bid = blockIdx.x; SP sp; int ch;
  if (bid < 128)      { sp = a; ch = bid; }
  else if (bid < 192) { sp = b; ch = bid - 128; }
  else                { sp = c; ch = bid - 192; }
  if (ch >= 2*sp.C1) return;
  partcoef_body(sp.part2, Y2B2, 2*sp.C1, ch, sp.g2, sp.b2, sp.coef2);
}

// ---- layer-1 voxel means of BN+ReLU(y1), y1 recomputed (all scales) --------
__global__ __launch_bounds__(BLK) void k_hsegT_all(SP a, SP b, SP c) {
  int bid = blockIdx.x; SP sp; int rb;
  if (bid < NHT)           { sp = a; rb = bid; }
  else if (bid < NHT+NHM)  { sp = b; rb = bid - NHT; }
  else                     { sp = c; rb = bid - NHT - NHM; }
  const int C1 = sp.C1;
  const int qsh = (C1 == 64) ? 4 : 3;
  __shared__ float w[640];
  __shared__ float sc[64], sb[64];
  for (int t = threadIdx.x; t < 10*C1; t += BLK) w[t] = sp.W1[t];
  for (int t = threadIdx.x; t < C1; t += BLK) { sc[t] = sp.coef1[t]; sb[t] = sp.coef1[C1 + t]; }
  __syncthreads();
  int tid = rb * BLK + threadIdx.x;
  int r = tid >> qsh;
  int q = tid & ((1 << qsh) - 1);
  if (r >= *sp.U) return;
  int lin = sp.uniq[r];
  int len = sp.cnt[lin];
  int base = sp.woff[r] - len;
  float4 vmn = sp.vm[r];
  int c0 = q * 4;
  float s0 = sc[c0+0], s1 = sc[c0+1], s2 = sc[c0+2], s3 = sc[c0+3];
  float o0 = sb[c0+0], o1 = sb[c0+1], o2 = sb[c0+2], o3 = sb[c0+3];
  float a0=0.f, a1=0.f, a2=0.f, a3=0.f;
  for (int k = 0; k < len; k++) {
    float4 p = sp.srt[base + k];
    float f[10];
    build_f(p, vmn, sp.vx, sp.vy, sp.vz, sp.gx, sp.gy, sp.gz, f);
    float y0=0.f, y1=0.f, y2=0.f, y3=0.f;
    #pragma unroll
    for (int d = 0; d < 10; d++) {
      float fv = f[d];
      const float* wr = &w[d*C1 + c0];
      y0 = fmaf(fv, wr[0], y0); y1 = fmaf(fv, wr[1], y1);
      y2 = fmaf(fv, wr[2], y2); y3 = fmaf(fv, wr[3], y3);
    }
    a0 += fmaxf(fmaf(y0, s0, o0), 0.f);
    a1 += fmaxf(fmaf(y1, s1, o1), 0.f);
    a2 += fmaxf(fmaf(y2, s2, o2), 0.f);
    a3 += fmaxf(fmaf(y3, s3, o3), 0.f);
  }
  float il = 1.0f / (float)len;
  sp.segt[(size_t)(c0+0)*sp.segstride + r] = a0*il;
  sp.segt[(size_t)(c0+1)*sp.segstride + r] = a1*il;
  sp.segt[(size_t)(c0+2)*sp.segstride + r] = a2*il;
  sp.segt[(size_t)(c0+3)*sp.segstride + r] = a3*il;
}

// ---- pack W2 -> bf16 B fragments (lane order for mfma 16x16x32) ------------
__global__ __launch_bounds__(BLK) void k_packB_all(
    const float* __restrict__ W2t_, unsigned short* __restrict__ Bt,
    const float* __restrict__ W2m_, unsigned short* __restrict__ Bm,
    const float* __restrict__ W2l_, unsigned short* __restrict__ Bl) {
  int bid = blockIdx.x;
  const float* W2; unsigned short* Bp; int C2, idx;
  if (bid < 64)      { W2 = W2t_; Bp = Bt; C2 = 128; idx = bid*BLK + threadIdx.x; }
  else if (bid < 80) { W2 = W2m_; Bp = Bm; C2 = 64;  idx = (bid-64)*BLK + threadIdx.x; }
  else               { W2 = W2l_; Bp = Bl; C2 = 64;  idx = (bid-80)*BLK + threadIdx.x; }
  if (idx >= C2*C2) return;            // K == C2 for all scales
  int NCF = C2/16;
  int per_kb = NCF*512;
  int kb = idx / per_kb, rem = idx % per_kb;
  int cf = rem / 512, r2 = rem % 512;
  int lane = r2 >> 3, j = r2 & 7;
  int k = kb*32 + (lane >> 4)*8 + j;
  int col = cf*16 + (lane & 15);
  Bp[idx] = f2bf(W2[(size_t)k*C2 + col]);
}

// ------- layer 2 as MFMA bf16 GEMM (64-row tiles); fused column stats -------
template<int C1>
__device__ __forceinline__ void y2m_body(const SP& sp,
    const unsigned short* __restrict__ Bpk, int blk, unsigned short* Alds) {
  constexpr int K   = 2*C1;
  constexpr int C2  = 2*C1;
  constexpr int MT  = 64;
  constexpr int NKB = K / 32;          // 4 (top), 2 (med/low)
  constexpr int NCF = C2 / 16;         // 8 (top), 4 (med/low)
  constexpr int RB  = K * 2;           // row bytes in Alds
  const int tid  = threadIdx.x;
  const int base = blk * MT;

  // ---- stage A tile (bf16, XOR-swizzled): 4 threads/row, K/4 channels each
  {
    const int jst = tid & 63;
    const int qst = tid >> 6;          // wave id == channel-quarter (wave-uniform)
    int jr = sp.jr[base + jst];
    float4 p = sp.srt[base + jst];
    float4 vmn = sp.vm[jr];
    float fs[10];
    build_f(p, vmn, sp.vx, sp.vy, sp.vz, sp.gx, sp.gy, sp.gz, fs);
    const int k_lo = qst * (K/4);
    #pragma unroll
    for (int kk = 0; kk < K/8; kk++) {
      int k0 = k_lo + kk*2;
      float v0, v1;
      if (k0 < C1) {
        float y0 = 0.f, y1v = 0.f;
        #pragma unroll
        for (int d = 0; d < 10; d++) {
          y0  = fmaf(fs[d], sp.W1[d*C1 + k0],     y0);
          y1v = fmaf(fs[d], sp.W1[d*C1 + k0 + 1], y1v);
        }
        v0 = fmaxf(fmaf(y0,  sp.coef1[k0],   sp.coef1[C1 + k0]),   0.f);
        v1 = fmaxf(fmaf(y1v, sp.coef1[k0+1], sp.coef1[C1 + k0+1]), 0.f);
      } else {
        v0 = sp.segt[(size_t)(k0     - C1)*sp.segstride + jr];
        v1 = sp.segt[(size_t)(k0 + 1 - C1)*sp.segstride + jr];
      }
      unsigned u = (unsigned)f2bf(v0) | ((unsigned)f2bf(v1) << 16);
      int g  = k0 >> 3;
      int gp = g ^ (jst & 7);
      *(unsigned*)((char*)Alds + (size_t)jst*RB + gp*16 + (k0 & 7)*2) = u;
    }
  }
  __syncthreads();

  // ---- MFMA main loop: wave w owns rows [w*16, w*16+16) ----
  const int w    = tid >> 6;
  const int l    = tid & 63;
  const int rowf = l & 15;
  const int kg   = l >> 4;
  const int row  = w*16 + rowf;
  f32x4 acc[NCF];
  #pragma unroll
  for (int cf = 0; cf < NCF; cf++) acc[cf] = (f32x4){0.f, 0.f, 0.f, 0.f};
  #pragma unroll
  for (int kb = 0; kb < NKB; kb++) {
    int g  = kb*4 + kg;
    int gp = g ^ (row & 7);
    bf16x8 a = *(const bf16x8*)((const char*)Alds + (size_t)row*RB + gp*16);
    const bf16x8* bfr = (const bf16x8*)Bpk + (size_t)(kb*NCF)*64 + l;
    #pragma unroll
    for (int cf = 0; cf < NCF; cf++) {
      bf16x8 b = bfr[cf*64];
      acc[cf] = __builtin_amdgcn_mfma_f32_16x16x32_bf16(a, b, acc[cf], 0, 0, 0);
    }
  }

  // ---- fused column sum/sumsq partials from fp32 acc (reuse Alds) ----
  __syncthreads();
  float* red = (float*)Alds;           // [32][C2] floats == Alds byte size
  #pragma unroll
  for (int cf = 0; cf < NCF; cf++) {
    f32x4 v = acc[cf];
    float sv = v.x + v.y + v.z + v.w;
    float qv = v.x*v.x + v.y*v.y + v.z*v.z + v.w*v.w;
    red[(w*4 + kg)*C2 + cf*16 + rowf]        = sv;
    red[(16 + w*4 + kg)*C2 + cf*16 + rowf]   = qv;
  }
  __syncthreads();
  if (tid < C2) {
    float sv = 0.f, qv = 0.f;
    #pragma unroll 4
    for (int i = 0; i < 16; i++) {
      sv += red[i*C2 + tid];
      qv += red[(16 + i)*C2 + tid];
    }
    sp.part2[(size_t)blk*2*C2 + tid]      = sv;
    sp.part2[(size_t)blk*2*C2 + C2 + tid] = qv;
  }
  __syncthreads();

  // ---- D -> LDS (bf16, row-major) -> coalesced global store ----
  unsigned short* D = Alds;
  #pragma unroll
  for (int cf = 0; cf < NCF; cf++) {
    #pragma unroll
    for (int rg = 0; rg < 4; rg++) {
      int rr = w*16 + kg*4 + rg;       // C/D: col=lane&15, row=(lane>>4)*4+reg
      D[rr*C2 + cf*16 + rowf] = f2bf(acc[cf][rg]);
    }
  }
  __syncthreads();
  for (int it = tid; it < MT*C2/8; it += BLK) {
    int r = (it*8) / C2;
    int c = (it*8) % C2;
    uint4 v = *(const uint4*)&D[it*8];
    *(uint4*)&sp.Y2[(size_t)(base + r)*C2 + c] = v;
  }
}

__global__ __launch_bounds__(BLK) void k_y2m_all(SP a, SP b, SP c,
    const unsigned short* __restrict__ Bt, const unsigned short* __restrict__ Bm,
    const unsigned short* __restrict__ Bl) {
  __shared__ unsigned short Alds[64*128];   // 16 KB (med/low use half)
  int bid = blockIdx.x;
  if (bid < Y2B2)        y2m_body<64>(a, Bt, bid, Alds);
  else if (bid < 2*Y2B2) y2m_body<32>(b, Bm, bid - Y2B2, Alds);
  else                   y2m_body<32>(c, Bl, bid - 2*Y2B2, Alds);
}

// -------- layer-2 BN+ReLU + voxel mean (bf16 Y2, all scales) ----------------
__global__ __launch_bounds__(BLK) void k_hseg2_all(SP a, SP b, SP c) {
  int bid = blockIdx.x; SP sp; int rb;
  if (bid < NJT)           { sp = a; rb = bid; }
  else if (bid < NJT+NJM)  { sp = b; rb = bid - NJT; }
  else                     { sp = c; rb = bid - NJT - NJM; }
  const int C = 2*sp.C1;
  const int qsh = (C == 128) ? 5 : 4;
  __shared__ float sc[128], sb[128];
  for (int t = threadIdx.x; t < C; t += BLK) { sc[t] = sp.coef2[t]; sb[t] = sp.coef2[C + t]; }
  __syncthreads();
  int tid = rb * BLK + threadIdx.x;
  int r = tid >> qsh;
  int q = tid & ((1 << qsh) - 1);
  if (r >= *sp.U) return;
  int lin = sp.uniq[r];
  int len = sp.cnt[lin];
  int base = sp.woff[r] - len;
  int c0 = q * 4;
  float s0 = sc[c0+0], s1 = sc[c0+1], s2 = sc[c0+2], s3 = sc[c0+3];
  float o0 = sb[c0+0], o1 = sb[c0+1], o2 = sb[c0+2], o3 = sb[c0+3];
  float a0=0.f, a1=0.f, a2=0.f, a3=0.f;
  const unsigned short* Yh = sp.Y2;
  for (int k = 0; k < len; k++) {
    ushort4 hv = *(const ushort4*)&Yh[(size_t)(base + k)*C + c0];
    a0 += fmaxf(fmaf(bf2f(hv.x), s0, o0), 0.f);
    a1 += fmaxf(fmaf(bf2f(hv.y), s1, o1), 0.f);
    a2 += fmaxf(fmaf(bf2f(hv.z), s2, o2), 0.f);
    a3 += fmaxf(fmaf(bf2f(hv.w), s3, o3), 0.f);
  }
  float il = 1.0f / (float)len;
  float4 o = {a0*il, a1*il, a2*il, a3*il};
  *(float4*)&sp.hout[(size_t)r*C + c0] = o;
}

// ------------- merge: per-parent child-rank lists (med+low batched) ---------
__global__ __launch_bounds__(BLK) void k_clist_all(const int* __restrict__ tuniq,
    const int* __restrict__ Utp,
    const int* __restrict__ cnt_m, const int* __restrict__ rank_m,
    int* __restrict__ clist_m, int* __restrict__ mcnt_m,
    const int* __restrict__ cnt_l, const int* __restrict__ rank_l,
    int* __restrict__ clist_l, int* __restrict__ mcnt_l) {
  int bid = blockIdx.x;
  const int *scnt, *srank; int *clist, *mcnt;
  int gx, gy, gz, f, rb;
  if (bid < NCL) { scnt=cnt_m; srank=rank_m; clist=clist_m; mcnt=mcnt_m;
                   gx=352; gy=400; gz=2; f=2; rb=bid; }
  else           { scnt=cnt_l; srank=rank_l; clist=clist_l; mcnt=mcnt_l;
                   gx=704; gy=800; gz=4; f=4; rb=bid-NCL; }
  int r = rb * BLK + threadIdx.x;
  if (r >= *Utp) return;
  int lin = tuniq[r];
  int x = lin % TGX; int t = lin / TGX;
  int y = t % TGY;   int b = t / TGY;   // TGZ == 1 so z == 0
  int m = 0;
  for (int cz = 0; cz < gz; cz++)
    for (int yy = y*f; yy < y*f + f; yy++)
      for (int xx = x*f; xx < x*f + f; xx++) {
        int cl = ((b*gz + cz)*gy + yy)*gx + xx;
        if (scnt[cl] > 0) clist[(size_t)r*64 + (m++)] = srank[cl];
      }
  mcnt[r] = m;
}

__global__ __launch_bounds__(BLK) void k_merge2_all(
    const float* __restrict__ vox_m, const int* __restrict__ clist_m,
    const int* __restrict__ mcnt_m, float* __restrict__ maccm,
    const float* __restrict__ vox_l, const int* __restrict__ clist_l,
    const int* __restrict__ mcnt_l, float* __restrict__ maccl,
    const int* __restrict__ Utp) {
  int bid = blockIdx.x;
  const float* vox; const int *clist, *mcnt; float* dest; int rb;
  if (bid < NHT) { vox=vox_m; clist=clist_m; mcnt=mcnt_m; dest=maccm; rb=bid; }
  else           { vox=vox_l; clist=clist_l; mcnt=mcnt_l; dest=maccl; rb=bid-NHT; }
  int idx = rb * BLK + threadIdx.x;
  int r = idx >> 4;
  int q = idx & 15;
  if (r >= *Utp) return;
  int m = mcnt[r];
  float a0=0.f, a1=0.f, a2=0.f, a3=0.f;
  for (int t = 0; t < m; t++) {
    int cr = clist[(size_t)r*64 + t];
    float4 v = *(const float4*)&vox[(size_t)cr*64 + q*4];
    a0 += v.x; a1 += v.y; a2 += v.z; a3 += v.w;
  }
  float inv = 1.0f / (float)max(m, 1);
  float4 o = {a0*inv, a1*inv, a2*inv, a3*inv};
  *(float4*)&dest[(size_t)r*64 + q*4] = o;
}

// ---- final: vf tail zero + coors + merged compose (one kernel) -------------
__global__ __launch_bounds__(BLK) void k_fin_all(const int* __restrict__ uniq,
    const int* __restrict__ Up, const float* __restrict__ maccm,
    const float* __restrict__ maccl, float* __restrict__ vf,
    float* __restrict__ mg, float* __restrict__ coors) {
  int idx = blockIdx.x * BLK + threadIdx.x;
  int r = idx >> 5;
  int q = idx & 31;
  if (r >= NPTS) return;
  int U = *Up;
  float4 v = {0.f, 0.f, 0.f, 0.f};
  if (r < U)
    v = (q < 16) ? *(const float4*)&maccm[(size_t)r*64 + q*4]
                 : *(const float4*)&maccl[(size_t)r*64 + (q-16)*4];
  *(float4*)&mg[(size_t)r*128 + q*4] = v;
  if (r >= U) {
    float4 z = {0.f, 0.f, 0.f, 0.f};
    *(float4*)&vf[(size_t)r*128 + q*4] = z;
  }
  if (q == 0) {
    float4 co;
    if (r < U) {
      int lin = uniq[r];
      int x = lin % TGX; int t = lin / TGX;
      int y = t % TGY;   t /= TGY;
      int z = t % TGZ;   int b = t / TGZ;
      co.x = (float)b; co.y = (float)z; co.z = (float)y; co.w = (float)x;
    } else {
      co.x = -1.f; co.y = -1.f; co.z = -1.f; co.w = -1.f;
    }
    *(float4*)&coors[(size_t)r*4] = co;
  }
}

extern "C" void kernel_launch(void* const* d_in, const int* in_sizes, int n_in,
                              void* d_out, int out_size, void* d_ws, size_t ws_size,
                              hipStream_t stream) {
  const float* pts = (const float*)d_in[0];

  float* out = (float*)d_out;
  float* vf = out;                              // N x 128 (final vf)
  float* mg = out + (size_t)NPTS * 128;         // N x 128 (merged)
  float* co = out + (size_t)NPTS * 256;         // N x 4   (coors)

  char* w = (char*)d_ws;
  size_t off = 0;
  auto alloc = [&](size_t bytes) -> void* {
    void* p = w + off;
    off = (off + bytes + 1023) & ~(size_t)1023;
    return p;
  };
  int*    cnt_t   = (int*)alloc(((size_t)G_TOPC + G_MEDC + G_LOWC) * 4);
  int*    cnt_m   = cnt_t + G_TOPC;
  int*    cnt_l   = cnt_t + G_TOPC + G_MEDC;
  int*    rank_t  = (int*)alloc((size_t)G_TOPC * 4);
  int*    rank_m  = (int*)alloc((size_t)G_MEDC * 4);
  int*    rank_l  = (int*)alloc((size_t)G_LOWC * 4);
  int*    uniq_t  = (int*)alloc((size_t)G_TOPC * 4);
  int*    uniq_m  = (int*)alloc((size_t)NPTS * 4);
  int*    uniq_l  = (int*)alloc((size_t)NPTS * 4);
  int*    woff_t  = (int*)alloc((size_t)G_TOPC * 4);
  int*    woff_m  = (int*)alloc((size_t)NPTS * 4);
  int*    woff_l  = (int*)alloc((size_t)NPTS * 4);
  float4* srt_t   = (float4*)alloc((size_t)NPTS * 16);
  float4* srt_m   = (float4*)alloc((size_t)NPTS * 16);
  float4* srt_l   = (float4*)alloc((size_t)NPTS * 16);
  int*    jr_t    = (int*)alloc((size_t)NPTS * 4);
  int*    jr_m    = (int*)alloc((size_t)NPTS * 4);
  int*    jr_l    = (int*)alloc((size_t)NPTS * 4);
  float4* vm_t    = (float4*)alloc((size_t)G_TOPC * 16);
  float4* vm_m    = (float4*)alloc((size_t)NPTS * 16);
  float4* vm_l    = (float4*)alloc((size_t)NPTS * 16);
  float*  segt_t  = (float*)alloc((size_t)G_TOPC * 64 * 4);
  float*  segt_m  = (float*)alloc((size_t)NPTS * 32 * 4);
  float*  segt_l  = (float*)alloc((size_t)NPTS * 32 * 4);
  float*  vox_m   = (float*)alloc((size_t)NPTS * 64 * 4);
  float*  vox_l   = (float*)alloc((size_t)NPTS * 64 * 4);
  unsigned short* Y2h_t = (unsigned short*)alloc((size_t)NPTS * 128 * 2);
  unsigned short* Y2h_m = (unsigned short*)alloc((size_t)NPTS * 64 * 2);
  unsigned short* Y2h_l = (unsigned short*)alloc((size_t)NPTS * 64 * 2);
  unsigned short* Bpk_t = (unsigned short*)alloc(16384 * 2);
  unsigned short* Bpk_m = (unsigned short*)alloc(4096 * 2);
  unsigned short* Bpk_l = (unsigned short*)alloc(4096 * 2);
  int*    clist_m = (int*)alloc((size_t)G_TOPC * 64 * 4);
  int*    clist_l = (int*)alloc((size_t)G_TOPC * 64 * 4);
  int*    mcnt_m  = (int*)alloc((size_t)G_TOPC * 4);
  int*    mcnt_l  = (int*)alloc((size_t)G_TOPC * 4);
  float*  maccm   = (float*)alloc((size_t)G_TOPC * 64 * 4);
  float*  maccl   = (float*)alloc((size_t)G_TOPC * 64 * 4);
  float*  part1_t = (float*)alloc((size_t)ST1BLKS * 128 * 4);
  float*  part1_m = (float*)alloc((size_t)ST1BLKS * 64 * 4);
  float*  part1_l = (float*)alloc((size_t)ST1BLKS * 64 * 4);
  float*  part2_t = (float*)alloc((size_t)Y2B2 * 256 * 4);
  float*  part2_m = (float*)alloc((size_t)Y2B2 * 128 * 4);
  float*  part2_l = (float*)alloc((size_t)Y2B2 * 128 * 4);
  float*  coef    = (float*)alloc(6 * 256 * 4);
  int2*   bsum    = (int2*)alloc(1024 * 8);
  int*    Ut      = (int*)alloc(64);
  int*    Um      = (int*)alloc(64);
  int*    Ul      = (int*)alloc(64);
  (void)in_sizes; (void)n_in; (void)out_size; (void)ws_size;

  auto mkSP = [&](int scaleIdx) -> SP {
    SP s{};
    if (scaleIdx == 0) {
      s.srt = srt_t; s.jr = jr_t; s.vm = vm_t;
      s.W1 = (const float*)d_in[2];  s.g1 = (const float*)d_in[3];
      s.b1 = (const float*)d_in[4];  s.W2 = (const float*)d_in[5];
      s.g2 = (const float*)d_in[6];  s.b2 = (const float*)d_in[7];
      s.cnt = cnt_t; s.uniq = uniq_t; s.woff = woff_t; s.U = Ut;
      s.segt = segt_t; s.part1 = part1_t; s.part2 = part2_t;
      s.coef1 = coef + 0*256; s.coef2 = coef + 1*256;
      s.Y2 = Y2h_t; s.hout = vf;
      s.C1 = 64; s.segstride = G_TOPC;
      s.gx = 176; s.gy = 200; s.gz = 1; s.vx = 0.4f; s.vy = 0.4f; s.vz = 4.0f;
    } else if (scaleIdx == 1) {
      s.srt = srt_m; s.jr = jr_m; s.vm = vm_m;
      s.W1 = (const float*)d_in[8];  s.g1 = (const float*)d_in[9];
      s.b1 = (const float*)d_in[10]; s.W2 = (const float*)d_in[11];
      s.g2 = (const float*)d_in[12]; s.b2 = (const float*)d_in[13];
      s.cnt = cnt_m; s.uniq = uniq_m; s.woff = woff_m; s.U = Um;
      s.segt = segt_m; s.part1 = part1_m; s.part2 = part2_m;
      s.coef1 = coef + 2*256; s.coef2 = coef + 3*256;
      s.Y2 = Y2h_m; s.hout = vox_m;
      s.C1 = 32; s.segstride = NPTS;
      s.gx = 352; s.gy = 400; s.gz = 2; s.vx = 0.2f; s.vy = 0.2f; s.vz = 2.0f;
    } else {
      s.srt = srt_l; s.jr = jr_l; s.vm = vm_l;
      s.W1 = (const float*)d_in[14]; s.g1 = (const float*)d_in[15];
      s.b1 = (const float*)d_in[16]; s.W2 = (const float*)d_in[17];
      s.g2 = (const float*)d_in[18]; s.b2 = (const float*)d_in[19];
      s.cnt = cnt_l; s.uniq = uniq_l; s.woff = woff_l; s.U = Ul;
      s.segt = segt_l; s.part1 = part1_l; s.part2 = part2_l;
      s.coef1 = coef + 4*256; s.coef2 = coef + 5*256;
      s.Y2 = Y2h_l; s.hout = vox_l;
      s.C1 = 32; s.segstride = NPTS;
      s.gx = 704; s.gy = 800; s.gz = 4; s.vx = 0.1f; s.vy = 0.1f; s.vz = 1.0f;
    }
    return s;
  };
  SP spT = mkSP(0), spM = mkSP(1), spL = mkSP(2);

  // ---- W2 bf16 fragment pre-pack (no deps beyond inputs) ----
  k_packB_all<<<96, BLK, 0, stream>>>((const float*)d_in[5], Bpk_t,
      (const float*)d_in[11], Bpk_m, (const float*)d_in[17], Bpk_l);

  // ---- batched voxelization front-end ----
  (void)hipMemsetAsync(cnt_t, 0, ((size_t)G_TOPC + G_MEDC + G_LOWC) * 4, stream);
  k_count3<<<NPTS/BLK, BLK, 0, stream>>>(pts, cnt_t, cnt_m, cnt_l);
  k_scan1_all<<<NB_T + NB_M + NB_L, BLK, 0, stream>>>(cnt_t, cnt_m, cnt_l, bsum);
  k_scan2_all<<<1, 1024, 0, stream>>>(bsum, Ut, Um, Ul);
  k_scan3_all<<<NB_T + NB_M + NB_L, BLK, 0, stream>>>(cnt_t, cnt_m, cnt_l, bsum,
      rank_t, rank_m, rank_l, uniq_t, uniq_m, uniq_l, woff_t, woff_m, woff_l);
  k_clist_all<<<2*NCL, BLK, 0, stream>>>(uniq_t, Ut,
      cnt_m, rank_m, clist_m, mcnt_m, cnt_l, rank_l, clist_l, mcnt_l);
  k_scatter3<<<NPTS/BLK, BLK, 0, stream>>>(pts,
      rank_t, woff_t, srt_t, jr_t,
      rank_m, woff_m, srt_m, jr_m,
      rank_l, woff_l, srt_l, jr_l);
  k_vox13<<<NBVT + NBVM + NBVL, BLK, 0, stream>>>(
      srt_t, uniq_t, cnt_t, woff_t, Ut, vm_t,
      srt_m, uniq_m, cnt_m, woff_m, Um, vm_m,
      srt_l, uniq_l, cnt_l, woff_l, Ul, vm_l);

  // ---- batched VFE pipeline (all scales per stage) ----
  k_stats1_all<<<3*ST1BLKS, BLK, 0, stream>>>(spT, spM, spL);
  k_partcoef1_all<<<128, BLK, 0, stream>>>(spT, spM, spL);
  k_hsegT_all<<<NHT + 2*NHM, BLK, 0, stream>>>(spT, spM, spL);
  k_y2m_all<<<3*Y2B2, BLK, 0, stream>>>(spT, spM, spL, Bpk_t, Bpk_m, Bpk_l);
  k_partcoef2_all<<<256, BLK, 0, stream>>>(spT, spM, spL);
  k_hseg2_all<<<NJT + 2*NJM, BLK, 0, stream>>>(spT, spM, spL);

  // ---- merges + final outputs ----
  k_merge2_all<<<2*NHT, BLK, 0, stream>>>(vox_m, clist_m, mcnt_m, maccm,
      vox_l, clist_l, mcnt_l, maccl, Ut);
  k_fin_all<<<(NPTS*32)/BLK, BLK, 0, stream>>>(uniq_t, Ut, maccm, maccl,
      vf, mg, co);
}

// Round 12
// 683.707 us; speedup vs baseline: 1.2656x; 1.0122x over previous
//
#include <hip/hip_runtime.h>
#include <cstdint>
#include <cstddef>

#define NPTS 262144
#define BLK 256
#define TGX 176
#define TGY 200
#define TGZ 1

#define G_TOPC 70400
#define G_MEDC 1126400
#define G_LOWC 4505600

#define SCAN_ITEMS 32
#define SCAN_CHUNK (BLK*SCAN_ITEMS)
// batched scan block counts / bsum offsets (disjoint: [0,9) [16,154) [160,710))
#define NB_T 9
#define NB_M 138
#define NB_L 550
#define BO_T 0
#define BO_M 16
#define BO_L 160
// vox13 block split
#define NBVT (G_TOPC/BLK)      // 275
#define NBVM (NPTS/BLK)        // 1024
#define NBVL (NPTS/BLK)        // 1024

#define Y2B2 (NPTS/64)         // 4096 blocks per scale (64-row MFMA tiles)
#define ST1BLKS 256            // fmom blocks per scale (1024 rows each)
// batched per-scale stage grids
#define NHT 4400               // G_TOPC*16/BLK
#define NHM 8192               // NPTS*8/BLK
#define NJT 8800               // G_TOPC*32/BLK
#define NJM 16384              // NPTS*16/BLK
#define NCL 275                // G_TOPC/BLK (ceil)

typedef __attribute__((ext_vector_type(8))) short bf16x8;
typedef __attribute__((ext_vector_type(4))) float f32x4;

// ---------------- per-scale parameter pack ----------------
struct SP {
  const float4* srt; const int* jr; const float4* vm;
  const float* W1; const float* W2;
  const float* g1; const float* b1; const float* g2; const float* b2;
  const int* cnt; const int* uniq; const int* woff; const int* U;
  float* segt; float* part1; float* part2;
  float* coef1; float* coef2;
  unsigned short* Y2;          // bf16 storage
  float* hout;
  int C1; int segstride; int gx, gy, gz; float vx, vy, vz;
};

// ---------------- bf16 helpers ----------------
__device__ __forceinline__ unsigned short f2bf(float v) {
  unsigned u = __float_as_uint(v);
  u += 0x7FFFu + ((u >> 16) & 1u);      // round-to-nearest-even
  return (unsigned short)(u >> 16);
}
__device__ __forceinline__ float bf2f(unsigned short h) {
  return __uint_as_float((unsigned)h << 16);
}

// ---------------- voxel coord helpers ----------------
__device__ __forceinline__ void pcoords(float x, float y, float z,
    float vx, float vy, float vz, int gx, int gy, int gz,
    int& cx, int& cy, int& cz) {
  cx = (int)floorf((x - 0.0f)  / vx);
  cy = (int)floorf((y + 40.0f) / vy);
  cz = (int)floorf((z + 3.0f)  / vz);
  cx = min(max(cx, 0), gx - 1);
  cy = min(max(cy, 0), gy - 1);
  cz = min(max(cz, 0), gz - 1);
}

__device__ __forceinline__ int lin3(float b, float x, float y, float z,
    float vx, float vy, float vz, int gx, int gy, int gz) {
  int cx, cy, cz; pcoords(x, y, z, vx, vy, vz, gx, gy, gz, cx, cy, cz);
  return (((int)b * gz + cz) * gy + cy) * gx + cx;
}

// f-vector (10 features) — identical expression everywhere y1 is recomputed.
__device__ __forceinline__ void build_f(float4 p, float4 vm,
    float vx, float vy, float vz, int gx, int gy, int gz, float* f) {
  int cx, cy, cz; pcoords(p.x, p.y, p.z, vx, vy, vz, gx, gy, gz, cx, cy, cz);
  f[0] = p.x; f[1] = p.y; f[2] = p.z; f[3] = p.w;
  f[4] = p.x - vm.x;
  f[5] = p.y - vm.y;
  f[6] = p.z - vm.z;
  f[7] = p.x - (0.0f   + (cx + 0.5f)*vx);
  f[8] = p.y - (-40.0f + (cy + 0.5f)*vy);
  f[9] = p.z - (-3.0f  + (cz + 0.5f)*vz);
}

// ---------------- batched dense count (all 3 scales) ----------------
__global__ __launch_bounds__(BLK) void k_count3(const float* __restrict__ pts,
    int* __restrict__ ct, int* __restrict__ cm, int* __restrict__ cl) {
  int i = blockIdx.x * BLK + threadIdx.x;
  if (i >= NPTS) return;
  float b = pts[i*5+0], x = pts[i*5+1], y = pts[i*5+2], z = pts[i*5+3];
  atomicAdd(&ct[lin3(b,x,y,z, 0.4f,0.4f,4.0f, 176,200,1)], 1);
  atomicAdd(&cm[lin3(b,x,y,z, 0.2f,0.2f,2.0f, 352,400,2)], 1);
  atomicAdd(&cl[lin3(b,x,y,z, 0.1f,0.1f,1.0f, 704,800,4)], 1);
}

// ---------------- batched scans ----------------
__global__ __launch_bounds__(BLK) void k_scan1_all(const int* __restrict__ ct,
    const int* __restrict__ cm, const int* __restrict__ cl,
    int2* __restrict__ bsum) {
  int bid = blockIdx.x;
  const int* cnt; int G, bo, cb;
  if (bid < NB_T)            { cnt = ct; G = G_TOPC; bo = BO_T; cb = bid; }
  else if (bid < NB_T+NB_M)  { cnt = cm; G = G_MEDC; bo = BO_M; cb = bid - NB_T; }
  else                       { cnt = cl; G = G_LOWC; bo = BO_L; cb = bid - NB_T - NB_M; }
  int base = cb * SCAN_CHUNK + threadIdx.x * SCAN_ITEMS;
  int so = 0, sp = 0;
  #pragma unroll
  for (int k = 0; k < SCAN_ITEMS; k++) {
    int j = base + k;
    if (j < G) { int c = cnt[j]; if (c > 0) { so++; sp += c; } }
  }
  __shared__ int sho[BLK], shp[BLK];
  sho[threadIdx.x] = so; shp[threadIdx.x] = sp; __syncthreads();
  for (int off = BLK/2; off > 0; off >>= 1) {
    if (threadIdx.x < off) {
      sho[threadIdx.x] += sho[threadIdx.x + off];
      shp[threadIdx.x] += shp[threadIdx.x + off];
    }
    __syncthreads();
  }
  if (threadIdx.x == 0) { int2 v; v.x = sho[0]; v.y = shp[0]; bsum[bo + cb] = v; }
}

__device__ void scan_pass(int2* bsum, int off, int nb, int* U,
                          int* so, int* sp) {
  int t = threadIdx.x;
  int vo = 0, vp = 0;
  if (t < nb) { int2 v = bsum[off + t]; vo = v.x; vp = v.y; }
  so[t] = vo; sp[t] = vp; __syncthreads();
  for (int o = 1; o < 1024; o <<= 1) {
    int ao = (t >= o) ? so[t - o] : 0;
    int ap = (t >= o) ? sp[t - o] : 0;
    __syncthreads();
    so[t] += ao; sp[t] += ap;
    __syncthreads();
  }
  if (t < nb) { int2 e; e.x = so[t] - vo; e.y = sp[t] - vp; bsum[off + t] = e; }
  if (t == 0) *U = so[1023];
  __syncthreads();
}

__global__ __launch_bounds__(1024) void k_scan2_all(int2* __restrict__ bsum,
    int* __restrict__ Ut, int* __restrict__ Um, int* __restrict__ Ul) {
  __shared__ int so[1024], sp[1024];
  scan_pass(bsum, BO_T, NB_T, Ut, so, sp);
  scan_pass(bsum, BO_M, NB_M, Um, so, sp);
  scan_pass(bsum, BO_L, NB_L, Ul, so, sp);
}

__global__ __launch_bounds__(BLK) void k_scan3_all(const int* __restrict__ ct,
    const int* __restrict__ cm, const int* __restrict__ cl,
    const int2* __restrict__ bsum,
    int* __restrict__ rkt, int* __restrict__ rkm, int* __restrict__ rkl,
    int* __restrict__ uqt, int* __restrict__ uqm, int* __restrict__ uql,
    int* __restrict__ wot, int* __restrict__ wom, int* __restrict__ wol) {
  int bid = blockIdx.x;
  const int* cnt; int G, bo, cb; int *rank, *uniq, *woff;
  if (bid < NB_T)           { cnt=ct; G=G_TOPC; bo=BO_T; cb=bid;            rank=rkt; uniq=uqt; woff=wot; }
  else if (bid < NB_T+NB_M) { cnt=cm; G=G_MEDC; bo=BO_M; cb=bid-NB_T;       rank=rkm; uniq=uqm; woff=wom; }
  else                      { cnt=cl; G=G_LOWC; bo=BO_L; cb=bid-NB_T-NB_M;  rank=rkl; uniq=uql; woff=wol; }
  int base = cb * SCAN_CHUNK + threadIdx.x * SCAN_ITEMS;
  int so = 0, sp = 0;
  #pragma unroll
  for (int k = 0; k < SCAN_ITEMS; k++) {
    int j = base + k;
    if (j < G) { int c = cnt[j]; if (c > 0) { so++; sp += c; } }
  }
  __shared__ int sho[BLK], shp[BLK];
  sho[threadIdx.x] = so; shp[threadIdx.x] = sp; __syncthreads();
  for (int off = 1; off < BLK; off <<= 1) {
    int ao = (threadIdx.x >= off) ? sho[threadIdx.x - off] : 0;
    int ap = (threadIdx.x >= off) ? shp[threadIdx.x - off] : 0;
    __syncthreads();
    sho[threadIdx.x] += ao; shp[threadIdx.x] += ap;
    __syncthreads();
  }
  int2 bb = bsum[bo + cb];
  int ro = bb.x + sho[threadIdx.x] - so;
  int po = bb.y + shp[threadIdx.x] - sp;
  for (int k = 0; k < SCAN_ITEMS; k++) {
    int j = base + k;
    if (j < G) {
      int c = cnt[j];
      if (c > 0) { rank[j] = ro; uniq[ro] = j; woff[ro] = po; ro++; po += c; }
    }
  }
}

// ---------------- batched counting-sort scatter ----------------
__global__ __launch_bounds__(BLK) void k_scatter3(const float* __restrict__ pts,
    const int* __restrict__ rkt, int* __restrict__ wot, float4* __restrict__ st, int* __restrict__ jt,
    const int* __restrict__ rkm, int* __restrict__ wom, float4* __restrict__ sm, int* __restrict__ jm,
    const int* __restrict__ rkl, int* __restrict__ wol, float4* __restrict__ sl, int* __restrict__ jl) {
  int i = blockIdx.x * BLK + threadIdx.x;
  if (i >= NPTS) return;
  float b = pts[i*5+0], x = pts[i*5+1], y = pts[i*5+2], z = pts[i*5+3], it = pts[i*5+4];
  float4 p; p.x = x; p.y = y; p.z = z; p.w = it;
  {
    int r = rkt[lin3(b,x,y,z, 0.4f,0.4f,4.0f, 176,200,1)];
    int j = atomicAdd(&wot[r], 1); st[j] = p; jt[j] = r;
  }
  {
    int r = rkm[lin3(b,x,y,z, 0.2f,0.2f,2.0f, 352,400,2)];
    int j = atomicAdd(&wom[r], 1); sm[j] = p; jm[j] = r;
  }
  {
    int r = rkl[lin3(b,x,y,z, 0.1f,0.1f,1.0f, 704,800,4)];
    int j = atomicAdd(&wol[r], 1); sl[j] = p; jl[j] = r;
  }
}

// ---------------- batched per-voxel xyz means ----------------
__global__ __launch_bounds__(BLK) void k_vox13(
    const float4* __restrict__ st, const int* __restrict__ uqt, const int* __restrict__ ct,
    const int* __restrict__ wot, const int* __restrict__ Ut, float4* __restrict__ vt,
    const float4* __restrict__ sm, const int* __restrict__ uqm, const int* __restrict__ cm,
    const int* __restrict__ wom, const int* __restrict__ Um, float4* __restrict__ vm,
    const float4* __restrict__ sl, const int* __restrict__ uql, const int* __restrict__ cl,
    const int* __restrict__ wol, const int* __restrict__ Ul, float4* __restrict__ vl) {
  int bid = blockIdx.x;
  const float4* srt; const int *uniq, *cnt, *woff, *Up; float4* vmean; int r;
  if (bid < NBVT)           { r = bid*BLK + threadIdx.x;           srt=st; uniq=uqt; cnt=ct; woff=wot; Up=Ut; vmean=vt; }
  else if (bid < NBVT+NBVM) { r = (bid-NBVT)*BLK + threadIdx.x;    srt=sm; uniq=uqm; cnt=cm; woff=wom; Up=Um; vmean=vm; }
  else                      { r = (bid-NBVT-NBVM)*BLK + threadIdx.x; srt=sl; uniq=uql; cnt=cl; woff=wol; Up=Ul; vmean=vl; }
  if (r >= *Up) return;
  int lin = uniq[r];
  int len = cnt[lin];
  int base = woff[r] - len;
  float sx = 0.f, sy = 0.f, sz = 0.f;
  for (int k = 0; k < len; k++) {
    float4 p = srt[base + k];
    sx += p.x; sy += p.y; sz += p.z;
  }
  float il = 1.0f / (float)len;
  float4 o; o.x = sx*il; o.y = sy*il; o.z = sz*il; o.w = il;
  vmean[r] = o;
}

// ------- f-moment partials (65 values: 10 means + 55 upper-tri products) ----
__global__ __launch_bounds__(BLK) void k_fmom_all(SP a, SP b, SP c) {
  int s = blockIdx.x >> 8;
  int blk = blockIdx.x & 255;
  SP sp = (s == 0) ? a : ((s == 1) ? b : c);
  float m[65];
  #pragma unroll
  for (int i = 0; i < 65; i++) m[i] = 0.f;
  #pragma unroll
  for (int k = 0; k < 4; k++) {
    int i = blk*1024 + k*BLK + threadIdx.x;
    float4 p = sp.srt[i];
    float4 vmn = sp.vm[sp.jr[i]];
    float f[10];
    build_f(p, vmn, sp.vx, sp.vy, sp.vz, sp.gx, sp.gy, sp.gz, f);
    int idx = 10;
    #pragma unroll
    for (int d = 0; d < 10; d++) {
      m[d] += f[d];
      #pragma unroll
      for (int e = d; e < 10; e++) {
        m[idx] = fmaf(f[d], f[e], m[idx]);
        idx++;
      }
    }
  }
  #pragma unroll
  for (int st = 1; st < 64; st <<= 1) {
    #pragma unroll
    for (int i = 0; i < 65; i++) m[i] += __shfl_xor(m[i], st);
  }
  __shared__ float ws[4][65];
  int wv = threadIdx.x >> 6;
  int lane = threadIdx.x & 63;
  if (lane == 0) {
    #pragma unroll
    for (int i = 0; i < 65; i++) ws[wv][i] = m[i];
  }
  __syncthreads();
  if (threadIdx.x < 65) {
    int t = threadIdx.x;
    sp.part1[(size_t)blk*65 + t] = ws[0][t] + ws[1][t] + ws[2][t] + ws[3][t];
  }
}

// ---- reduce f-moments -> BN1 coef via mu = E[f]^T w, E[y^2] = w^T M w ------
__global__ __launch_bounds__(BLK) void k_mcoef_all(SP a, SP b, SP c) {
  SP sp = (blockIdx.x == 0) ? a : ((blockIdx.x == 1) ? b : c);
  const int C1 = sp.C1;
  __shared__ float M[65];
  int t = threadIdx.x;
  if (t < 65) {
    float s = 0.f;
    #pragma unroll 8
    for (int bk = 0; bk < ST1BLKS; bk++) s += sp.part1[(size_t)bk*65 + t];
    M[t] = s * (1.0f / NPTS);
  }
  __syncthreads();
  if (t < C1) {
    float wv[10];
    #pragma unroll
    for (int d = 0; d < 10; d++) wv[d] = sp.W1[d*C1 + t];
    float mu = 0.f;
    #pragma unroll
    for (int d = 0; d < 10; d++) mu = fmaf(M[d], wv[d], mu);
    float ey2 = 0.f;
    int idx = 10;
    #pragma unroll
    for (int d = 0; d < 10; d++) {
      #pragma unroll
      for (int e = d; e < 10; e++) {
        float c2 = M[idx] * wv[d] * wv[e];
        ey2 += (e == d) ? c2 : 2.0f * c2;
        idx++;
      }
    }
    float var = ey2 - mu*mu;
    float sc  = sp.g1[t] * (1.0f / sqrtf(var + 1e-3f));
    sp.coef1[t]      = sc;
    sp.coef1[C1 + t] = fmaf(-mu, sc, sp.b1[t]);
  }
}

// ---- layer-2 stats partials reduce -> BN2 coef -----------------------------
__device__ __forceinline__ void partcoef_body(const float* part, int NB, int C,
    int ch, const float* g, const float* b, float* coef) {
  float s = 0.f, q = 0.f;
  for (int bk = threadIdx.x; bk < NB; bk += BLK) {
    s += part[(size_t)bk*2*C + ch];
    q += part[(size_t)bk*2*C + C + ch];
  }
  __shared__ float ss[BLK], sq[BLK];
  ss[threadIdx.x] = s; sq[threadIdx.x] = q; __syncthreads();
  for (int off = BLK/2; off > 0; off >>= 1) {
    if (threadIdx.x < off) {
      ss[threadIdx.x] += ss[threadIdx.x + off];
      sq[threadIdx.x] += sq[threadIdx.x + off];
    }
    __syncthreads();
  }
  if (threadIdx.x == 0) {
    float mu  = ss[0] * (1.0f / NPTS);
    float var = sq[0] * (1.0f / NPTS) - mu*mu;
    float sc  = g[ch] * (1.0f / sqrtf(var + 1e-3f));
    coef[ch]     = sc;
    coef[C + ch] = fmaf(-mu, sc, b[ch]);
  }
}

__global__ __launch_bounds__(BLK) void k_partcoef2_all(SP a, SP b, SP c) {
  int bid = blockIdx.x; SP sp; int ch;
  if (bid < 128)      { sp = a; ch = bid; }
  else if (bid < 192) { sp = b; ch = bid - 128; }
  else                { sp = c; ch = bid - 192; }
  if (ch >= 2*sp.C1) return;
  partcoef_body(sp.part2, Y2B2, 2*sp.C1, ch, sp.g2, sp.b2, sp.coef2);
}

// ---- layer-1 voxel means of BN+ReLU(y1), y1 recomputed (all scales) --------
__global__ __launch_bounds__(BLK) void k_hsegT_all(SP a, SP b, SP c) {
  int bid = blockIdx.x; SP sp; int rb;
  if (bid < NHT)           { sp = a; rb = bid; }
  else if (bid < NHT+NHM)  { sp = b; rb = bid - NHT; }
  else                     { sp = c; rb = bid - NHT - NHM; }
  const int C1 = sp.C1;
  const int qsh = (C1 == 64) ? 4 : 3;
  __shared__ float w[640];
  __shared__ float sc[64], sb[64];
  for (int t = threadIdx.x; t < 10*C1; t += BLK) w[t] = sp.W1[t];
  for (int t = threadIdx.x; t < C1; t += BLK) { sc[t] = sp.coef1[t]; sb[t] = sp.coef1[C1 + t]; }
  __syncthreads();
  int tid = rb * BLK + threadIdx.x;
  int r = tid >> qsh;
  int q = tid & ((1 << qsh) - 1);
  if (r >= *sp.U) return;
  int lin = sp.uniq[r];
  int len = sp.cnt[lin];
  int base = sp.woff[r] - len;
  float4 vmn = sp.vm[r];
  int c0 = q * 4;
  float s0 = sc[c0+0], s1 = sc[c0+1], s2 = sc[c0+2], s3 = sc[c0+3];
  float o0 = sb[c0+0], o1 = sb[c0+1], o2 = sb[c0+2], o3 = sb[c0+3];
  float a0=0.f, a1=0.f, a2=0.f, a3=0.f;
  for (int k = 0; k < len; k++) {
    float4 p = sp.srt[base + k];
    float f[10];
    build_f(p, vmn, sp.vx, sp.vy, sp.vz, sp.gx, sp.gy, sp.gz, f);
    float y0=0.f, y1=0.f, y2=0.f, y3=0.f;
    #pragma unroll
    for (int d = 0; d < 10; d++) {
      float fv = f[d];
      const float* wr = &w[d*C1 + c0];
      y0 = fmaf(fv, wr[0], y0); y1 = fmaf(fv, wr[1], y1);
      y2 = fmaf(fv, wr[2], y2); y3 = fmaf(fv, wr[3], y3);
    }
    a0 += fmaxf(fmaf(y0, s0, o0), 0.f);
    a1 += fmaxf(fmaf(y1, s1, o1), 0.f);
    a2 += fmaxf(fmaf(y2, s2, o2), 0.f);
    a3 += fmaxf(fmaf(y3, s3, o3), 0.f);
  }
  float il = 1.0f / (float)len;
  sp.segt[(size_t)(c0+0)*sp.segstride + r] = a0*il;
  sp.segt[(size_t)(c0+1)*sp.segstride + r] = a1*il;
  sp.segt[(size_t)(c0+2)*sp.segstride + r] = a2*il;
  sp.segt[(size_t)(c0+3)*sp.segstride + r] = a3*il;
}

// ---- pack W2 -> bf16 B fragments (lane order for mfma 16x16x32) ------------
__global__ __launch_bounds__(BLK) void k_packB_all(
    const float* __restrict__ W2t_, unsigned short* __restrict__ Bt,
    const float* __restrict__ W2m_, unsigned short* __restrict__ Bm,
    const float* __restrict__ W2l_, unsigned short* __restrict__ Bl) {
  int bid = blockIdx.x;
  const float* W2; unsigned short* Bp; int C2, idx;
  if (bid < 64)      { W2 = W2t_; Bp = Bt; C2 = 128; idx = bid*BLK + threadIdx.x; }
  else if (bid < 80) { W2 = W2m_; Bp = Bm; C2 = 64;  idx = (bid-64)*BLK + threadIdx.x; }
  else               { W2 = W2l_; Bp = Bl; C2 = 64;  idx = (bid-80)*BLK + threadIdx.x; }
  if (idx >= C2*C2) return;            // K == C2 for all scales
  int NCF = C2/16;
  int per_kb = NCF*512;
  int kb = idx / per_kb, rem = idx % per_kb;
  int cf = rem / 512, r2 = rem % 512;
  int lane = r2 >> 3, j = r2 & 7;
  int k = kb*32 + (lane >> 4)*8 + j;
  int col = cf*16 + (lane & 15);
  Bp[idx] = f2bf(W2[(size_t)k*C2 + col]);
}

// ------- layer 2 as MFMA bf16 GEMM (64-row tiles); fused column stats -------
template<int C1>
__device__ __forceinline__ void y2m_body(const SP& sp,
    const unsigned short* __restrict__ Bpk, int blk, unsigned short* Alds) {
  constexpr int K   = 2*C1;
  constexpr int C2  = 2*C1;
  constexpr int MT  = 64;
  constexpr int NKB = K / 32;          // 4 (top), 2 (med/low)
  constexpr int NCF = C2 / 16;         // 8 (top), 4 (med/low)
  constexpr int RB  = K * 2;           // row bytes in Alds
  const int tid  = threadIdx.x;
  const int base = blk * MT;

  // ---- stage A tile (bf16, XOR-swizzled): 4 threads/row, K/4 channels each
  {
    const int jst = tid & 63;
    const int qst = tid >> 6;          // wave id == channel-quarter (wave-uniform)
    int jr = sp.jr[base + jst];
    float4 p = sp.srt[base + jst];
    float4 vmn = sp.vm[jr];
    float fs[10];
    build_f(p, vmn, sp.vx, sp.vy, sp.vz, sp.gx, sp.gy, sp.gz, fs);
    const int k_lo = qst * (K/4);
    #pragma unroll
    for (int kk = 0; kk < K/8; kk++) {
      int k0 = k_lo + kk*2;
      float v0, v1;
      if (k0 < C1) {
        float y0 = 0.f, y1v = 0.f;
        #pragma unroll
        for (int d = 0; d < 10; d++) {
          y0  = fmaf(fs[d], sp.W1[d*C1 + k0],     y0);
          y1v = fmaf(fs[d], sp.W1[d*C1 + k0 + 1], y1v);
        }
        v0 = fmaxf(fmaf(y0,  sp.coef1[k0],   sp.coef1[C1 + k0]),   0.f);
        v1 = fmaxf(fmaf(y1v, sp.coef1[k0+1], sp.coef1[C1 + k0+1]), 0.f);
      } else {
        v0 = sp.segt[(size_t)(k0     - C1)*sp.segstride + jr];
        v1 = sp.segt[(size_t)(k0 + 1 - C1)*sp.segstride + jr];
      }
      unsigned u = (unsigned)f2bf(v0) | ((unsigned)f2bf(v1) << 16);
      int g  = k0 >> 3;
      int gp = g ^ (jst & 7);
      *(unsigned*)((char*)Alds + (size_t)jst*RB + gp*16 + (k0 & 7)*2) = u;
    }
  }
  __syncthreads();

  // ---- MFMA main loop: wave w owns rows [w*16, w*16+16) ----
  const int w    = tid >> 6;
  const int l    = tid & 63;
  const int rowf = l & 15;
  const int kg   = l >> 4;
  const int row  = w*16 + rowf;
  f32x4 acc[NCF];
  #pragma unroll
  for (int cf = 0; cf < NCF; cf++) acc[cf] = (f32x4){0.f, 0.f, 0.f, 0.f};
  #pragma unroll
  for (int kb = 0; kb < NKB; kb++) {
    int g  = kb*4 + kg;
    int gp = g ^ (row & 7);
    bf16x8 a = *(const bf16x8*)((const char*)Alds + (size_t)row*RB + gp*16);
    const bf16x8* bfr = (const bf16x8*)Bpk + (size_t)(kb*NCF)*64 + l;
    #pragma unroll
    for (int cf = 0; cf < NCF; cf++) {
      bf16x8 b = bfr[cf*64];
      acc[cf] = __builtin_amdgcn_mfma_f32_16x16x32_bf16(a, b, acc[cf], 0, 0, 0);
    }
  }

  // ---- fused column sum/sumsq partials from fp32 acc (reuse Alds) ----
  __syncthreads();
  float* red = (float*)Alds;           // [32][C2] floats == Alds byte size
  #pragma unroll
  for (int cf = 0; cf < NCF; cf++) {
    f32x4 v = acc[cf];
    float sv = v.x + v.y + v.z + v.w;
    float qv = v.x*v.x + v.y*v.y + v.z*v.z + v.w*v.w;
    red[(w*4 + kg)*C2 + cf*16 + rowf]        = sv;
    red[(16 + w*4 + kg)*C2 + cf*16 + rowf]   = qv;
  }
  __syncthreads();
  if (tid < C2) {
    float sv = 0.f, qv = 0.f;
    #pragma unroll 4
    for (int i = 0; i < 16; i++) {
      sv += red[i*C2 + tid];
      qv += red[(16 + i)*C2 + tid];
    }
    sp.part2[(size_t)blk*2*C2 + tid]      = sv;
    sp.part2[(size_t)blk*2*C2 + C2 + tid] = qv;
  }
  __syncthreads();

  // ---- D -> LDS (bf16, row-major) -> coalesced global store ----
  unsigned short* D = Alds;
  #pragma unroll
  for (int cf = 0; cf < NCF; cf++) {
    #pragma unroll
    for (int rg = 0; rg < 4; rg++) {
      int rr = w*16 + kg*4 + rg;       // C/D: col=lane&15, row=(lane>>4)*4+reg
      D[rr*C2 + cf*16 + rowf] = f2bf(acc[cf][rg]);
    }
  }
  __syncthreads();
  for (int it = tid; it < MT*C2/8; it += BLK) {
    int r = (it*8) / C2;
    int c = (it*8) % C2;
    uint4 v = *(const uint4*)&D[it*8];
    *(uint4*)&sp.Y2[(size_t)(base + r)*C2 + c] = v;
  }
}

__global__ __launch_bounds__(BLK) void k_y2m_all(SP a, SP b, SP c,
    const unsigned short* __restrict__ Bt, const unsigned short* __restrict__ Bm,
    const unsigned short* __restrict__ Bl) {
  __shared__ unsigned short Alds[64*128];   // 16 KB (med/low use half)
  int bid = blockIdx.x;
  if (bid < Y2B2)        y2m_body<64>(a, Bt, bid, Alds);
  else if (bid < 2*Y2B2) y2m_body<32>(b, Bm, bid - Y2B2, Alds);
  else                   y2m_body<32>(c, Bl, bid - 2*Y2B2, Alds);
}

// -------- layer-2 BN+ReLU + voxel mean (bf16 Y2, all scales) ----------------
__global__ __launch_bounds__(BLK) void k_hseg2_all(SP a, SP b, SP c) {
  int bid = blockIdx.x; SP sp; int rb;
  if (bid < NJT)           { sp = a; rb = bid; }
  else if (bid < NJT+NJM)  { sp = b; rb = bid - NJT; }
  else                     { sp = c; rb = bid - NJT - NJM; }
  const int C = 2*sp.C1;
  const int qsh = (C == 128) ? 5 : 4;
  __shared__ float sc[128], sb[128];
  for (int t = threadIdx.x; t < C; t += BLK) { sc[t] = sp.coef2[t]; sb[t] = sp.coef2[C + t]; }
  __syncthreads();
  int tid = rb * BLK + threadIdx.x;
  int r = tid >> qsh;
  int q = tid & ((1 << qsh) - 1);
  if (r >= *sp.U) return;
  int lin = sp.uniq[r];
  int len = sp.cnt[lin];
  int base = sp.woff[r] - len;
  int c0 = q * 4;
  float s0 = sc[c0+0], s1 = sc[c0+1], s2 = sc[c0+2], s3 = sc[c0+3];
  float o0 = sb[c0+0], o1 = sb[c0+1], o2 = sb[c0+2], o3 = sb[c0+3];
  float a0=0.f, a1=0.f, a2=0.f, a3=0.f;
  const unsigned short* Yh = sp.Y2;
  for (int k = 0; k < len; k++) {
    ushort4 hv = *(const ushort4*)&Yh[(size_t)(base + k)*C + c0];
    a0 += fmaxf(fmaf(bf2f(hv.x), s0, o0), 0.f);
    a1 += fmaxf(fmaf(bf2f(hv.y), s1, o1), 0.f);
    a2 += fmaxf(fmaf(bf2f(hv.z), s2, o2), 0.f);
    a3 += fmaxf(fmaf(bf2f(hv.w), s3, o3), 0.f);
  }
  float il = 1.0f / (float)len;
  float4 o = {a0*il, a1*il, a2*il, a3*il};
  *(float4*)&sp.hout[(size_t)r*C + c0] = o;
}

// ------------- merge: per-parent child-rank lists (med+low batched) ---------
__global__ __launch_bounds__(BLK) void k_clist_all(const int* __restrict__ tuniq,
    const int* __restrict__ Utp,
    const int* __restrict__ cnt_m, const int* __restrict__ rank_m,
    int* __restrict__ clist_m, int* __restrict__ mcnt_m,
    const int* __restrict__ cnt_l, const int* __restrict__ rank_l,
    int* __restrict__ clist_l, int* __restrict__ mcnt_l) {
  int bid = blockIdx.x;
  const int *scnt, *srank; int *clist, *mcnt;
  int gx, gy, gz, f, rb;
  if (bid < NCL) { scnt=cnt_m; srank=rank_m; clist=clist_m; mcnt=mcnt_m;
                   gx=352; gy=400; gz=2; f=2; rb=bid; }
  else           { scnt=cnt_l; srank=rank_l; clist=clist_l; mcnt=mcnt_l;
                   gx=704; gy=800; gz=4; f=4; rb=bid-NCL; }
  int r = rb * BLK + threadIdx.x;
  if (r >= *Utp) return;
  int lin = tuniq[r];
  int x = lin % TGX; int t = lin / TGX;
  int y = t % TGY;   int b = t / TGY;   // TGZ == 1 so z == 0
  int m = 0;
  for (int cz = 0; cz < gz; cz++)
    for (int yy = y*f; yy < y*f + f; yy++)
      for (int xx = x*f; xx < x*f + f; xx++) {
        int cl = ((b*gz + cz)*gy + yy)*gx + xx;
        if (scnt[cl] > 0) clist[(size_t)r*64 + (m++)] = srank[cl];
      }
  mcnt[r] = m;
}

// ---- merge means written DIRECTLY into mg (med: cols 0-63, low: 64-127) ----
__global__ __launch_bounds__(BLK) void k_merge2_all(
    const float* __restrict__ vox_m, const int* __restrict__ clist_m,
    const int* __restrict__ mcnt_m,
    const float* __restrict__ vox_l, const int* __restrict__ clist_l,
    const int* __restrict__ mcnt_l,
    const int* __restrict__ Utp, float* __restrict__ mg) {
  int bid = blockIdx.x;
  const float* vox; const int *clist, *mcnt; int half, rb;
  if (bid < NHT) { vox=vox_m; clist=clist_m; mcnt=mcnt_m; half=0; rb=bid; }
  else           { vox=vox_l; clist=clist_l; mcnt=mcnt_l; half=64; rb=bid-NHT; }
  int idx = rb * BLK + threadIdx.x;
  int r = idx >> 4;
  int q = idx & 15;
  if (r >= *Utp) return;
  int m = mcnt[r];
  float a0=0.f, a1=0.f, a2=0.f, a3=0.f;
  for (int t = 0; t < m; t++) {
    int cr = clist[(size_t)r*64 + t];
    float4 v = *(const float4*)&vox[(size_t)cr*64 + q*4];
    a0 += v.x; a1 += v.y; a2 += v.z; a3 += v.w;
  }
  float inv = 1.0f / (float)max(m, 1);
  float4 o = {a0*inv, a1*inv, a2*inv, a3*inv};
  *(float4*)&mg[(size_t)r*128 + half + q*4] = o;
}

// ---- final: vf/mg tail zero + coors ----------------------------------------
__global__ __launch_bounds__(BLK) void k_fin_all(const int* __restrict__ uniq,
    const int* __restrict__ Up, float* __restrict__ vf,
    float* __restrict__ mg, float* __restrict__ coors) {
  int idx = blockIdx.x * BLK + threadIdx.x;
  int r = idx >> 5;
  int q = idx & 31;
  if (r >= NPTS) return;
  int U = *Up;
  if (r >= U) {
    float4 z = {0.f, 0.f, 0.f, 0.f};
    *(float4*)&mg[(size_t)r*128 + q*4] = z;
    *(float4*)&vf[(size_t)r*128 + q*4] = z;
  }
  if (q == 0) {
    float4 co;
    if (r < U) {
      int lin = uniq[r];
      int x = lin % TGX; int t = lin / TGX;
      int y = t % TGY;   t /= TGY;
      int z = t % TGZ;   int b = t / TGZ;
      co.x = (float)b; co.y = (float)z; co.z = (float)y; co.w = (float)x;
    } else {
      co.x = -1.f; co.y = -1.f; co.z = -1.f; co.w = -1.f;
    }
    *(float4*)&coors[(size_t)r*4] = co;
  }
}

extern "C" void kernel_launch(void* const* d_in, const int* in_sizes, int n_in,
                              void* d_out, int out_size, void* d_ws, size_t ws_size,
                              hipStream_t stream) {
  const float* pts = (const float*)d_in[0];

  float* out = (float*)d_out;
  float* vf = out;                              // N x 128 (final vf)
  float* mg = out + (size_t)NPTS * 128;         // N x 128 (merged)
  float* co = out + (size_t)NPTS * 256;         // N x 4   (coors)

  char* w = (char*)d_ws;
  size_t off = 0;
  auto alloc = [&](size_t bytes) -> void* {
    void* p = w + off;
    off = (off + bytes + 1023) & ~(size_t)1023;
    return p;
  };
  int*    cnt_t   = (int*)alloc(((size_t)G_TOPC + G_MEDC + G_LOWC) * 4);
  int*    cnt_m   = cnt_t + G_TOPC;
  int*    cnt_l   = cnt_t + G_TOPC + G_MEDC;
  int*    rank_t  = (int*)alloc((size_t)G_TOPC * 4);
  int*    rank_m  = (int*)alloc((size_t)G_MEDC * 4);
  int*    rank_l  = (int*)alloc((size_t)G_LOWC * 4);
  int*    uniq_t  = (int*)alloc((size_t)G_TOPC * 4);
  int*    uniq_m  = (int*)alloc((size_t)NPTS * 4);
  int*    uniq_l  = (int*)alloc((size_t)NPTS * 4);
  int*    woff_t  = (int*)alloc((size_t)G_TOPC * 4);
  int*    woff_m  = (int*)alloc((size_t)NPTS * 4);
  int*    woff_l  = (int*)alloc((size_t)NPTS * 4);
  float4* srt_t   = (float4*)alloc((size_t)NPTS * 16);
  float4* srt_m   = (float4*)alloc((size_t)NPTS * 16);
  float4* srt_l   = (float4*)alloc((size_t)NPTS * 16);
  int*    jr_t    = (int*)alloc((size_t)NPTS * 4);
  int*    jr_m    = (int*)alloc((size_t)NPTS * 4);
  int*    jr_l    = (int*)alloc((size_t)NPTS * 4);
  float4* vm_t    = (float4*)alloc((size_t)G_TOPC * 16);
  float4* vm_m    = (float4*)alloc((size_t)NPTS * 16);
  float4* vm_l    = (float4*)alloc((size_t)NPTS * 16);
  float*  segt_t  = (float*)alloc((size_t)G_TOPC * 64 * 4);
  float*  segt_m  = (float*)alloc((size_t)NPTS * 32 * 4);
  float*  segt_l  = (float*)alloc((size_t)NPTS * 32 * 4);
  float*  vox_m   = (float*)alloc((size_t)NPTS * 64 * 4);
  float*  vox_l   = (float*)alloc((size_t)NPTS * 64 * 4);
  unsigned short* Y2h_t = (unsigned short*)alloc((size_t)NPTS * 128 * 2);
  unsigned short* Y2h_m = (unsigned short*)alloc((size_t)NPTS * 64 * 2);
  unsigned short* Y2h_l = (unsigned short*)alloc((size_t)NPTS * 64 * 2);
  unsigned short* Bpk_t = (unsigned short*)alloc(16384 * 2);
  unsigned short* Bpk_m = (unsigned short*)alloc(4096 * 2);
  unsigned short* Bpk_l = (unsigned short*)alloc(4096 * 2);
  int*    clist_m = (int*)alloc((size_t)G_TOPC * 64 * 4);
  int*    clist_l = (int*)alloc((size_t)G_TOPC * 64 * 4);
  int*    mcnt_m  = (int*)alloc((size_t)G_TOPC * 4);
  int*    mcnt_l  = (int*)alloc((size_t)G_TOPC * 4);
  float*  part1_t = (float*)alloc((size_t)ST1BLKS * 128 * 4);
  float*  part1_m = (float*)alloc((size_t)ST1BLKS * 128 * 4);
  float*  part1_l = (float*)alloc((size_t)ST1BLKS * 128 * 4);
  float*  part2_t = (float*)alloc((size_t)Y2B2 * 256 * 4);
  float*  part2_m = (float*)alloc((size_t)Y2B2 * 128 * 4);
  float*  part2_l = (float*)alloc((size_t)Y2B2 * 128 * 4);
  float*  coef    = (float*)alloc(6 * 256 * 4);
  int2*   bsum    = (int2*)alloc(1024 * 8);
  int*    Ut      = (int*)alloc(64);
  int*    Um      = (int*)alloc(64);
  int*    Ul      = (int*)alloc(64);
  (void)in_sizes; (void)n_in; (void)out_size; (void)ws_size;

  auto mkSP = [&](int scaleIdx) -> SP {
    SP s{};
    if (scaleIdx == 0) {
      s.srt = srt_t; s.jr = jr_t; s.vm = vm_t;
      s.W1 = (const float*)d_in[2];  s.g1 = (const float*)d_in[3];
      s.b1 = (const float*)d_in[4];  s.W2 = (const float*)d_in[5];
      s.g2 = (const float*)d_in[6];  s.b2 = (const float*)d_in[7];
      s.cnt = cnt_t; s.uniq = uniq_t; s.woff = woff_t; s.U = Ut;
      s.segt = segt_t; s.part1 = part1_t; s.part2 = part2_t;
      s.coef1 = coef + 0*256; s.coef2 = coef + 1*256;
      s.Y2 = Y2h_t; s.hout = vf;
      s.C1 = 64; s.segstride = G_TOPC;
      s.gx = 176; s.gy = 200; s.gz = 1; s.vx = 0.4f; s.vy = 0.4f; s.vz = 4.0f;
    } else if (scaleIdx == 1) {
      s.srt = srt_m; s.jr = jr_m; s.vm = vm_m;
      s.W1 = (const float*)d_in[8];  s.g1 = (const float*)d_in[9];
      s.b1 = (const float*)d_in[10]; s.W2 = (const float*)d_in[11];
      s.g2 = (const float*)d_in[12]; s.b2 = (const float*)d_in[13];
      s.cnt = cnt_m; s.uniq = uniq_m; s.woff = woff_m; s.U = Um;
      s.segt = segt_m; s.part1 = part1_m; s.part2 = part2_m;
      s.coef1 = coef + 2*256; s.coef2 = coef + 3*256;
      s.Y2 = Y2h_m; s.hout = vox_m;
      s.C1 = 32; s.segstride = NPTS;
      s.gx = 352; s.gy = 400; s.gz = 2; s.vx = 0.2f; s.vy = 0.2f; s.vz = 2.0f;
    } else {
      s.srt = srt_l; s.jr = jr_l; s.vm = vm_l;
      s.W1 = (const float*)d_in[14]; s.g1 = (const float*)d_in[15];
      s.b1 = (const float*)d_in[16]; s.W2 = (const float*)d_in[17];
      s.g2 = (const float*)d_in[18]; s.b2 = (const float*)d_in[19];
      s.cnt = cnt_l; s.uniq = uniq_l; s.woff = woff_l; s.U = Ul;
      s.segt = segt_l; s.part1 = part1_l; s.part2 = part2_l;
      s.coef1 = coef + 4*256; s.coef2 = coef + 5*256;
      s.Y2 = Y2h_l; s.hout = vox_l;
      s.C1 = 32; s.segstride = NPTS;
      s.gx = 704; s.gy = 800; s.gz = 4; s.vx = 0.1f; s.vy = 0.1f; s.vz = 1.0f;
    }
    return s;
  };
  SP spT = mkSP(0), spM = mkSP(1), spL = mkSP(2);

  // ---- W2 bf16 fragment pre-pack (no deps beyond inputs) ----
  k_packB_all<<<96, BLK, 0, stream>>>((const float*)d_in[5], Bpk_t,
      (const float*)d_in[11], Bpk_m, (const float*)d_in[17], Bpk_l);

  // ---- batched voxelization front-end ----
  (void)hipMemsetAsync(cnt_t, 0, ((size_t)G_TOPC + G_MEDC + G_LOWC) * 4, stream);
  k_count3<<<NPTS/BLK, BLK, 0, stream>>>(pts, cnt_t, cnt_m, cnt_l);
  k_scan1_all<<<NB_T + NB_M + NB_L, BLK, 0, stream>>>(cnt_t, cnt_m, cnt_l, bsum);
  k_scan2_all<<<1, 1024, 0, stream>>>(bsum, Ut, Um, Ul);
  k_scan3_all<<<NB_T + NB_M + NB_L, BLK, 0, stream>>>(cnt_t, cnt_m, cnt_l, bsum,
      rank_t, rank_m, rank_l, uniq_t, uniq_m, uniq_l, woff_t, woff_m, woff_l);
  k_clist_all<<<2*NCL, BLK, 0, stream>>>(uniq_t, Ut,
      cnt_m, rank_m, clist_m, mcnt_m, cnt_l, rank_l, clist_l, mcnt_l);
  k_scatter3<<<NPTS/BLK, BLK, 0, stream>>>(pts,
      rank_t, woff_t, srt_t, jr_t,
      rank_m, woff_m, srt_m, jr_m,
      rank_l, woff_l, srt_l, jr_l);
  k_vox13<<<NBVT + NBVM + NBVL, BLK, 0, stream>>>(
      srt_t, uniq_t, cnt_t, woff_t, Ut, vm_t,
      srt_m, uniq_m, cnt_m, woff_m, Um, vm_m,
      srt_l, uniq_l, cnt_l, woff_l, Ul, vm_l);

  // ---- batched VFE pipeline (all scales per stage) ----
  k_fmom_all<<<3*ST1BLKS, BLK, 0, stream>>>(spT, spM, spL);
  k_mcoef_all<<<3, BLK, 0, stream>>>(spT, spM, spL);
  k_hsegT_all<<<NHT + 2*NHM, BLK, 0, stream>>>(spT, spM, spL);
  k_y2m_all<<<3*Y2B2, BLK, 0, stream>>>(spT, spM, spL, Bpk_t, Bpk_m, Bpk_l);
  k_partcoef2_all<<<256, BLK, 0, stream>>>(spT, spM, spL);
  k_hseg2_all<<<NJT + 2*NJM, BLK, 0, stream>>>(spT, spM, spL);

  // ---- merges + final outputs ----
  k_merge2_all<<<2*NHT, BLK, 0, stream>>>(vox_m, clist_m, mcnt_m,
      vox_l, clist_l, mcnt_l, Ut, mg);
  k_fin_all<<<(NPTS*32)/BLK, BLK, 0, stream>>>(uniq_t, Ut, vf, mg, co);
}

// Round 13
// 609.616 us; speedup vs baseline: 1.4194x; 1.1215x over previous
//
#include <hip/hip_runtime.h>
#include <cstdint>
#include <cstddef>

#define NPTS 262144
#define BLK 256
#define TGX 176
#define TGY 200
#define TGZ 1

#define G_TOPC 70400
#define G_MEDC 1126400
#define G_LOWC 4505600

#define SCAN_ITEMS 32
#define SCAN_CHUNK (BLK*SCAN_ITEMS)
// batched scan block counts / bsum offsets (disjoint: [0,9) [16,154) [160,710))
#define NB_T 9
#define NB_M 138
#define NB_L 550
#define BO_T 0
#define BO_M 16
#define BO_L 160
// vox13 block split
#define NBVT (G_TOPC/BLK)      // 275
#define NBVM (NPTS/BLK)        // 1024
#define NBVL (NPTS/BLK)        // 1024

#define Y2B2 (NPTS/64)         // 4096 blocks per scale (64-row MFMA tiles)
#define ST1BLKS 256            // fmom blocks per scale (1024 rows each)
// batched per-scale stage grids
#define NHT2 2200              // G_TOPC*8/BLK   (hsegT top, 8 ch/thread)
#define NHM2 4096              // NPTS*4/BLK     (hsegT med/low)
#define NJT2 4400              // G_TOPC*16/BLK  (hseg2 top, 8 ch/thread)
#define NJM2 8192              // NPTS*8/BLK     (hseg2 med/low)
#define NMG 4400               // G_TOPC*16/BLK  (merge, 16 thr/voxel)
#define FINB 32768             // NPTS*32/BLK    (fin)
#define NCL 275                // G_TOPC/BLK (ceil)

typedef __attribute__((ext_vector_type(8))) short bf16x8;
typedef __attribute__((ext_vector_type(4))) float f32x4;

// ---------------- per-scale parameter pack ----------------
struct SP {
  const float4* srt; const int* jr; const float4* vm;
  const float* W1; const float* W2;
  const float* g1; const float* b1; const float* g2; const float* b2;
  const int* cnt; const int* uniq; const int* woff; const int* U;
  unsigned short* segt;        // bf16 storage (lossless: only consumed as bf16)
  float* part1; float* part2;
  float* coef1; float* coef2;
  unsigned short* Y2;          // bf16 storage
  float* hout;
  int C1; int segstride; int gx, gy, gz; float vx, vy, vz;
};

// ---------------- bf16 helpers ----------------
__device__ __forceinline__ unsigned short f2bf(float v) {
  unsigned u = __float_as_uint(v);
  u += 0x7FFFu + ((u >> 16) & 1u);      // round-to-nearest-even
  return (unsigned short)(u >> 16);
}
__device__ __forceinline__ float bf2f(unsigned short h) {
  return __uint_as_float((unsigned)h << 16);
}

// ---------------- voxel coord helpers ----------------
__device__ __forceinline__ void pcoords(float x, float y, float z,
    float vx, float vy, float vz, int gx, int gy, int gz,
    int& cx, int& cy, int& cz) {
  cx = (int)floorf((x - 0.0f)  / vx);
  cy = (int)floorf((y + 40.0f) / vy);
  cz = (int)floorf((z + 3.0f)  / vz);
  cx = min(max(cx, 0), gx - 1);
  cy = min(max(cy, 0), gy - 1);
  cz = min(max(cz, 0), gz - 1);
}

__device__ __forceinline__ int lin3(float b, float x, float y, float z,
    float vx, float vy, float vz, int gx, int gy, int gz) {
  int cx, cy, cz; pcoords(x, y, z, vx, vy, vz, gx, gy, gz, cx, cy, cz);
  return (((int)b * gz + cz) * gy + cy) * gx + cx;
}

// f-vector (10 features) — identical expression everywhere y1 is recomputed.
__device__ __forceinline__ void build_f(float4 p, float4 vm,
    float vx, float vy, float vz, int gx, int gy, int gz, float* f) {
  int cx, cy, cz; pcoords(p.x, p.y, p.z, vx, vy, vz, gx, gy, gz, cx, cy, cz);
  f[0] = p.x; f[1] = p.y; f[2] = p.z; f[3] = p.w;
  f[4] = p.x - vm.x;
  f[5] = p.y - vm.y;
  f[6] = p.z - vm.z;
  f[7] = p.x - (0.0f   + (cx + 0.5f)*vx);
  f[8] = p.y - (-40.0f + (cy + 0.5f)*vy);
  f[9] = p.z - (-3.0f  + (cz + 0.5f)*vz);
}

// ------- fused: dense count (3 scales) + W2 bf16 fragment pre-pack ----------
__global__ __launch_bounds__(BLK) void k_count3pack(const float* __restrict__ pts,
    int* __restrict__ ct, int* __restrict__ cm, int* __restrict__ cl,
    const float* __restrict__ W2t_, unsigned short* __restrict__ Bt,
    const float* __restrict__ W2m_, unsigned short* __restrict__ Bm,
    const float* __restrict__ W2l_, unsigned short* __restrict__ Bl) {
  int bid = blockIdx.x;
  if (bid < NPTS/BLK) {
    int i = bid * BLK + threadIdx.x;
    float b = pts[i*5+0], x = pts[i*5+1], y = pts[i*5+2], z = pts[i*5+3];
    atomicAdd(&ct[lin3(b,x,y,z, 0.4f,0.4f,4.0f, 176,200,1)], 1);
    atomicAdd(&cm[lin3(b,x,y,z, 0.2f,0.2f,2.0f, 352,400,2)], 1);
    atomicAdd(&cl[lin3(b,x,y,z, 0.1f,0.1f,1.0f, 704,800,4)], 1);
    return;
  }
  int pb = bid - NPTS/BLK;
  const float* W2; unsigned short* Bp; int C2, idx;
  if (pb < 64)      { W2 = W2t_; Bp = Bt; C2 = 128; idx = pb*BLK + threadIdx.x; }
  else if (pb < 80) { W2 = W2m_; Bp = Bm; C2 = 64;  idx = (pb-64)*BLK + threadIdx.x; }
  else              { W2 = W2l_; Bp = Bl; C2 = 64;  idx = (pb-80)*BLK + threadIdx.x; }
  if (idx >= C2*C2) return;            // K == C2 for all scales
  int NCF = C2/16;
  int per_kb = NCF*512;
  int kb = idx / per_kb, rem = idx % per_kb;
  int cf = rem / 512, r2 = rem % 512;
  int lane = r2 >> 3, j = r2 & 7;
  int k = kb*32 + (lane >> 4)*8 + j;
  int col = cf*16 + (lane & 15);
  Bp[idx] = f2bf(W2[(size_t)k*C2 + col]);
}

// ---------------- batched scans ----------------
__global__ __launch_bounds__(BLK) void k_scan1_all(const int* __restrict__ ct,
    const int* __restrict__ cm, const int* __restrict__ cl,
    int2* __restrict__ bsum) {
  int bid = blockIdx.x;
  const int* cnt; int G, bo, cb;
  if (bid < NB_T)            { cnt = ct; G = G_TOPC; bo = BO_T; cb = bid; }
  else if (bid < NB_T+NB_M)  { cnt = cm; G = G_MEDC; bo = BO_M; cb = bid - NB_T; }
  else                       { cnt = cl; G = G_LOWC; bo = BO_L; cb = bid - NB_T - NB_M; }
  int base = cb * SCAN_CHUNK + threadIdx.x * SCAN_ITEMS;
  int so = 0, sp = 0;
  #pragma unroll
  for (int k = 0; k < SCAN_ITEMS; k++) {
    int j = base + k;
    if (j < G) { int c = cnt[j]; if (c > 0) { so++; sp += c; } }
  }
  __shared__ int sho[BLK], shp[BLK];
  sho[threadIdx.x] = so; shp[threadIdx.x] = sp; __syncthreads();
  for (int off = BLK/2; off > 0; off >>= 1) {
    if (threadIdx.x < off) {
      sho[threadIdx.x] += sho[threadIdx.x + off];
      shp[threadIdx.x] += shp[threadIdx.x + off];
    }
    __syncthreads();
  }
  if (threadIdx.x == 0) { int2 v; v.x = sho[0]; v.y = shp[0]; bsum[bo + cb] = v; }
}

// ---- scan2: 3 independent wave-level shuffle scans (no __syncthreads) ------
__global__ __launch_bounds__(192) void k_scan2_all(int2* __restrict__ bsum,
    int* __restrict__ Ut, int* __restrict__ Um, int* __restrict__ Ul) {
  int wv = threadIdx.x >> 6;
  int lane = threadIdx.x & 63;
  int off, nb; int* U;
  if (wv == 0)      { off = BO_T; nb = NB_T; U = Ut; }
  else if (wv == 1) { off = BO_M; nb = NB_M; U = Um; }
  else              { off = BO_L; nb = NB_L; U = Ul; }
  const int IPL = 9;                       // 64*9 = 576 >= 550
  int eo[IPL], ep[IPL];
  int accO = 0, accP = 0;
  #pragma unroll
  for (int k = 0; k < IPL; k++) {
    int idx = lane*IPL + k;
    int2 t = {0, 0};
    if (idx < nb) t = bsum[off + idx];
    eo[k] = accO; ep[k] = accP;            // within-lane exclusive prefix
    accO += t.x; accP += t.y;
  }
  int xo = accO, xp = accP;
  #pragma unroll
  for (int d = 1; d < 64; d <<= 1) {
    int to = __shfl_up(xo, d);
    int tp = __shfl_up(xp, d);
    if (lane >= d) { xo += to; xp += tp; }
  }
  int baseO = xo - accO, baseP = xp - accP;
  #pragma unroll
  for (int k = 0; k < IPL; k++) {
    int idx = lane*IPL + k;
    if (idx < nb) { int2 e; e.x = baseO + eo[k]; e.y = baseP + ep[k]; bsum[off + idx] = e; }
  }
  int tot = __shfl(xo, 63);
  if (lane == 0) *U = tot;
}

__global__ __launch_bounds__(BLK) void k_scan3_all(const int* __restrict__ ct,
    const int* __restrict__ cm, const int* __restrict__ cl,
    const int2* __restrict__ bsum,
    int* __restrict__ rkt, int* __restrict__ rkm, int* __restrict__ rkl,
    int* __restrict__ uqt, int* __restrict__ uqm, int* __restrict__ uql,
    int* __restrict__ wot, int* __restrict__ wom, int* __restrict__ wol) {
  int bid = blockIdx.x;
  const int* cnt; int G, bo, cb; int *rank, *uniq, *woff;
  if (bid < NB_T)           { cnt=ct; G=G_TOPC; bo=BO_T; cb=bid;            rank=rkt; uniq=uqt; woff=wot; }
  else if (bid < NB_T+NB_M) { cnt=cm; G=G_MEDC; bo=BO_M; cb=bid-NB_T;       rank=rkm; uniq=uqm; woff=wom; }
  else                      { cnt=cl; G=G_LOWC; bo=BO_L; cb=bid-NB_T-NB_M;  rank=rkl; uniq=uql; woff=wol; }
  int base = cb * SCAN_CHUNK + threadIdx.x * SCAN_ITEMS;
  int so = 0, sp = 0;
  #pragma unroll
  for (int k = 0; k < SCAN_ITEMS; k++) {
    int j = base + k;
    if (j < G) { int c = cnt[j]; if (c > 0) { so++; sp += c; } }
  }
  __shared__ int sho[BLK], shp[BLK];
  sho[threadIdx.x] = so; shp[threadIdx.x] = sp; __syncthreads();
  for (int off = 1; off < BLK; off <<= 1) {
    int ao = (threadIdx.x >= off) ? sho[threadIdx.x - off] : 0;
    int ap = (threadIdx.x >= off) ? shp[threadIdx.x - off] : 0;
    __syncthreads();
    sho[threadIdx.x] += ao; shp[threadIdx.x] += ap;
    __syncthreads();
  }
  int2 bb = bsum[bo + cb];
  int ro = bb.x + sho[threadIdx.x] - so;
  int po = bb.y + shp[threadIdx.x] - sp;
  for (int k = 0; k < SCAN_ITEMS; k++) {
    int j = base + k;
    if (j < G) {
      int c = cnt[j];
      if (c > 0) { rank[j] = ro; uniq[ro] = j; woff[ro] = po; ro++; po += c; }
    }
  }
}

// ------- fused: counting-sort scatter (3 scales) + parent child-lists -------
__global__ __launch_bounds__(BLK) void k_scatclist(const float* __restrict__ pts,
    const int* __restrict__ rkt, int* __restrict__ wot, float4* __restrict__ st, int* __restrict__ jt,
    const int* __restrict__ rkm, int* __restrict__ wom, float4* __restrict__ sm, int* __restrict__ jm,
    const int* __restrict__ rkl, int* __restrict__ wol, float4* __restrict__ sl, int* __restrict__ jl,
    const int* __restrict__ tuniq, const int* __restrict__ Utp,
    const int* __restrict__ cnt_m, const int* __restrict__ rank_m,
    int* __restrict__ clist_m, int* __restrict__ mcnt_m,
    const int* __restrict__ cnt_l, const int* __restrict__ rank_l,
    int* __restrict__ clist_l, int* __restrict__ mcnt_l) {
  int bid = blockIdx.x;
  if (bid < NPTS/BLK) {
    int i = bid * BLK + threadIdx.x;
    float b = pts[i*5+0], x = pts[i*5+1], y = pts[i*5+2], z = pts[i*5+3], it = pts[i*5+4];
    float4 p; p.x = x; p.y = y; p.z = z; p.w = it;
    {
      int r = rkt[lin3(b,x,y,z, 0.4f,0.4f,4.0f, 176,200,1)];
      int j = atomicAdd(&wot[r], 1); st[j] = p; jt[j] = r;
    }
    {
      int r = rkm[lin3(b,x,y,z, 0.2f,0.2f,2.0f, 352,400,2)];
      int j = atomicAdd(&wom[r], 1); sm[j] = p; jm[j] = r;
    }
    {
      int r = rkl[lin3(b,x,y,z, 0.1f,0.1f,1.0f, 704,800,4)];
      int j = atomicAdd(&wol[r], 1); sl[j] = p; jl[j] = r;
    }
    return;
  }
  int cb = bid - NPTS/BLK;
  const int *scnt, *srank; int *clist, *mcnt;
  int gx, gy, gz, f, rb;
  if (cb < NCL) { scnt=cnt_m; srank=rank_m; clist=clist_m; mcnt=mcnt_m;
                  gx=352; gy=400; gz=2; f=2; rb=cb; }
  else          { scnt=cnt_l; srank=rank_l; clist=clist_l; mcnt=mcnt_l;
                  gx=704; gy=800; gz=4; f=4; rb=cb-NCL; }
  int r = rb * BLK + threadIdx.x;
  if (r >= *Utp) return;
  int lin = tuniq[r];
  int x = lin % TGX; int t = lin / TGX;
  int y = t % TGY;   int b = t / TGY;   // TGZ == 1 so z == 0
  int m = 0;
  for (int cz = 0; cz < gz; cz++)
    for (int yy = y*f; yy < y*f + f; yy++)
      for (int xx = x*f; xx < x*f + f; xx++) {
        int cl = ((b*gz + cz)*gy + yy)*gx + xx;
        if (scnt[cl] > 0) clist[(size_t)r*64 + (m++)] = srank[cl];
      }
  mcnt[r] = m;
}

// ---------------- batched per-voxel xyz means ----------------
__global__ __launch_bounds__(BLK) void k_vox13(
    const float4* __restrict__ st, const int* __restrict__ uqt, const int* __restrict__ ct,
    const int* __restrict__ wot, const int* __restrict__ Ut, float4* __restrict__ vt,
    const float4* __restrict__ sm, const int* __restrict__ uqm, const int* __restrict__ cm,
    const int* __restrict__ wom, const int* __restrict__ Um, float4* __restrict__ vm,
    const float4* __restrict__ sl, const int* __restrict__ uql, const int* __restrict__ cl,
    const int* __restrict__ wol, const int* __restrict__ Ul, float4* __restrict__ vl) {
  int bid = blockIdx.x;
  const float4* srt; const int *uniq, *cnt, *woff, *Up; float4* vmean; int r;
  if (bid < NBVT)           { r = bid*BLK + threadIdx.x;           srt=st; uniq=uqt; cnt=ct; woff=wot; Up=Ut; vmean=vt; }
  else if (bid < NBVT+NBVM) { r = (bid-NBVT)*BLK + threadIdx.x;    srt=sm; uniq=uqm; cnt=cm; woff=wom; Up=Um; vmean=vm; }
  else                      { r = (bid-NBVT-NBVM)*BLK + threadIdx.x; srt=sl; uniq=uql; cnt=cl; woff=wol; Up=Ul; vmean=vl; }
  if (r >= *Up) return;
  int lin = uniq[r];
  int len = cnt[lin];
  int base = woff[r] - len;
  float sx = 0.f, sy = 0.f, sz = 0.f;
  for (int k = 0; k < len; k++) {
    float4 p = srt[base + k];
    sx += p.x; sy += p.y; sz += p.z;
  }
  float il = 1.0f / (float)len;
  float4 o; o.x = sx*il; o.y = sy*il; o.z = sz*il; o.w = il;
  vmean[r] = o;
}

// ------- f-moment partials (65 values: 10 means + 55 upper-tri products) ----
__global__ __launch_bounds__(BLK) void k_fmom_all(SP a, SP b, SP c) {
  int s = blockIdx.x >> 8;
  int blk = blockIdx.x & 255;
  SP sp = (s == 0) ? a : ((s == 1) ? b : c);
  float m[65];
  #pragma unroll
  for (int i = 0; i < 65; i++) m[i] = 0.f;
  #pragma unroll
  for (int k = 0; k < 4; k++) {
    int i = blk*1024 + k*BLK + threadIdx.x;
    float4 p = sp.srt[i];
    float4 vmn = sp.vm[sp.jr[i]];
    float f[10];
    build_f(p, vmn, sp.vx, sp.vy, sp.vz, sp.gx, sp.gy, sp.gz, f);
    int idx = 10;
    #pragma unroll
    for (int d = 0; d < 10; d++) {
      m[d] += f[d];
      #pragma unroll
      for (int e = d; e < 10; e++) {
        m[idx] = fmaf(f[d], f[e], m[idx]);
        idx++;
      }
    }
  }
  #pragma unroll
  for (int st = 1; st < 64; st <<= 1) {
    #pragma unroll
    for (int i = 0; i < 65; i++) m[i] += __shfl_xor(m[i], st);
  }
  __shared__ float ws[4][65];
  int wv = threadIdx.x >> 6;
  int lane = threadIdx.x & 63;
  if (lane == 0) {
    #pragma unroll
    for (int i = 0; i < 65; i++) ws[wv][i] = m[i];
  }
  __syncthreads();
  if (threadIdx.x < 65) {
    int t = threadIdx.x;
    sp.part1[(size_t)blk*65 + t] = ws[0][t] + ws[1][t] + ws[2][t] + ws[3][t];
  }
}

// ---- reduce f-moments -> BN1 coef via mu = E[f]^T w, E[y^2] = w^T M w ------
__global__ __launch_bounds__(BLK) void k_mcoef_all(SP a, SP b, SP c) {
  SP sp = (blockIdx.x == 0) ? a : ((blockIdx.x == 1) ? b : c);
  const int C1 = sp.C1;
  __shared__ float M[65];
  int t = threadIdx.x;
  if (t < 65) {
    float s = 0.f;
    #pragma unroll 8
    for (int bk = 0; bk < ST1BLKS; bk++) s += sp.part1[(size_t)bk*65 + t];
    M[t] = s * (1.0f / NPTS);
  }
  __syncthreads();
  if (t < C1) {
    float wv[10];
    #pragma unroll
    for (int d = 0; d < 10; d++) wv[d] = sp.W1[d*C1 + t];
    float mu = 0.f;
    #pragma unroll
    for (int d = 0; d < 10; d++) mu = fmaf(M[d], wv[d], mu);
    float ey2 = 0.f;
    int idx = 10;
    #pragma unroll
    for (int d = 0; d < 10; d++) {
      #pragma unroll
      for (int e = d; e < 10; e++) {
        float c2 = M[idx] * wv[d] * wv[e];
        ey2 += (e == d) ? c2 : 2.0f * c2;
        idx++;
      }
    }
    float var = ey2 - mu*mu;
    float sc  = sp.g1[t] * (1.0f / sqrtf(var + 1e-3f));
    sp.coef1[t]      = sc;
    sp.coef1[C1 + t] = fmaf(-mu, sc, sp.b1[t]);
  }
}

// ---- layer-2 stats partials reduce -> BN2 coef -----------------------------
__device__ __forceinline__ void partcoef_body(const float* part, int NB, int C,
    int ch, const float* g, const float* b, float* coef) {
  float s = 0.f, q = 0.f;
  for (int bk = threadIdx.x; bk < NB; bk += BLK) {
    s += part[(size_t)bk*2*C + ch];
    q += part[(size_t)bk*2*C + C + ch];
  }
  __shared__ float ss[BLK], sq[BLK];
  ss[threadIdx.x] = s; sq[threadIdx.x] = q; __syncthreads();
  for (int off = BLK/2; off > 0; off >>= 1) {
    if (threadIdx.x < off) {
      ss[threadIdx.x] += ss[threadIdx.x + off];
      sq[threadIdx.x] += sq[threadIdx.x + off];
    }
    __syncthreads();
  }
  if (threadIdx.x == 0) {
    float mu  = ss[0] * (1.0f / NPTS);
    float var = sq[0] * (1.0f / NPTS) - mu*mu;
    float sc  = g[ch] * (1.0f / sqrtf(var + 1e-3f));
    coef[ch]     = sc;
    coef[C + ch] = fmaf(-mu, sc, b[ch]);
  }
}

__global__ __launch_bounds__(BLK) void k_partcoef2_all(SP a, SP b, SP c) {
  int bid = blockIdx.x; SP sp; int ch;
  if (bid < 128)      { sp = a; ch = bid; }
  else if (bid < 192) { sp = b; ch = bid - 128; }
  else                { sp = c; ch = bid - 192; }
  if (ch >= 2*sp.C1) return;
  partcoef_body(sp.part2, Y2B2, 2*sp.C1, ch, sp.g2, sp.b2, sp.coef2);
}

// ---- layer-1 voxel means of BN+ReLU(y1), 8 channels/thread, bf16 out -------
__global__ __launch_bounds__(BLK) void k_hsegT_all(SP a, SP b, SP c) {
  int bid = blockIdx.x; SP sp; int rb;
  if (bid < NHT2)           { sp = a; rb = bid; }
  else if (bid < NHT2+NHM2) { sp = b; rb = bid - NHT2; }
  else                      { sp = c; rb = bid - NHT2 - NHM2; }
  const int C1 = sp.C1;
  const int qsh = (C1 == 64) ? 3 : 2;      // threads per voxel = C1/8
  __shared__ float w[640];
  __shared__ float sc[64], sb[64];
  for (int t = threadIdx.x; t < 10*C1; t += BLK) w[t] = sp.W1[t];
  for (int t = threadIdx.x; t < C1; t += BLK) { sc[t] = sp.coef1[t]; sb[t] = sp.coef1[C1 + t]; }
  __syncthreads();
  int tid = rb * BLK + threadIdx.x;
  int r = tid >> qsh;
  int q = tid & ((1 << qsh) - 1);
  if (r >= *sp.U) return;
  int lin = sp.uniq[r];
  int len = sp.cnt[lin];
  int base = sp.woff[r] - len;
  float4 vmn = sp.vm[r];
  int c0 = q * 8;
  float s[8], o[8], acc[8];
  #pragma unroll
  for (int e = 0; e < 8; e++) { s[e] = sc[c0+e]; o[e] = sb[c0+e]; acc[e] = 0.f; }
  for (int k = 0; k < len; k++) {
    float4 p = sp.srt[base + k];
    float f[10];
    build_f(p, vmn, sp.vx, sp.vy, sp.vz, sp.gx, sp.gy, sp.gz, f);
    float y[8] = {0,0,0,0,0,0,0,0};
    #pragma unroll
    for (int d = 0; d < 10; d++) {
      float fv = f[d];
      const float* wr = &w[d*C1 + c0];
      #pragma unroll
      for (int e = 0; e < 8; e++) y[e] = fmaf(fv, wr[e], y[e]);
    }
    #pragma unroll
    for (int e = 0; e < 8; e++) acc[e] += fmaxf(fmaf(y[e], s[e], o[e]), 0.f);
  }
  float il = 1.0f / (float)len;
  #pragma unroll
  for (int e = 0; e < 8; e++)
    sp.segt[(size_t)(c0+e)*sp.segstride + r] = f2bf(acc[e]*il);
}

// ------- layer 2 as MFMA bf16 GEMM (64-row tiles); fused column stats -------
template<int C1>
__device__ __forceinline__ void y2m_body(const SP& sp,
    const unsigned short* __restrict__ Bpk, int blk, unsigned short* Alds) {
  constexpr int K   = 2*C1;
  constexpr int C2  = 2*C1;
  constexpr int MT  = 64;
  constexpr int NKB = K / 32;          // 4 (top), 2 (med/low)
  constexpr int NCF = C2 / 16;         // 8 (top), 4 (med/low)
  constexpr int RB  = K * 2;           // row bytes in Alds
  const int tid  = threadIdx.x;
  const int base = blk * MT;

  // ---- stage A tile (bf16, XOR-swizzled): 4 threads/row, K/4 channels each
  {
    const int jst = tid & 63;
    const int qst = tid >> 6;          // wave id == channel-quarter (wave-uniform)
    int jr = sp.jr[base + jst];
    float4 p = sp.srt[base + jst];
    float4 vmn = sp.vm[jr];
    float fs[10];
    build_f(p, vmn, sp.vx, sp.vy, sp.vz, sp.gx, sp.gy, sp.gz, fs);
    const int k_lo = qst * (K/4);
    #pragma unroll
    for (int kk = 0; kk < K/8; kk++) {
      int k0 = k_lo + kk*2;
      unsigned u;
      if (k0 < C1) {
        float y0 = 0.f, y1v = 0.f;
        #pragma unroll
        for (int d = 0; d < 10; d++) {
          y0  = fmaf(fs[d], sp.W1[d*C1 + k0],     y0);
          y1v = fmaf(fs[d], sp.W1[d*C1 + k0 + 1], y1v);
        }
        float v0 = fmaxf(fmaf(y0,  sp.coef1[k0],   sp.coef1[C1 + k0]),   0.f);
        float v1 = fmaxf(fmaf(y1v, sp.coef1[k0+1], sp.coef1[C1 + k0+1]), 0.f);
        u = (unsigned)f2bf(v0) | ((unsigned)f2bf(v1) << 16);
      } else {
        unsigned s0 = sp.segt[(size_t)(k0     - C1)*sp.segstride + jr];
        unsigned s1 = sp.segt[(size_t)(k0 + 1 - C1)*sp.segstride + jr];
        u = s0 | (s1 << 16);
      }
      int g  = k0 >> 3;
      int gp = g ^ (jst & 7);
      *(unsigned*)((char*)Alds + (size_t)jst*RB + gp*16 + (k0 & 7)*2) = u;
    }
  }
  __syncthreads();

  // ---- MFMA main loop: wave w owns rows [w*16, w*16+16) ----
  const int w    = tid >> 6;
  const int l    = tid & 63;
  const int rowf = l & 15;
  const int kg   = l >> 4;
  const int row  = w*16 + rowf;
  f32x4 acc[NCF];
  #pragma unroll
  for (int cf = 0; cf < NCF; cf++) acc[cf] = (f32x4){0.f, 0.f, 0.f, 0.f};
  #pragma unroll
  for (int kb = 0; kb < NKB; kb++) {
    int g  = kb*4 + kg;
    int gp = g ^ (row & 7);
    bf16x8 a = *(const bf16x8*)((const char*)Alds + (size_t)row*RB + gp*16);
    const bf16x8* bfr = (const bf16x8*)Bpk + (size_t)(kb*NCF)*64 + l;
    #pragma unroll
    for (int cf = 0; cf < NCF; cf++) {
      bf16x8 b = bfr[cf*64];
      acc[cf] = __builtin_amdgcn_mfma_f32_16x16x32_bf16(a, b, acc[cf], 0, 0, 0);
    }
  }

  // ---- fused column sum/sumsq partials from fp32 acc (reuse Alds) ----
  __syncthreads();
  float* red = (float*)Alds;           // [32][C2] floats == Alds byte size
  #pragma unroll
  for (int cf = 0; cf < NCF; cf++) {
    f32x4 v = acc[cf];
    float sv = v.x + v.y + v.z + v.w;
    float qv = v.x*v.x + v.y*v.y + v.z*v.z + v.w*v.w;
    red[(w*4 + kg)*C2 + cf*16 + rowf]        = sv;
    red[(16 + w*4 + kg)*C2 + cf*16 + rowf]   = qv;
  }
  __syncthreads();
  if (tid < C2) {
    float sv = 0.f, qv = 0.f;
    #pragma unroll 4
    for (int i = 0; i < 16; i++) {
      sv += red[i*C2 + tid];
      qv += red[(16 + i)*C2 + tid];
    }
    sp.part2[(size_t)blk*2*C2 + tid]      = sv;
    sp.part2[(size_t)blk*2*C2 + C2 + tid] = qv;
  }
  __syncthreads();

  // ---- D -> LDS (bf16, row-major) -> coalesced global store ----
  unsigned short* D = Alds;
  #pragma unroll
  for (int cf = 0; cf < NCF; cf++) {
    #pragma unroll
    for (int rg = 0; rg < 4; rg++) {
      int rr = w*16 + kg*4 + rg;       // C/D: col=lane&15, row=(lane>>4)*4+reg
      D[rr*C2 + cf*16 + rowf] = f2bf(acc[cf][rg]);
    }
  }
  __syncthreads();
  for (int it = tid; it < MT*C2/8; it += BLK) {
    int r = (it*8) / C2;
    int c = (it*8) % C2;
    uint4 v = *(const uint4*)&D[it*8];
    *(uint4*)&sp.Y2[(size_t)(base + r)*C2 + c] = v;
  }
}

__global__ __launch_bounds__(BLK) void k_y2m_all(SP a, SP b, SP c,
    const unsigned short* __restrict__ Bt, const unsigned short* __restrict__ Bm,
    const unsigned short* __restrict__ Bl) {
  __shared__ unsigned short Alds[64*128];   // 16 KB (med/low use half)
  int bid = blockIdx.x;
  if (bid < Y2B2)        y2m_body<64>(a, Bt, bid, Alds);
  else if (bid < 2*Y2B2) y2m_body<32>(b, Bm, bid - Y2B2, Alds);
  else                   y2m_body<32>(c, Bl, bid - 2*Y2B2, Alds);
}

// -------- layer-2 BN+ReLU + voxel mean (bf16 Y2, 8 channels/thread) ---------
__global__ __launch_bounds__(BLK) void k_hseg2_all(SP a, SP b, SP c) {
  int bid = blockIdx.x; SP sp; int rb;
  if (bid < NJT2)           { sp = a; rb = bid; }
  else if (bid < NJT2+NJM2) { sp = b; rb = bid - NJT2; }
  else                      { sp = c; rb = bid - NJT2 - NJM2; }
  const int C = 2*sp.C1;
  const int qsh = (C == 128) ? 4 : 3;      // threads per voxel = C/8
  __shared__ float sc[128], sb[128];
  for (int t = threadIdx.x; t < C; t += BLK) { sc[t] = sp.coef2[t]; sb[t] = sp.coef2[C + t]; }
  __syncthreads();
  int tid = rb * BLK + threadIdx.x;
  int r = tid >> qsh;
  int q = tid & ((1 << qsh) - 1);
  if (r >= *sp.U) return;
  int lin = sp.uniq[r];
  int len = sp.cnt[lin];
  int base = sp.woff[r] - len;
  int c0 = q * 8;
  float s[8], o[8], acc[8];
  #pragma unroll
  for (int e = 0; e < 8; e++) { s[e] = sc[c0+e]; o[e] = sb[c0+e]; acc[e] = 0.f; }
  const unsigned short* Yh = sp.Y2;
  for (int k = 0; k < len; k++) {
    uint4 hv = *(const uint4*)&Yh[(size_t)(base + k)*C + c0];
    unsigned uu[4] = {hv.x, hv.y, hv.z, hv.w};
    #pragma unroll
    for (int j = 0; j < 4; j++) {
      float lo = __uint_as_float(uu[j] << 16);
      float hi = __uint_as_float(uu[j] & 0xFFFF0000u);
      acc[2*j+0] += fmaxf(fmaf(lo, s[2*j+0], o[2*j+0]), 0.f);
      acc[2*j+1] += fmaxf(fmaf(hi, s[2*j+1], o[2*j+1]), 0.f);
    }
  }
  float il = 1.0f / (float)len;
  float4 o0 = {acc[0]*il, acc[1]*il, acc[2]*il, acc[3]*il};
  float4 o1 = {acc[4]*il, acc[5]*il, acc[6]*il, acc[7]*il};
  *(float4*)&sp.hout[(size_t)r*C + c0]     = o0;
  *(float4*)&sp.hout[(size_t)r*C + c0 + 4] = o1;
}

// ---- fused: merge means into mg (r<U) + tail zero + coors ------------------
__global__ __launch_bounds__(BLK) void k_mergefin(
    const float* __restrict__ vox_m, const int* __restrict__ clist_m,
    const int* __restrict__ mcnt_m,
    const float* __restrict__ vox_l, const int* __restrict__ clist_l,
    const int* __restrict__ mcnt_l,
    const int* __restrict__ uniq, const int* __restrict__ Up,
    float* __restrict__ vf, float* __restrict__ mg, float* __restrict__ coors) {
  int bid = blockIdx.x;
  if (bid < 2*NMG) {
    const float* vox; const int *clist, *mcnt; int half, rb;
    if (bid < NMG) { vox=vox_m; clist=clist_m; mcnt=mcnt_m; half=0; rb=bid; }
    else           { vox=vox_l; clist=clist_l; mcnt=mcnt_l; half=64; rb=bid-NMG; }
    int idx = rb * BLK + threadIdx.x;
    int r = idx >> 4;
    int q = idx & 15;
    if (r >= *Up) return;
    int m = mcnt[r];
    float a0=0.f, a1=0.f, a2=0.f, a3=0.f;
    for (int t = 0; t < m; t++) {
      int cr = clist[(size_t)r*64 + t];
      float4 v = *(const float4*)&vox[(size_t)cr*64 + q*4];
      a0 += v.x; a1 += v.y; a2 += v.z; a3 += v.w;
    }
    float inv = 1.0f / (float)max(m, 1);
    float4 o = {a0*inv, a1*inv, a2*inv, a3*inv};
    *(float4*)&mg[(size_t)r*128 + half + q*4] = o;
    return;
  }
  int idx = (bid - 2*NMG) * BLK + threadIdx.x;
  int r = idx >> 5;
  int q = idx & 31;
  if (r >= NPTS) return;
  int U = *Up;
  if (r >= U) {
    float4 z = {0.f, 0.f, 0.f, 0.f};
    *(float4*)&mg[(size_t)r*128 + q*4] = z;
    *(float4*)&vf[(size_t)r*128 + q*4] = z;
  }
  if (q == 0) {
    float4 co;
    if (r < U) {
      int lin = uniq[r];
      int x = lin % TGX; int t = lin / TGX;
      int y = t % TGY;   t /= TGY;
      int z = t % TGZ;   int b = t / TGZ;
      co.x = (float)b; co.y = (float)z; co.z = (float)y; co.w = (float)x;
    } else {
      co.x = -1.f; co.y = -1.f; co.z = -1.f; co.w = -1.f;
    }
    *(float4*)&coors[(size_t)r*4] = co;
  }
}

extern "C" void kernel_launch(void* const* d_in, const int* in_sizes, int n_in,
                              void* d_out, int out_size, void* d_ws, size_t ws_size,
                              hipStream_t stream) {
  const float* pts = (const float*)d_in[0];

  float* out = (float*)d_out;
  float* vf = out;                              // N x 128 (final vf)
  float* mg = out + (size_t)NPTS * 128;         // N x 128 (merged)
  float* co = out + (size_t)NPTS * 256;         // N x 4   (coors)

  char* w = (char*)d_ws;
  size_t off = 0;
  auto alloc = [&](size_t bytes) -> void* {
    void* p = w + off;
    off = (off + bytes + 1023) & ~(size_t)1023;
    return p;
  };
  int*    cnt_t   = (int*)alloc(((size_t)G_TOPC + G_MEDC + G_LOWC) * 4);
  int*    cnt_m   = cnt_t + G_TOPC;
  int*    cnt_l   = cnt_t + G_TOPC + G_MEDC;
  int*    rank_t  = (int*)alloc((size_t)G_TOPC * 4);
  int*    rank_m  = (int*)alloc((size_t)G_MEDC * 4);
  int*    rank_l  = (int*)alloc((size_t)G_LOWC * 4);
  int*    uniq_t  = (int*)alloc((size_t)G_TOPC * 4);
  int*    uniq_m  = (int*)alloc((size_t)NPTS * 4);
  int*    uniq_l  = (int*)alloc((size_t)NPTS * 4);
  int*    woff_t  = (int*)alloc((size_t)G_TOPC * 4);
  int*    woff_m  = (int*)alloc((size_t)NPTS * 4);
  int*    woff_l  = (int*)alloc((size_t)NPTS * 4);
  float4* srt_t   = (float4*)alloc((size_t)NPTS * 16);
  float4* srt_m   = (float4*)alloc((size_t)NPTS * 16);
  float4* srt_l   = (float4*)alloc((size_t)NPTS * 16);
  int*    jr_t    = (int*)alloc((size_t)NPTS * 4);
  int*    jr_m    = (int*)alloc((size_t)NPTS * 4);
  int*    jr_l    = (int*)alloc((size_t)NPTS * 4);
  float4* vm_t    = (float4*)alloc((size_t)G_TOPC * 16);
  float4* vm_m    = (float4*)alloc((size_t)NPTS * 16);
  float4* vm_l    = (float4*)alloc((size_t)NPTS * 16);
  unsigned short* segt_t = (unsigned short*)alloc((size_t)G_TOPC * 64 * 2);
  unsigned short* segt_m = (unsigned short*)alloc((size_t)NPTS * 32 * 2);
  unsigned short* segt_l = (unsigned short*)alloc((size_t)NPTS * 32 * 2);
  float*  vox_m   = (float*)alloc((size_t)NPTS * 64 * 4);
  float*  vox_l   = (float*)alloc((size_t)NPTS * 64 * 4);
  unsigned short* Y2h_t = (unsigned short*)alloc((size_t)NPTS * 128 * 2);
  unsigned short* Y2h_m = (unsigned short*)alloc((size_t)NPTS * 64 * 2);
  unsigned short* Y2h_l = (unsigned short*)alloc((size_t)NPTS * 64 * 2);
  unsigned short* Bpk_t = (unsigned short*)alloc(16384 * 2);
  unsigned short* Bpk_m = (unsigned short*)alloc(4096 * 2);
  unsigned short* Bpk_l = (unsigned short*)alloc(4096 * 2);
  int*    clist_m = (int*)alloc((size_t)G_TOPC * 64 * 4);
  int*    clist_l = (int*)alloc((size_t)G_TOPC * 64 * 4);
  int*    mcnt_m  = (int*)alloc((size_t)G_TOPC * 4);
  int*    mcnt_l  = (int*)alloc((size_t)G_TOPC * 4);
  float*  part1_t = (float*)alloc((size_t)ST1BLKS * 128 * 4);
  float*  part1_m = (float*)alloc((size_t)ST1BLKS * 128 * 4);
  float*  part1_l = (float*)alloc((size_t)ST1BLKS * 128 * 4);
  float*  part2_t = (float*)alloc((size_t)Y2B2 * 256 * 4);
  float*  part2_m = (float*)alloc((size_t)Y2B2 * 128 * 4);
  float*  part2_l = (float*)alloc((size_t)Y2B2 * 128 * 4);
  float*  coef    = (float*)alloc(6 * 256 * 4);
  int2*   bsum    = (int2*)alloc(1024 * 8);
  int*    Ut      = (int*)alloc(64);
  int*    Um      = (int*)alloc(64);
  int*    Ul      = (int*)alloc(64);
  (void)in_sizes; (void)n_in; (void)out_size; (void)ws_size;

  auto mkSP = [&](int scaleIdx) -> SP {
    SP s{};
    if (scaleIdx == 0) {
      s.srt = srt_t; s.jr = jr_t; s.vm = vm_t;
      s.W1 = (const float*)d_in[2];  s.g1 = (const float*)d_in[3];
      s.b1 = (const float*)d_in[4];  s.W2 = (const float*)d_in[5];
      s.g2 = (const float*)d_in[6];  s.b2 = (const float*)d_in[7];
      s.cnt = cnt_t; s.uniq = uniq_t; s.woff = woff_t; s.U = Ut;
      s.segt = segt_t; s.part1 = part1_t; s.part2 = part2_t;
      s.coef1 = coef + 0*256; s.coef2 = coef + 1*256;
      s.Y2 = Y2h_t; s.hout = vf;
      s.C1 = 64; s.segstride = G_TOPC;
      s.gx = 176; s.gy = 200; s.gz = 1; s.vx = 0.4f; s.vy = 0.4f; s.vz = 4.0f;
    } else if (scaleIdx == 1) {
      s.srt = srt_m; s.jr = jr_m; s.vm = vm_m;
      s.W1 = (const float*)d_in[8];  s.g1 = (const float*)d_in[9];
      s.b1 = (const float*)d_in[10]; s.W2 = (const float*)d_in[11];
      s.g2 = (const float*)d_in[12]; s.b2 = (const float*)d_in[13];
      s.cnt = cnt_m; s.uniq = uniq_m; s.woff = woff_m; s.U = Um;
      s.segt = segt_m; s.part1 = part1_m; s.part2 = part2_m;
      s.coef1 = coef + 2*256; s.coef2 = coef + 3*256;
      s.Y2 = Y2h_m; s.hout = vox_m;
      s.C1 = 32; s.segstride = NPTS;
      s.gx = 352; s.gy = 400; s.gz = 2; s.vx = 0.2f; s.vy = 0.2f; s.vz = 2.0f;
    } else {
      s.srt = srt_l; s.jr = jr_l; s.vm = vm_l;
      s.W1 = (const float*)d_in[14]; s.g1 = (const float*)d_in[15];
      s.b1 = (const float*)d_in[16]; s.W2 = (const float*)d_in[17];
      s.g2 = (const float*)d_in[18]; s.b2 = (const float*)d_in[19];
      s.cnt = cnt_l; s.uniq = uniq_l; s.woff = woff_l; s.U = Ul;
      s.segt = segt_l; s.part1 = part1_l; s.part2 = part2_l;
      s.coef1 = coef + 4*256; s.coef2 = coef + 5*256;
      s.Y2 = Y2h_l; s.hout = vox_l;
      s.C1 = 32; s.segstride = NPTS;
      s.gx = 704; s.gy = 800; s.gz = 4; s.vx = 0.1f; s.vy = 0.1f; s.vz = 1.0f;
    }
    return s;
  };
  SP spT = mkSP(0), spM = mkSP(1), spL = mkSP(2);

  // ---- batched voxelization front-end ----
  (void)hipMemsetAsync(cnt_t, 0, ((size_t)G_TOPC + G_MEDC + G_LOWC) * 4, stream);
  k_count3pack<<<NPTS/BLK + 96, BLK, 0, stream>>>(pts, cnt_t, cnt_m, cnt_l,
      (const float*)d_in[5], Bpk_t, (const float*)d_in[11], Bpk_m,
      (const float*)d_in[17], Bpk_l);
  k_scan1_all<<<NB_T + NB_M + NB_L, BLK, 0, stream>>>(cnt_t, cnt_m, cnt_l, bsum);
  k_scan2_all<<<1, 192, 0, stream>>>(bsum, Ut, Um, Ul);
  k_scan3_all<<<NB_T + NB_M + NB_L, BLK, 0, stream>>>(cnt_t, cnt_m, cnt_l, bsum,
      rank_t, rank_m, rank_l, uniq_t, uniq_m, uniq_l, woff_t, woff_m, woff_l);
  k_scatclist<<<NPTS/BLK + 2*NCL, BLK, 0, stream>>>(pts,
      rank_t, woff_t, srt_t, jr_t,
      rank_m, woff_m, srt_m, jr_m,
      rank_l, woff_l, srt_l, jr_l,
      uniq_t, Ut, cnt_m, rank_m, clist_m, mcnt_m, cnt_l, rank_l, clist_l, mcnt_l);
  k_vox13<<<NBVT + NBVM + NBVL, BLK, 0, stream>>>(
      srt_t, uniq_t, cnt_t, woff_t, Ut, vm_t,
      srt_m, uniq_m, cnt_m, woff_m, Um, vm_m,
      srt_l, uniq_l, cnt_l, woff_l, Ul, vm_l);

  // ---- batched VFE pipeline (all scales per stage) ----
  k_fmom_all<<<3*ST1BLKS, BLK, 0, stream>>>(spT, spM, spL);
  k_mcoef_all<<<3, BLK, 0, stream>>>(spT, spM, spL);
  k_hsegT_all<<<NHT2 + 2*NHM2, BLK, 0, stream>>>(spT, spM, spL);
  k_y2m_all<<<3*Y2B2, BLK, 0, stream>>>(spT, spM, spL, Bpk_t, Bpk_m, Bpk_l);
  k_partcoef2_all<<<256, BLK, 0, stream>>>(spT, spM, spL);
  k_hseg2_all<<<NJT2 + 2*NJM2, BLK, 0, stream>>>(spT, spM, spL);

  // ---- merges + final outputs (one kernel) ----
  k_mergefin<<<2*NMG + FINB, BLK, 0, stream>>>(vox_m, clist_m, mcnt_m,
      vox_l, clist_l, mcnt_l, uniq_t, Ut, vf, mg, co);
}